// Round 7
// baseline (2907.804 us; speedup 1.0000x reference)
//
#include <hip/hip_runtime.h>
#include <math.h>

typedef unsigned short u16;
typedef unsigned int u32;

#define D_DIM 2048
#define N_ROWS 4096
#define EPS_DIAG 1e-3f
#define NS_ITERS 16  // fallback path only

typedef __attribute__((ext_vector_type(8))) short bf16x8;
typedef __attribute__((ext_vector_type(4))) float f32x4;

__device__ __forceinline__ u16 f2bf(float f) {
  u32 u = __float_as_uint(f);
  u += 0x7fffu + ((u >> 16) & 1u);
  return (u16)(u >> 16);
}
__device__ __forceinline__ float bf2f(u16 h) {
  return __uint_as_float(((u32)h) << 16);
}

#define GLD16(g, l)                                        \
  __builtin_amdgcn_global_load_lds(                        \
      (const __attribute__((address_space(1))) void*)(g),  \
      (__attribute__((address_space(3))) void*)(l), 16, 0, 0)

// scal layout (floats): [1]=trA [2]=trB [5]=c  [6..11]=powerA  [16..21]=powerB
// [24..25] = trdot double accumulator

// XCD column-ownership swizzle for 256-tile grids (16 bi x 16 bj).
// (Round-6 A/B: L2-locality swizzles are NULL -- staging cap is per-CU,
// not aggregate. Kept because it is harmless and bijective.)
__device__ __forceinline__ void swz256(int id, int& bi, int& bj) {
  int s = id & 7;   // XCD (dispatch round-robin)
  int j = id >> 3;  // 0..31 within XCD
  bj = s * 2 + (j & 1);
  bi = j >> 1;
}

// ---------------- column statistics (both inputs, one launch) ----------------

__global__ __launch_bounds__(256)
void k_colstats2(const float* __restrict__ za, const float* __restrict__ zb,
                 float* __restrict__ stat) {
  const float* z = blockIdx.z ? zb : za;
  float* sum_ = stat + blockIdx.z * 2 * D_DIM;
  float* ssq_ = sum_ + D_DIM;
  const int c = blockIdx.x * 256 + threadIdx.x;
  const int r0 = blockIdx.y * (N_ROWS / 16);
  float s = 0.f, q = 0.f;
#pragma unroll 8
  for (int r = 0; r < N_ROWS / 16; ++r) {
    float v = z[(size_t)(r0 + r) * D_DIM + c];
    s += v;
    q += v * v;
  }
  atomicAdd(&sum_[c], s);
  atomicAdd(&ssq_[c], q);
}

__global__ __launch_bounds__(256)
void k_finalize_stats(float* stat) {
  const int t = blockIdx.x * 256 + threadIdx.x;
  const int g = t >> 11;
  const int c = t & (D_DIM - 1);
  float* base = stat + g * 2 * D_DIM;
  float s = base[c];
  float q = base[D_DIM + c];
  float mean = s * (1.0f / N_ROWS);
  float var = (q - (float)N_ROWS * mean * mean) * (1.0f / (N_ROWS - 1));
  var = fmaxf(var, 1e-30f);
  base[c] = mean;
  base[D_DIM + c] = 1.0f / sqrtf(var);
}

// ================== FAST PATH (needs 128MB + 64KB workspace) ==================

// standardize + split + TRANSPOSE both inputs: z[N][D] -> Zt[D][N] bf16 h/l
__global__ __launch_bounds__(256)
void k_zsplit_t2(const float* __restrict__ za, const float* __restrict__ zb,
                 const float* __restrict__ stat, u16* __restrict__ Zh0,
                 u16* __restrict__ Zl0, u16* __restrict__ Zh1,
                 u16* __restrict__ Zl1) {
  __shared__ float T[64 * 72];
  const float* z = blockIdx.z ? zb : za;
  const float* mean = stat + blockIdx.z * 2 * D_DIM;
  const float* rstd = mean + D_DIM;
  u16* Zth = blockIdx.z ? Zh1 : Zh0;
  u16* Ztl = blockIdx.z ? Zl1 : Zl0;
  const int t = threadIdx.x;
  const int r0 = blockIdx.x * 64;
  const int c0 = blockIdx.y * 64;
#pragma unroll
  for (int p = 0; p < 4; ++p) {
    int row = p * 16 + (t >> 4);
    int c4 = t & 15;
    float4 v = *(const float4*)(z + (size_t)(r0 + row) * D_DIM + c0 + c4 * 4);
    *(float4*)&T[row * 72 + c4 * 4] = v;
  }
  __syncthreads();
  const int c = c0 + (t >> 2);
  const float m = mean[c];
  const float r = rstd[c];
  const int cc = t >> 2;
#pragma unroll
  for (int g = 0; g < 2; ++g) {
    int rbase = g * 32 + (t & 3) * 8;
    u16 hs[8], ls[8];
#pragma unroll
    for (int i = 0; i < 8; ++i) {
      float x = (T[(rbase + i) * 72 + cc] - m) * r;
      hs[i] = f2bf(x);
      ls[i] = f2bf(x - bf2f(hs[i]));
    }
    uint4 ph, pl;
    ph.x = (u32)hs[0] | ((u32)hs[1] << 16);
    ph.y = (u32)hs[2] | ((u32)hs[3] << 16);
    ph.z = (u32)hs[4] | ((u32)hs[5] << 16);
    ph.w = (u32)hs[6] | ((u32)hs[7] << 16);
    pl.x = (u32)ls[0] | ((u32)ls[1] << 16);
    pl.y = (u32)ls[2] | ((u32)ls[3] << 16);
    pl.z = (u32)ls[4] | ((u32)ls[5] << 16);
    pl.w = (u32)ls[6] | ((u32)ls[7] << 16);
    size_t o = (size_t)c * N_ROWS + r0 + rbase;
    *(uint4*)(Zth + o) = ph;
    *(uint4*)(Ztl + o) = pl;
  }
}

#define FINVC 1
#define FTRACE 4
#define FCOL 8
#define FROW 16

// Unified split-bf16 MFMA GEMM body: C = diag*I + pm*(X * W^T).
// 128x128 tile, BK=64 (was 32): per-wave in-flight staging bytes DOUBLE
// (16 loads, vmcnt(16)) and barrier/drain events HALVE, at constant
// staged traffic (2.0 B/elem). Round-6 PMC localized the wall as a
// PER-CU staging service cap (~10-12 B/cyc even with 240 CUs idle) --
// Little's law says the fix is outstanding bytes, not placement.
// Schedule (race-free per round 4):
//   barrier#1 -> STAGE(k+1)->nxt -> vmcnt(16) -> barrier#2 -> compute(cur)
// LDS 2 x 64KB = 128KB -> 1 block/CU.
__device__ __forceinline__ void nn_body(
    u16* lds, const u16* __restrict__ Xh, const u16* __restrict__ Xl,
    const u16* __restrict__ Wh, const u16* __restrict__ Wl,
    u16* __restrict__ Crh, u16* __restrict__ Crl, u16* __restrict__ Cch,
    u16* __restrict__ Ccl, float* __restrict__ scal, int K, float diag,
    float pmul, int flags, int tidx, int bi, int bj) {
  const int tid = threadIdx.x;
  const int lane = tid & 63;
  const int w = tid >> 6;
  const int I = bi * 128;
  const int J = bj * 128;

  // staging map (BK=64): slot s in [0,1024): row m = (s>>7)*16 + (s&15),
  // k-chunk q = (s>>4)&7 (8 elems). Bijective; matches MFMA fragment layout
  // for k-slice ks: slot = group*128 + ks*64 + lane.
  size_t xro[4], wro[4];
  int xbase[4];
#pragma unroll
  for (int p = 0; p < 4; ++p) {
    int s = p * 256 + w * 64 + lane;
    int m = ((s >> 7) << 4) + (s & 15);
    int qq = (s >> 4) & 7;
    xro[p] = (size_t)(I + m) * K + qq * 8;
    wro[p] = (size_t)(J + m) * K + qq * 8;
    xbase[p] = s * 8;
  }

  f32x4 acc[2][8];
#pragma unroll
  for (int i = 0; i < 2; ++i)
#pragma unroll
    for (int j = 0; j < 8; ++j) acc[i][j] = (f32x4){0.f, 0.f, 0.f, 0.f};

// 16 global_load_lds per wave per stage (X h/l + W h/l, 4 each).
// Buffer layout (u16): Xh @0, Xl @8192, Wh @16384, Wl @24576; stride 32768.
#define NN_STAGE(k1, buf)                                         \
  {                                                               \
    _Pragma("unroll") for (int p = 0; p < 4; ++p) {               \
      GLD16(Xh + xro[p] + (k1), &lds[(buf) + xbase[p]]);          \
      GLD16(Xl + xro[p] + (k1), &lds[(buf) + 8192 + xbase[p]]);   \
      GLD16(Wh + wro[p] + (k1), &lds[(buf) + 16384 + xbase[p]]);  \
      GLD16(Wl + wro[p] + (k1), &lds[(buf) + 24576 + xbase[p]]);  \
    }                                                             \
  }

// compute: 2 k-slices (ks) x 2 jb half-passes (4 W-fragments live -> VGPR cap)
#define NN_COMPUTE(CUR)                                                \
  {                                                                    \
    _Pragma("unroll") for (int ks = 0; ks < 2; ++ks) {                 \
      bf16x8 fxh[2], fxl[2];                                           \
      _Pragma("unroll") for (int i = 0; i < 2; ++i) {                  \
        int sl = ((w * 2 + i) * 128 + ks * 64 + lane) * 8;             \
        fxh[i] = *(const bf16x8*)&lds[(CUR) + sl];                     \
        fxl[i] = *(const bf16x8*)&lds[(CUR) + 8192 + sl];              \
      }                                                                \
      _Pragma("unroll") for (int jb = 0; jb < 2; ++jb) {               \
        bf16x8 fwh[4], fwl[4];                                         \
        _Pragma("unroll") for (int jj = 0; jj < 4; ++jj) {             \
          int sl = ((jb * 4 + jj) * 128 + ks * 64 + lane) * 8;         \
          fwh[jj] = *(const bf16x8*)&lds[(CUR) + 16384 + sl];          \
          fwl[jj] = *(const bf16x8*)&lds[(CUR) + 24576 + sl];          \
        }                                                              \
        _Pragma("unroll") for (int i = 0; i < 2; ++i)                  \
          _Pragma("unroll") for (int jj = 0; jj < 4; ++jj) {           \
            acc[i][jb * 4 + jj] = __builtin_amdgcn_mfma_f32_16x16x32_bf16( \
                fxh[i], fwh[jj], acc[i][jb * 4 + jj], 0, 0, 0);        \
            acc[i][jb * 4 + jj] = __builtin_amdgcn_mfma_f32_16x16x32_bf16( \
                fxh[i], fwl[jj], acc[i][jb * 4 + jj], 0, 0, 0);        \
            acc[i][jb * 4 + jj] = __builtin_amdgcn_mfma_f32_16x16x32_bf16( \
                fxl[i], fwh[jj], acc[i][jb * 4 + jj], 0, 0, 0);        \
          }                                                            \
      }                                                                \
    }                                                                  \
  }

  const int nk = K >> 6;  // K divisible by 64 everywhere (2048 / 4096)
  NN_STAGE(0, 0);
  for (int k = 0; k < nk; ++k) {
    const int cur = (k & 1) * 32768;
    const int nxt = 32768 - cur;
    // barrier #1: every wave finished its compute(k-1) reads of nxt.
    __builtin_amdgcn_s_barrier();
    __builtin_amdgcn_sched_barrier(0);
    if (k + 1 < nk) {
      NN_STAGE((k + 1) * 64, nxt);
      __builtin_amdgcn_sched_barrier(0);
      // own stage(k) landed (oldest 16 of 32); stage(k+1) stays in flight.
      asm volatile("s_waitcnt vmcnt(16)" ::: "memory");
    } else {
      asm volatile("s_waitcnt vmcnt(0)" ::: "memory");
    }
    // barrier #2: ALL waves' stage(k) landed -> cur fully populated.
    __builtin_amdgcn_s_barrier();
    __builtin_amdgcn_sched_barrier(0);
    NN_COMPUTE(cur);
  }
  __syncthreads();  // separate K-loop LDS reads from epilogue LDS writes
#undef NN_COMPUTE
#undef NN_STAGE

  const int qd = lane >> 4;
  const int nl = lane & 15;
  float pm = pmul;
  if (flags & FINVC) pm = pmul / scal[5];

#define NN_VAL(i, j, r, out)                           \
  {                                                    \
    int gi_ = I + w * 32 + (i)*16 + qd * 4 + (r);      \
    int gj_ = J + (j)*16 + nl;                         \
    out = pm * acc[i][j][r];                           \
    if (gi_ == gj_) out += diag;                       \
  }

  if (flags & FTRACE) {
    float ts = 0.f;
#pragma unroll
    for (int i = 0; i < 2; ++i)
#pragma unroll
      for (int j = 0; j < 8; ++j)
#pragma unroll
        for (int r = 0; r < 4; ++r) {
          int gi = I + w * 32 + i * 16 + qd * 4 + r;
          int gj = J + j * 16 + nl;
          if (gi == gj) {
            float v;
            NN_VAL(i, j, r, v);
            ts += v;
          }
        }
#pragma unroll
    for (int o = 32; o > 0; o >>= 1) ts += __shfl_down(ts, o, 64);
    float* red = (float*)lds;
    if (lane == 0) red[w] = ts;
    __syncthreads();
    if (tid == 0) atomicAdd(&scal[tidx], red[0] + red[1] + red[2] + red[3]);
    __syncthreads();
  }

  // dual-layout store via per-wave LDS transpose (wave region: 32x136 u16)
  const int wbp = w * 4352;
  for (int half = 0; half < 2; ++half) {
#pragma unroll
    for (int i = 0; i < 2; ++i)
#pragma unroll
      for (int j = 0; j < 8; ++j)
#pragma unroll
        for (int r = 0; r < 4; ++r) {
          float v;
          NN_VAL(i, j, r, v);
          u16 hv = f2bf(v);
          u16 sv = half ? f2bf(v - bf2f(hv)) : hv;
          lds[wbp + (i * 16 + qd * 4 + r) * 136 + j * 16 + nl] = sv;
        }
    __syncthreads();
    if (flags & FROW) {
      u16* dst = half ? Crl : Crh;
#pragma unroll
      for (int p2 = 0; p2 < 8; ++p2) {
        int rr = lane >> 1;
        int ch = (lane & 1) + p2 * 2;
        bf16x8 vv = *(const bf16x8*)&lds[wbp + rr * 136 + ch * 8];
        *(bf16x8*)(dst + (size_t)(I + w * 32 + rr) * D_DIM + J + ch * 8) = vv;
      }
    }
    if (flags & FCOL) {
      u16* dst = half ? Ccl : Cch;
#pragma unroll
      for (int jj = 0; jj < 8; ++jj) {
        int c = jj * 16 + (lane >> 2);
        int run = (lane & 3) * 8;
        u16 tp[8];
#pragma unroll
        for (int r2 = 0; r2 < 8; ++r2) tp[r2] = lds[wbp + (run + r2) * 136 + c];
        uint4 pk;
        pk.x = (u32)tp[0] | ((u32)tp[1] << 16);
        pk.y = (u32)tp[2] | ((u32)tp[3] << 16);
        pk.z = (u32)tp[4] | ((u32)tp[5] << 16);
        pk.w = (u32)tp[6] | ((u32)tp[7] << 16);
        *(uint4*)(dst + (size_t)(J + c) * D_DIM + I + w * 32 + run) = pk;
      }
    }
    __syncthreads();
  }
#undef NN_VAL
}

// plain GEMM over 256 tiles (16x16), XCD column-ownership swizzle
__global__ __launch_bounds__(256)
void k_nn(const u16* Xh, const u16* Xl, const u16* Wh, const u16* Wl, u16* Crh,
          u16* Crl, u16* Cch, u16* Ccl, float* scal, int K, float diag,
          float pmul, int flags, int tidx) {
  __shared__ u16 lds[65536];
  int bi, bj;
  swz256(blockIdx.x + (blockIdx.y << 4), bi, bj);
  nn_body(lds, Xh, Xl, Wh, Wl, Crh, Crl, Cch, Ccl, scal, K, diag, pmul, flags,
          tidx, bi, bj);
}

// both triangle grams in ONE launch: 272 blocks (2 x 136 lower-tri tiles)
// XCD-chunked swizzle: 272 % 8 == 0, each XCD gets 34 consecutive tri-tiles.
// Symmetric output: FROW fills C[I..][J..] (J<=I), FCOL fills C[J..][I..].
__global__ __launch_bounds__(256)
void k_nn_tri2(const u16* Xh0, const u16* Xl0, u16* Ch0, u16* Cl0,
               const u16* Xh1, const u16* Xl1, u16* Ch1, u16* Cl1,
               float* scal) {
  __shared__ u16 lds[65536];
  int x = blockIdx.x;
  int f5 = (x & 7) * 34 + (x >> 3);  // bijective on [0,272)
  int g = (f5 >= 136) ? 1 : 0;
  int f = f5 - g * 136;
  int bi = (int)((sqrtf(8.f * (float)f + 1.f) - 1.f) * 0.5f);
  while (bi * (bi + 1) / 2 > f) --bi;
  while ((bi + 1) * (bi + 2) / 2 <= f) ++bi;
  int bj = f - bi * (bi + 1) / 2;  // 0 <= bj <= bi
  if (g)
    nn_body(lds, Xh1, Xl1, Xh1, Xl1, Ch1, Cl1, Ch1, Cl1, scal, N_ROWS,
            EPS_DIAG, 1.0f, FROW | FCOL | FTRACE, 2, bi, bj);
  else
    nn_body(lds, Xh0, Xl0, Xh0, Xl0, Ch0, Cl0, Ch0, Cl0, scal, N_ROWS,
            EPS_DIAG, 1.0f, FROW | FCOL | FTRACE, 1, bi, bj);
}

// fused pair: grid (16,16,2)
struct NN2Args {
  const u16 *xh0, *xl0, *wh0, *wl0;
  u16 *crh0, *crl0, *cch0, *ccl0;
  const u16 *xh1, *xl1, *wh1, *wl1;
  u16 *crh1, *crl1, *cch1, *ccl1;
  float pm0, pm1;
};

__global__ __launch_bounds__(256)
void k_nn2(NN2Args a, float* scal) {
  __shared__ u16 lds[65536];
  int bi, bj;
  swz256(blockIdx.x + (blockIdx.y << 4), bi, bj);
  if (blockIdx.z == 0)
    nn_body(lds, a.xh0, a.xl0, a.wh0, a.wl0, a.crh0, a.crl0, a.cch0, a.ccl0,
            scal, D_DIM, 0.f, a.pm0, FROW | FCOL, 0, bi, bj);
  else
    nn_body(lds, a.xh1, a.xl1, a.wh1, a.wl1, a.crh1, a.crl1, a.cch1, a.ccl1,
            scal, D_DIM, 0.f, a.pm1, FROW | FCOL, 0, bi, bj);
}

// ---------------- power iteration (both chains fused) ----------------

__global__ __launch_bounds__(256)
void k_pones2(float* __restrict__ va, float* __restrict__ vb,
              float* __restrict__ snA, float* __restrict__ snB) {
  int t = blockIdx.x * 256 + threadIdx.x;  // 0..4095
  if (t < D_DIM)
    va[t] = 1.0f;
  else
    vb[t - D_DIM] = 1.0f;
  if (t == 0) {
    snA[0] = 1.0f;
    snB[0] = 1.0f;
  }
}

__global__ __launch_bounds__(256)
void k_gemv2(const u16* __restrict__ Ah, const u16* __restrict__ Bh,
             const float* viA, float* voA, const float* viB, float* voB,
             const float* snA, const float* snB, u32* smA, u32* smB) {
  const int zc = blockIdx.y;
  const u16* Mh = zc ? Bh : Ah;
  const float* vin = zc ? viB : viA;
  float* vout = zc ? voB : voA;
  const float* snorm = zc ? snB : snA;
  u32* smax = zc ? smB : smA;
  __shared__ float vs[D_DIM];
  float inv = 1.0f / snorm[0];
  for (int i = threadIdx.x; i < D_DIM; i += 256) vs[i] = vin[i] * inv;
  __syncthreads();
  int row = blockIdx.x * 4 + (threadIdx.x >> 6);
  int lane = threadIdx.x & 63;
  const u16* r = Mh + (size_t)row * D_DIM;
  float s = 0.f;
  for (int c0 = lane * 8; c0 < D_DIM; c0 += 512) {
    uint4 p = *(const uint4*)(r + c0);
    u32 w4[4] = {p.x, p.y, p.z, p.w};
#pragma unroll
    for (int q = 0; q < 4; ++q) {
      s += bf2f((u16)(w4[q] & 0xffff)) * vs[c0 + 2 * q];
      s += bf2f((u16)(w4[q] >> 16)) * vs[c0 + 2 * q + 1];
    }
  }
#pragma unroll
  for (int o = 32; o > 0; o >>= 1) s += __shfl_down(s, o, 64);
  if (lane == 0) {
    vout[row] = s;
    atomicMax(smax, __float_as_uint(fabsf(s)));
  }
}

__global__ void k_setc(float* scal) {
  scal[5] = 1.1f * scal[11] * scal[21];
}

// T1 = 3I - M/c in BOTH layouts (c = scal[5])
__global__ __launch_bounds__(256)
void k_t1(const u16* __restrict__ Mrh, const u16* __restrict__ Mrl,
          const u16* __restrict__ Mth, const u16* __restrict__ Mtl,
          const float* __restrict__ scal, u16* __restrict__ Trh,
          u16* __restrict__ Trl, u16* __restrict__ Tth, u16* __restrict__ Ttl) {
  size_t t = (size_t)blockIdx.x * 256 + threadIdx.x;
  float invc = 1.0f / scal[5];
  size_t e = t * 4;
  int i = (int)(e >> 11);
  int j0 = (int)(e & (D_DIM - 1));
#pragma unroll
  for (int pass = 0; pass < 2; ++pass) {
    const u16* sh = pass ? Mth : Mrh;
    const u16* sl = pass ? Mtl : Mrl;
    u16* dh = pass ? Tth : Trh;
    u16* dl = pass ? Ttl : Trl;
    uint2 hv = ((const uint2*)sh)[t];
    uint2 lv = ((const uint2*)sl)[t];
    u16 hs[4] = {(u16)(hv.x & 0xffff), (u16)(hv.x >> 16), (u16)(hv.y & 0xffff),
                 (u16)(hv.y >> 16)};
    u16 ls[4] = {(u16)(lv.x & 0xffff), (u16)(lv.x >> 16), (u16)(lv.y & 0xffff),
                 (u16)(lv.y >> 16)};
    u16 th[4], tl[4];
#pragma unroll
    for (int c = 0; c < 4; ++c) {
      float m = bf2f(hs[c]) + bf2f(ls[c]);
      float tv = ((i == j0 + c) ? 3.0f : 0.0f) - m * invc;
      th[c] = f2bf(tv);
      tl[c] = f2bf(tv - bf2f(th[c]));
    }
    ((uint2*)dh)[t] = make_uint2((u32)th[0] | ((u32)th[1] << 16),
                                 (u32)th[2] | ((u32)th[3] << 16));
    ((uint2*)dl)[t] = make_uint2((u32)tl[0] | ((u32)tl[1] << 16),
                                 (u32)tl[2] | ((u32)tl[3] << 16));
  }
}

__global__ __launch_bounds__(256)
void k_trdot(const u16* __restrict__ Ah, const u16* __restrict__ Al,
             const u16* __restrict__ Bh, const u16* __restrict__ Bl,
             double* __restrict__ acc) {
  size_t t = (size_t)blockIdx.x * 256 + threadIdx.x;
  uint2 ah = ((const uint2*)Ah)[t], al = ((const uint2*)Al)[t];
  uint2 bh = ((const uint2*)Bh)[t], bl = ((const uint2*)Bl)[t];
  float s = 0.f;
  u32 ha[4] = {ah.x & 0xffffu, ah.x >> 16, ah.y & 0xffffu, ah.y >> 16};
  u32 la[4] = {al.x & 0xffffu, al.x >> 16, al.y & 0xffffu, al.y >> 16};
  u32 hb[4] = {bh.x & 0xffffu, bh.x >> 16, bh.y & 0xffffu, bh.y >> 16};
  u32 lb[4] = {bl.x & 0xffffu, bl.x >> 16, bl.y & 0xffffu, bl.y >> 16};
#pragma unroll
  for (int c = 0; c < 4; ++c)
    s += (bf2f((u16)ha[c]) + bf2f((u16)la[c])) *
         (bf2f((u16)hb[c]) + bf2f((u16)lb[c]));
#pragma unroll
  for (int o = 32; o > 0; o >>= 1) s += __shfl_down(s, o, 64);
  __shared__ float red[4];
  if ((threadIdx.x & 63) == 0) red[threadIdx.x >> 6] = s;
  __syncthreads();
  if (threadIdx.x == 0)
    atomicAdd(acc, (double)(red[0] + red[1] + red[2] + red[3]));
}

__global__ void k_final2(const float* __restrict__ scal,
                         const double* __restrict__ dot,
                         float* __restrict__ out) {
  out[0] = scal[1] + scal[2] - sqrtf(scal[5]) * (float)dot[0];
}

// ================== FALLBACK PATH (round-4, 64MB-proven) ==================

__global__ __launch_bounds__(256)
void k_zsplit(const float* __restrict__ z, const float* __restrict__ mean,
              const float* __restrict__ rstd, u16* __restrict__ zh,
              u16* __restrict__ zl) {
  size_t t = (size_t)blockIdx.x * 256 + threadIdx.x;
  int ci = (int)(t & 511);
  float4 v = ((const float4*)z)[t];
  float4 m = ((const float4*)mean)[ci];
  float4 r = ((const float4*)rstd)[ci];
  float x[4] = {(v.x - m.x) * r.x, (v.y - m.y) * r.y, (v.z - m.z) * r.z,
                (v.w - m.w) * r.w};
  u16 h[4], l[4];
#pragma unroll
  for (int i = 0; i < 4; ++i) {
    h[i] = f2bf(x[i]);
    l[i] = f2bf(x[i] - bf2f(h[i]));
  }
  ((uint2*)zh)[t] = make_uint2((u32)h[0] | ((u32)h[1] << 16),
                               (u32)h[2] | ((u32)h[3] << 16));
  ((uint2*)zl)[t] = make_uint2((u32)l[0] | ((u32)l[1] << 16),
                               (u32)l[2] | ((u32)l[3] << 16));
}

__global__ __launch_bounds__(256)
void k_gram_mm(const u16* __restrict__ zh, const u16* __restrict__ zl,
               u16* __restrict__ Oh, u16* __restrict__ Ol) {
  __shared__ u16 lds[24576];
  const int tid = threadIdx.x;
  const int lane = tid & 63;
  const int w = tid >> 6;
  const int I = blockIdx.y * 128;
  const int J = blockIdx.x * 64;
  const int kp = tid >> 4;
  const int nc = tid & 15;
  const int qq = kp >> 2;
  const int kd = (kp & 3) * 2;
  const size_t aro = (size_t)(2 * kp) * D_DIM + I + nc * 8;
  const size_t bro = (size_t)(2 * kp) * D_DIM + J + nc * 4;
  union U4 { uint4 v; u16 s[8]; };
  union U2 { uint2 v; u16 s[4]; };
  U4 ah0, ah1, al0, al1;
  U2 bh0, bh1, bl0, bl1;
  f32x4 acc[2][4];
#pragma unroll
  for (int i = 0; i < 2; ++i)
#pragma unroll
    for (int j = 0; j < 4; ++j) acc[i][j] = (f32x4){0.f, 0.f, 0.f, 0.f};
#define GRAM_LOAD(k1)                         \
  {                                           \
    size_t ao = aro + (size_t)(k1)*D_DIM;     \
    size_t bo = bro + (size_t)(k1)*D_DIM;     \
    ah0.v = *(const uint4*)(zh + ao);         \
    ah1.v = *(const uint4*)(zh + ao + D_DIM); \
    al0.v = *(const uint4*)(zl + ao);         \
    al1.v = *(const uint4*)(zl + ao + D_DIM); \
    bh0.v = *(const uint2*)(zh + bo);         \
    bh1.v = *(const uint2*)(zh + bo + D_DIM); \
    bl0.v = *(const uint2*)(zl + bo);         \
    bl1.v = *(const uint2*)(zl + bo + D_DIM); \
  }
#define GRAM_PACK(buf)                                                       \
  {                                                                          \
    _Pragma("unroll") for (int j = 0; j < 8; ++j) {                          \
      int mc = nc * 8 + j;                                                   \
      int t2 = mc >> 4, ml = mc & 15;                                        \
      int slot = (t2 * 64 + qq * 16 + ml) ^ t2;                              \
      *(u32*)&lds[(buf) + slot * 8 + kd] =                                   \
          (u32)ah0.s[j] | ((u32)ah1.s[j] << 16);                             \
      *(u32*)&lds[(buf) + 4096 + slot * 8 + kd] =                            \
          (u32)al0.s[j] | ((u32)al1.s[j] << 16);                             \
    }                                                                        \
    _Pragma("unroll") for (int j = 0; j < 4; ++j) {                          \
      int n = nc * 4 + j;                                                    \
      int u = n >> 4, nl = n & 15;                                           \
      int slot = (u * 64 + qq * 16 + nl) ^ u;                                \
      *(u32*)&lds[(buf) + 8192 + slot * 8 + kd] =                            \
          (u32)bh0.s[j] | ((u32)bh1.s[j] << 16);                             \
      *(u32*)&lds[(buf) + 10240 + slot * 8 + kd] =                           \
          (u32)bl0.s[j] | ((u32)bl1.s[j] << 16);                             \
    }                                                                        \
  }
  GRAM_LOAD(0);
  GRAM_PACK(0);
  __syncthreads();
  for (int k = 0; k < N_ROWS / 32; ++k) {
    const int cur = (k & 1) * 12288;
    const int nxt = 12288 - cur;
    if (k < N_ROWS / 32 - 1) GRAM_LOAD((k + 1) * 32);
    bf16x8 fah[2], fal[2], fbh[4], fbl[4];
#pragma unroll
    for (int i = 0; i < 2; ++i) {
      int t2 = w * 2 + i;
      int sl = (t2 * 64 + lane) ^ t2;
      fah[i] = *(const bf16x8*)&lds[cur + sl * 8];
      fal[i] = *(const bf16x8*)&lds[cur + 4096 + sl * 8];
    }
#pragma unroll
    for (int j = 0; j < 4; ++j) {
      int sl = (j * 64 + lane) ^ j;
      fbh[j] = *(const bf16x8*)&lds[cur + 8192 + sl * 8];
      fbl[j] = *(const bf16x8*)&lds[cur + 10240 + sl * 8];
    }
#pragma unroll
    for (int i = 0; i < 2; ++i)
#pragma unroll
      for (int j = 0; j < 4; ++j) {
        acc[i][j] = __builtin_amdgcn_mfma_f32_16x16x32_bf16(fah[i], fbh[j],
                                                            acc[i][j], 0, 0, 0);
        acc[i][j] = __builtin_amdgcn_mfma_f32_16x16x32_bf16(fah[i], fbl[j],
                                                            acc[i][j], 0, 0, 0);
        acc[i][j] = __builtin_amdgcn_mfma_f32_16x16x32_bf16(fal[i], fbh[j],
                                                            acc[i][j], 0, 0, 0);
      }
    if (k < N_ROWS / 32 - 1) GRAM_PACK(nxt);
    __syncthreads();
  }
  const int qd = lane >> 4;
  const int nl = lane & 15;
#pragma unroll
  for (int i = 0; i < 2; ++i)
#pragma unroll
    for (int j = 0; j < 4; ++j)
#pragma unroll
      for (int r = 0; r < 4; ++r) {
        int gi = I + w * 32 + i * 16 + qd * 4 + r;
        int gj = J + j * 16 + nl;
        float v = acc[i][j][r] + ((gi == gj) ? EPS_DIAG : 0.f);
        u16 h = f2bf(v);
        u16 l = f2bf(v - bf2f(h));
        Oh[(size_t)gi * D_DIM + gj] = h;
        Ol[(size_t)gi * D_DIM + gj] = l;
      }
#undef GRAM_LOAD
#undef GRAM_PACK
}

template <int MODE>
__global__ __launch_bounds__(256)
void k_mm(const u16* __restrict__ Ph, const u16* __restrict__ Pl,
          const u16* __restrict__ Qh, const u16* __restrict__ Ql,
          u16* __restrict__ Ch, u16* __restrict__ Cl,
          const float* __restrict__ scal) {
  __shared__ u16 lds[24576];
  const int tid = threadIdx.x;
  const int lane = tid & 63;
  const int w = tid >> 6;
  const int I = blockIdx.y * 128;
  const int J = blockIdx.x * 64;
  const int kp = tid >> 4;
  const int nc = tid & 15;
  const int qq = kp >> 2;
  const int kd = (kp & 3) * 2;
  size_t aro[2];
  int acl[2], abase[2];
#pragma unroll
  for (int p = 0; p < 2; ++p) {
    int s = p * 256 + w * 64 + lane;
    aro[p] = (size_t)(I + (s >> 6) * 16 + (s & 15)) * D_DIM;
    acl[p] = ((s >> 4) & 3) * 8;
    abase[p] = (p * 256 + w * 64) * 8;
  }
  const size_t bro = (size_t)(2 * kp) * D_DIM + J + nc * 4;
  union U2 { uint2 v; u16 s[4]; };
  U2 bh0, bh1, bl0, bl1;
  f32x4 acc[2][4];
#pragma unroll
  for (int i = 0; i < 2; ++i)
#pragma unroll
    for (int j = 0; j < 4; ++j) acc[i][j] = (f32x4){0.f, 0.f, 0.f, 0.f};
#define MM_STAGE_A(k1, buf)                                              \
  {                                                                      \
    _Pragma("unroll") for (int p = 0; p < 2; ++p) {                      \
      GLD16(Ph + aro[p] + (k1) + acl[p], &lds[(buf) + abase[p]]);        \
      GLD16(Pl + aro[p] + (k1) + acl[p], &lds[(buf) + 4096 + abase[p]]); \
    }                                                                    \
  }
#define MM_LOAD_B(k1)                         \
  {                                           \
    size_t bo = bro + (size_t)(k1)*D_DIM;     \
    bh0.v = *(const uint2*)(Qh + bo);         \
    bh1.v = *(const uint2*)(Qh + bo + D_DIM); \
    bl0.v = *(const uint2*)(Ql + bo);         \
    bl1.v = *(const uint2*)(Ql + bo + D_DIM); \
  }
#define MM_PACK_B(buf)                                                       \
  {                                                                          \
    _Pragma("unroll") for (int j = 0; j < 4; ++j) {                          \
      int n = nc * 4 + j;                                                    \
      int u = n >> 4, nl2 = n & 15;                                          \
      int slot = (u * 64 + qq * 16 + nl2) ^ u;                               \
      *(u32*)&lds[(buf) + 8192 + slot * 8 + kd] =                            \
          (u32)bh0.s[j] | ((u32)bh1.s[j] << 16);                             \
      *(u32*)&lds[(buf) + 10240 + slot * 8 + kd] =                           \
          (u32)bl0.s[j] | ((u32)bl1.s[j] << 16);                             \
    }                                                                        \
  }
  MM_STAGE_A(0, 0);
  MM_LOAD_B(0);
  MM_PACK_B(0);
  __syncthreads();
  for (int k = 0; k < D_DIM / 32; ++k) {
    const int cur = (k & 1) * 12288;
    const int nxt = 12288 - cur;
    if (k < D_DIM / 32 - 1) {
      MM_STAGE_A((k + 1) * 32, nxt);
      MM_LOAD_B((k + 1) * 32);
    }
    bf16x8 fah[2], fal[2], fbh[4], fbl[4];
#pragma unroll
    for (int i = 0; i < 2; ++i) {
      int t2 = w * 2 + i;
      fah[i] = *(const bf16x8*)&lds[cur + (t2 * 64 + lane) * 8];
      fal[i] = *(const bf16x8*)&lds[cur + 4096 + (t2 * 64 + lane) * 8];
    }
#pragma unroll
    for (int j = 0; j < 4; ++j) {
      int sl = (j * 64 + lane) ^ j;
      fbh[j] = *(const bf16x8*)&lds[cur + 8192 + sl * 8];
      fbl[j] = *(const bf16x8*)&lds[cur + 10240 + sl * 8];
    }
#pragma unroll
    for (int i = 0; i < 2; ++i)
#pragma unroll
      for (int j = 0; j < 4; ++j) {
        acc[i][j] = __builtin_amdgcn_mfma_f32_16x16x32_bf16(fah[i], fbh[j],
                                                            acc[i][j], 0, 0, 0);
        acc[i][j] = __builtin_amdgcn_mfma_f32_16x16x32_bf16(fah[i], fbl[j],
                                                            acc[i][j], 0, 0, 0);
        acc[i][j] = __builtin_amdgcn_mfma_f32_16x16x32_bf16(fal[i], fbh[j],
                                                            acc[i][j], 0, 0, 0);
      }
    if (k < D_DIM / 32 - 1) MM_PACK_B(nxt);
    __syncthreads();
  }
  float mul = (MODE == 2) ? 0.5f : 1.0f;
  if (MODE == 3) mul = 0.5f / sqrtf(scal[0]);
  const int qd = lane >> 4;
  const int nl = lane & 15;
#pragma unroll
  for (int i = 0; i < 2; ++i)
#pragma unroll
    for (int j = 0; j < 4; ++j)
#pragma unroll
      for (int r = 0; r < 4; ++r) {
        int gi = I + w * 32 + i * 16 + qd * 4 + r;
        int gj = J + j * 16 + nl;
        float v = acc[i][j][r];
        if (MODE == 1)
          v = ((gi == gj) ? 3.0f : 0.0f) - v;
        else
          v *= mul;
        u16 h = f2bf(v);
        u16 l = f2bf(v - bf2f(h));
        Ch[(size_t)gi * D_DIM + gj] = h;
        Cl[(size_t)gi * D_DIM + gj] = l;
      }
#undef MM_STAGE_A
#undef MM_LOAD_B
#undef MM_PACK_B
}

__global__ __launch_bounds__(256)
void k_frob_hl(const u16* __restrict__ mh, const u16* __restrict__ ml,
               float* __restrict__ c2) {
  size_t t = (size_t)blockIdx.x * 256 + threadIdx.x;
  uint2 hv = ((const uint2*)mh)[t];
  uint2 lv = ((const uint2*)ml)[t];
  float v0 = bf2f((u16)(hv.x & 0xffff)) + bf2f((u16)(lv.x & 0xffff));
  float v1 = bf2f((u16)(hv.x >> 16)) + bf2f((u16)(lv.x >> 16));
  float v2 = bf2f((u16)(hv.y & 0xffff)) + bf2f((u16)(lv.y & 0xffff));
  float v3 = bf2f((u16)(hv.y >> 16)) + bf2f((u16)(lv.y >> 16));
  float q = v0 * v0 + v1 * v1 + v2 * v2 + v3 * v3;
#pragma unroll
  for (int o = 32; o > 0; o >>= 1) q += __shfl_down(q, o, 64);
  __shared__ float red[4];
  if ((threadIdx.x & 63) == 0) red[threadIdx.x >> 6] = q;
  __syncthreads();
  if (threadIdx.x == 0) atomicAdd(c2, red[0] + red[1] + red[2] + red[3]);
}

__global__ __launch_bounds__(256)
void k_t1z1(const u16* __restrict__ Mh, const u16* __restrict__ Ml,
            const float* __restrict__ scal, u16* __restrict__ Th,
            u16* __restrict__ Tl, u16* __restrict__ Zh, u16* __restrict__ Zl) {
  size_t t = (size_t)blockIdx.x * 256 + threadIdx.x;
  float invc = 1.0f / sqrtf(scal[0]);
  size_t e = t * 4;
  int i = (int)(e >> 11);
  int j0 = (int)(e & (D_DIM - 1));
  uint2 hv = ((const uint2*)Mh)[t];
  uint2 lv = ((const uint2*)Ml)[t];
  u16 hs[4] = {(u16)(hv.x & 0xffff), (u16)(hv.x >> 16), (u16)(hv.y & 0xffff),
               (u16)(hv.y >> 16)};
  u16 ls[4] = {(u16)(lv.x & 0xffff), (u16)(lv.x >> 16), (u16)(lv.y & 0xffff),
               (u16)(lv.y >> 16)};
  u16 th[4], tl[4], zh[4], zl[4];
#pragma unroll
  for (int c = 0; c < 4; ++c) {
    float m = bf2f(hs[c]) + bf2f(ls[c]);
    float tv = ((i == j0 + c) ? 3.0f : 0.0f) - m * invc;
    th[c] = f2bf(tv);
    tl[c] = f2bf(tv - bf2f(th[c]));
    float zv = 0.5f * tv;
    zh[c] = f2bf(zv);
    zl[c] = f2bf(zv - bf2f(zh[c]));
  }
  ((uint2*)Th)[t] = make_uint2((u32)th[0] | ((u32)th[1] << 16),
                               (u32)th[2] | ((u32)th[3] << 16));
  ((uint2*)Tl)[t] = make_uint2((u32)tl[0] | ((u32)tl[1] << 16),
                               (u32)tl[2] | ((u32)tl[3] << 16));
  ((uint2*)Zh)[t] = make_uint2((u32)zh[0] | ((u32)zh[1] << 16),
                               (u32)zh[2] | ((u32)zh[3] << 16));
  ((uint2*)Zl)[t] = make_uint2((u32)zl[0] | ((u32)zl[1] << 16),
                               (u32)zl[2] | ((u32)zl[3] << 16));
}

__global__ __launch_bounds__(256)
void k_trace_hl(const u16* __restrict__ mh, const u16* __restrict__ ml,
                float* __restrict__ out) {
  __shared__ float red[256];
  float s = 0.f;
  for (int i = threadIdx.x; i < D_DIM; i += 256) {
    size_t d = (size_t)i * (D_DIM + 1);
    s += bf2f(mh[d]) + bf2f(ml[d]);
  }
  red[threadIdx.x] = s;
  __syncthreads();
  for (int o = 128; o > 0; o >>= 1) {
    if (threadIdx.x < o) red[threadIdx.x] += red[threadIdx.x + o];
    __syncthreads();
  }
  if (threadIdx.x == 0) out[0] = red[0];
}

__global__ __launch_bounds__(256)
void k_final(const u16* __restrict__ Yh, const u16* __restrict__ Yl,
             const float* __restrict__ scal, float* __restrict__ out) {
  __shared__ float red[256];
  float s = 0.f;
  for (int i = threadIdx.x; i < D_DIM; i += 256) {
    size_t d = (size_t)i * (D_DIM + 1);
    s += bf2f(Yh[d]) + bf2f(Yl[d]);
  }
  red[threadIdx.x] = s;
  __syncthreads();
  for (int o = 128; o > 0; o >>= 1) {
    if (threadIdx.x < o) red[threadIdx.x] += red[threadIdx.x + o];
    __syncthreads();
  }
  if (threadIdx.x == 0) {
    float sqrtc = sqrtf(sqrtf(scal[0]));
    out[0] = scal[1] + scal[2] - 2.0f * sqrtc * red[0];
  }
}

// ---------------- launch ----------------

extern "C" void kernel_launch(void* const* d_in, const int* in_sizes, int n_in,
                              void* d_out, int out_size, void* d_ws,
                              size_t ws_size, hipStream_t stream) {
  (void)in_sizes; (void)n_in; (void)out_size;
  const float* za = (const float*)d_in[0];
  const float* zb = (const float*)d_in[1];
  float* out = (float*)d_out;
  float* ws = (float*)d_ws;
  float* stat = ws;
  float* scal = ws + 4 * D_DIM;

  hipMemsetAsync(ws, 0, (4 * D_DIM + 32) * sizeof(float), stream);
  dim3 blk(256);

  const size_t NEED = 65536ull + 8ull * 16 * 1024 * 1024;
  if (ws_size >= NEED) {
    // ================= FAST PATH =================
    char* pool = (char*)d_ws + 65536;
    auto uh = [&](int u) { return (u16*)(pool + (size_t)u * 16777216); };
    auto ul = [&](int u) {
      return (u16*)(pool + (size_t)u * 16777216 + 8388608);
    };
    // z-split A: whole U0 (h) + whole U1 (l); B: whole U4 + whole U5
    u16* ZhA = (u16*)(pool);
    u16* ZlA = (u16*)(pool + 1ull * 16777216);
    u16* ZhB = (u16*)(pool + 4ull * 16777216);
    u16* ZlB = (u16*)(pool + 5ull * 16777216);
    dim3 gm(16, 16);

    k_colstats2<<<dim3(8, 16, 2), blk, 0, stream>>>(za, zb, stat);
    k_finalize_stats<<<16, blk, 0, stream>>>(stat);
    k_zsplit_t2<<<dim3(64, 32, 2), blk, 0, stream>>>(za, zb, stat, ZhA, ZlA,
                                                     ZhB, ZlB);
    // both grams, one launch: A -> U2 (trace scal[1]), B -> U3 (scal[2])
    k_nn_tri2<<<272, blk, 0, stream>>>(ZhA, ZlA, uh(2), ul(2), ZhB, ZlB,
                                       uh(3), ul(3), scal);

    // paired power iteration: lambda_max(A)->scal[11], lambda_max(B)->scal[21]
    k_pones2<<<16, blk, 0, stream>>>(stat, stat + 2 * D_DIM, scal + 6,
                                     scal + 16);
    for (int s = 0; s < 5; ++s) {
      const float* viA = (s & 1) ? stat + D_DIM : stat;
      float* voA = (s & 1) ? stat : stat + D_DIM;
      const float* viB = (s & 1) ? stat + 3 * D_DIM : stat + 2 * D_DIM;
      float* voB = (s & 1) ? stat + 2 * D_DIM : stat + 3 * D_DIM;
      k_gemv2<<<dim3(512, 2), blk, 0, stream>>>(
          uh(2), uh(3), viA, voA, viB, voB, scal + 6 + s, scal + 16 + s,
          (u32*)(scal + 7 + s), (u32*)(scal + 17 + s));
    }
    k_setc<<<1, 1, 0, stream>>>(scal);

    // M = A*B -> row U4, col U5 (zsplit-B dead; B symmetric => W=B row)
    k_nn<<<gm, blk, 0, stream>>>(uh(2), ul(2), uh(3), ul(3), uh(4), ul(4),
                                 uh(5), ul(5), scal, D_DIM, 0.f, 1.0f,
                                 FROW | FCOL, 0);
    // T1 = 3I - M/c -> row U6, col U7
    k_t1<<<4096, blk, 0, stream>>>(uh(4), ul(4), uh(5), ul(5), scal, uh(6),
                                   ul(6), uh(7), ul(7));
    // Y1 = (0.5/c) M*T1 -> row U0, col U1 (zsplit-A dead)
    k_nn<<<gm, blk, 0, stream>>>(uh(4), ul(4), uh(7), ul(7), uh(0), ul(0),
                                 uh(1), ul(1), scal, D_DIM, 0.f, 0.5f,
                                 FROW | FCOL | FINVC, 0);
    // T2 = 3I - 0.5*T1*Y1 -> row U4, col U5 (M dead; Z1 = T1/2 implicit)
    k_nn<<<gm, blk, 0, stream>>>(uh(6), ul(6), uh(1), ul(1), uh(4), ul(4),
                                 uh(5), ul(5), scal, D_DIM, 3.f, -0.5f,
                                 FROW | FCOL, 0);
    // fused: Y2 = 0.5*Y1*T2 -> U1(row),U2(col) ; Z2 = 0.25*T2*T1 -> U3,U6
    {
      NN2Args a;
      a.xh0 = uh(0); a.xl0 = ul(0); a.wh0 = uh(5); a.wl0 = ul(5);
      a.crh0 = uh(1); a.crl0 = ul(1); a.cch0 = uh(2); a.ccl0 = ul(2);
      a.pm0 = 0.5f;
      a.xh1 = uh(4); a.xl1 = ul(4); a.wh1 = uh(7); a.wl1 = ul(7);
      a.crh1 = uh(3); a.crl1 = ul(3); a.cch1 = uh(6); a.ccl1 = ul(6);
      a.pm1 = 0.25f;
      k_nn2<<<dim3(16, 16, 2), blk, 0, stream>>>(a, scal);
    }
    int Yr = 1, Yt = 2, Zr = 3, Zt = 6;
    int fr0 = 0, fr1 = 4, fr2 = 5, fr3 = 7;
    for (int it = 3; it <= 10; ++it) {
      // T = 3I - Z*Y -> row fr0, col fr1
      k_nn<<<gm, blk, 0, stream>>>(uh(Zr), ul(Zr), uh(Yt), ul(Yt), uh(fr0),
                                   ul(fr0), uh(fr1), ul(fr1), scal, D_DIM, 3.f,
                                   -1.f, FROW | FCOL, 0);
      // fused: Yn = 0.5*Y*T -> fr2,fr3 ; Zn = 0.5*T*Z -> Yt,Zr (dead units)
      NN2Args a;
      a.xh0 = uh(Yr); a.xl0 = ul(Yr); a.wh0 = uh(fr1); a.wl0 = ul(fr1);
      a.crh0 = uh(fr2); a.crl0 = ul(fr2); a.cch0 = uh(fr3); a.ccl0 = ul(fr3);
      a.pm0 = 0.5f;
      a.xh1 = uh(fr0); a.xl1 = ul(fr0); a.wh1 = uh(Zt); a.wl1 = ul(Zt);
      a.crh1 = uh(Yt); a.crl1 = ul(Yt); a.cch1 = uh(Zr); a.ccl1 = ul(Zr);
      a.pm1 = 0.5f;
      k_nn2<<<dim3(16, 16, 2), blk, 0, stream>>>(a, scal);
      int nYr = fr2, nYt = fr3, nZr = Yt, nZt = Zr;
      int nf0 = Yr, nf1 = Zt, nf2 = fr0, nf3 = fr1;
      Yr = nYr; Yt = nYt; Zr = nZr; Zt = nZt;
      fr0 = nf0; fr1 = nf1; fr2 = nf2; fr3 = nf3;
    }
    // step 11: T11 col-only -> fr0 ; trY11 = 0.5*dot(Y10 row, T11 col)
    k_nn<<<gm, blk, 0, stream>>>(uh(Zr), ul(Zr), uh(Yt), ul(Yt), uh(fr1),
                                 ul(fr1), uh(fr0), ul(fr0), scal, D_DIM, 3.f,
                                 -1.f, FCOL, 0);
    k_trdot<<<4096, blk, 0, stream>>>(uh(Yr), ul(Yr), uh(fr0), ul(fr0),
                                      (double*)(scal + 24));
    k_final2<<<1, 1, 0, stream>>>(scal, (const double*)(scal + 24), out);
    return;
  }

  // ================= FALLBACK (round-4, 64MB) =================
  k_colstats2<<<dim3(8, 16, 2), blk, 0, stream>>>(za, zb, stat);
  k_finalize_stats<<<16, blk, 0, stream>>>(stat);
  u16* b[8];
  {
    char* pool = (char*)d_ws + 65536;
    for (int i = 0; i < 8; ++i) b[i] = (u16*)(pool + (size_t)i * 8388608);
  }
#define PH(p) b[2 * (p)]
#define PL(p) b[2 * (p) + 1]
  u16* zh = b[4];
  u16* zl = b[6];
  dim3 gm(32, 16);
  k_zsplit<<<8192, blk, 0, stream>>>(za, stat, stat + D_DIM, zh, zl);
  k_gram_mm<<<gm, blk, 0, stream>>>(zh, zl, PH(0), PL(0));
  k_zsplit<<<8192, blk, 0, stream>>>(zb, stat + 2 * D_DIM, stat + 3 * D_DIM,
                                     zh, zl);
  k_gram_mm<<<gm, blk, 0, stream>>>(zh, zl, PH(1), PL(1));
  k_trace_hl<<<1, blk, 0, stream>>>(PH(0), PL(0), scal + 1);
  k_trace_hl<<<1, blk, 0, stream>>>(PH(1), PL(1), scal + 2);
  k_mm<0><<<gm, blk, 0, stream>>>(PH(0), PL(0), PH(1), PL(1), PH(2), PL(2),
                                  scal);
  k_frob_hl<<<4096, blk, 0, stream>>>(PH(2), PL(2), scal);
  k_t1z1<<<4096, blk, 0, stream>>>(PH(2), PL(2), scal, PH(0), PL(0), PH(1),
                                   PL(1));
  k_mm<3><<<gm, blk, 0, stream>>>(PH(2), PL(2), PH(0), PL(0), PH(3), PL(3),
                                  scal);
  int Y = 3, Z = 1, fA = 0, fB = 2;
  for (int it = 2; it <= NS_ITERS; ++it) {
    k_mm<1><<<gm, blk, 0, stream>>>(PH(Z), PL(Z), PH(Y), PL(Y), PH(fA), PL(fA),
                                    scal);
    k_mm<2><<<gm, blk, 0, stream>>>(PH(Y), PL(Y), PH(fA), PL(fA), PH(fB),
                                    PL(fB), scal);
    if (it < NS_ITERS)
      k_mm<2><<<gm, blk, 0, stream>>>(PH(fA), PL(fA), PH(Z), PL(Z), PH(Y),
                                      PL(Y), scal);
    int oy = Y, oz = Z, oa = fA, ob = fB;
    Y = ob; Z = oy; fA = oz; fB = oa;
  }
  k_final<<<1, blk, 0, stream>>>(PH(Y), PL(Y), scal, out);
#undef PH
#undef PL
}

// Round 8
// 2415.033 us; speedup vs baseline: 1.2040x; 1.2040x over previous
//
#include <hip/hip_runtime.h>
#include <math.h>

typedef unsigned short u16;
typedef unsigned int u32;

#define D_DIM 2048
#define N_ROWS 4096
#define EPS_DIAG 1e-3f
#define NS_ITERS 16  // fallback path only

typedef __attribute__((ext_vector_type(8))) short bf16x8;
typedef __attribute__((ext_vector_type(4))) float f32x4;

__device__ __forceinline__ u16 f2bf(float f) {
  u32 u = __float_as_uint(f);
  u += 0x7fffu + ((u >> 16) & 1u);
  return (u16)(u >> 16);
}
__device__ __forceinline__ float bf2f(u16 h) {
  return __uint_as_float(((u32)h) << 16);
}

#define GLD16(g, l)                                        \
  __builtin_amdgcn_global_load_lds(                        \
      (const __attribute__((address_space(1))) void*)(g),  \
      (__attribute__((address_space(3))) void*)(l), 16, 0, 0)

// ---------------------------------------------------------------------------
// SWIZZLED GLOBAL LAYOUT (fast path only): every GEMM operand array is
// row-major [r][K] where, within each 64-element k-block, the 16B chunk c
// (8 bf16) of row r is stored at slot c ^ (r & 7). Producers write with the
// XOR; global_load_lds copies rows linearly (adjacent lanes CONTIGUOUS ->
// coalesced requests, the round-7 diagnosis); ds_reads apply the same XOR
// (2 lanes/bank = conflict-free). Elementwise consumers compensate.
// swizzled flat minor position of logical minor u, given major r:
//   pos(u,r) = (u & ~63) | (((u>>3 & 7) ^ (r & 7)) << 3) | (u & 7)
// ---------------------------------------------------------------------------

// scal layout (floats): [1]=trA [2]=trB [5]=c  [6..11]=powerA  [16..21]=powerB
// [24..25] = trdot double accumulator

// XCD column-ownership swizzle for 256-tile grids (16 bi x 16 bj).
__device__ __forceinline__ void swz256(int id, int& bi, int& bj) {
  int s = id & 7;   // XCD (dispatch round-robin)
  int j = id >> 3;  // 0..31 within XCD
  bj = s * 2 + (j & 1);
  bi = j >> 1;
}

// ---------------- column statistics (both inputs, one launch) ----------------

__global__ __launch_bounds__(256)
void k_colstats2(const float* __restrict__ za, const float* __restrict__ zb,
                 float* __restrict__ stat) {
  const float* z = blockIdx.z ? zb : za;
  float* sum_ = stat + blockIdx.z * 2 * D_DIM;
  float* ssq_ = sum_ + D_DIM;
  const int c = blockIdx.x * 256 + threadIdx.x;
  const int r0 = blockIdx.y * (N_ROWS / 16);
  float s = 0.f, q = 0.f;
#pragma unroll 8
  for (int r = 0; r < N_ROWS / 16; ++r) {
    float v = z[(size_t)(r0 + r) * D_DIM + c];
    s += v;
    q += v * v;
  }
  atomicAdd(&sum_[c], s);
  atomicAdd(&ssq_[c], q);
}

__global__ __launch_bounds__(256)
void k_finalize_stats(float* stat) {
  const int t = blockIdx.x * 256 + threadIdx.x;
  const int g = t >> 11;
  const int c = t & (D_DIM - 1);
  float* base = stat + g * 2 * D_DIM;
  float s = base[c];
  float q = base[D_DIM + c];
  float mean = s * (1.0f / N_ROWS);
  float var = (q - (float)N_ROWS * mean * mean) * (1.0f / (N_ROWS - 1));
  var = fmaxf(var, 1e-30f);
  base[c] = mean;
  base[D_DIM + c] = 1.0f / sqrtf(var);
}

// ================== FAST PATH (needs 128MB + 64KB workspace) ==================

// standardize + split + TRANSPOSE both inputs: z[N][D] -> Zt[D][N] bf16 h/l
// Output is SWIZZLED row-major [d][N] (chunk XOR by d&7).
__global__ __launch_bounds__(256)
void k_zsplit_t2(const float* __restrict__ za, const float* __restrict__ zb,
                 const float* __restrict__ stat, u16* __restrict__ Zh0,
                 u16* __restrict__ Zl0, u16* __restrict__ Zh1,
                 u16* __restrict__ Zl1) {
  __shared__ float T[64 * 72];
  const float* z = blockIdx.z ? zb : za;
  const float* mean = stat + blockIdx.z * 2 * D_DIM;
  const float* rstd = mean + D_DIM;
  u16* Zth = blockIdx.z ? Zh1 : Zh0;
  u16* Ztl = blockIdx.z ? Zl1 : Zl0;
  const int t = threadIdx.x;
  const int r0 = blockIdx.x * 64;
  const int c0 = blockIdx.y * 64;
#pragma unroll
  for (int p = 0; p < 4; ++p) {
    int row = p * 16 + (t >> 4);
    int c4 = t & 15;
    float4 v = *(const float4*)(z + (size_t)(r0 + row) * D_DIM + c0 + c4 * 4);
    *(float4*)&T[row * 72 + c4 * 4] = v;
  }
  __syncthreads();
  const int c = c0 + (t >> 2);
  const float m = mean[c];
  const float r = rstd[c];
  const int cc = t >> 2;
#pragma unroll
  for (int g = 0; g < 2; ++g) {
    int rbase = g * 32 + (t & 3) * 8;
    u16 hs[8], ls[8];
#pragma unroll
    for (int i = 0; i < 8; ++i) {
      float x = (T[(rbase + i) * 72 + cc] - m) * r;
      hs[i] = f2bf(x);
      ls[i] = f2bf(x - bf2f(hs[i]));
    }
    uint4 ph, pl;
    ph.x = (u32)hs[0] | ((u32)hs[1] << 16);
    ph.y = (u32)hs[2] | ((u32)hs[3] << 16);
    ph.z = (u32)hs[4] | ((u32)hs[5] << 16);
    ph.w = (u32)hs[6] | ((u32)hs[7] << 16);
    pl.x = (u32)ls[0] | ((u32)ls[1] << 16);
    pl.y = (u32)ls[2] | ((u32)ls[3] << 16);
    pl.z = (u32)ls[4] | ((u32)ls[5] << 16);
    pl.w = (u32)ls[6] | ((u32)ls[7] << 16);
    int n = r0 + rbase;  // multiple of 8
    int slot = ((n >> 3) & 7) ^ (c & 7);
    size_t o = (size_t)c * N_ROWS + (size_t)((n & ~63) | (slot << 3));
    *(uint4*)(Zth + o) = ph;
    *(uint4*)(Ztl + o) = pl;
  }
}

#define FINVC 1
#define FTRACE 4
#define FCOL 8
#define FROW 16

// Unified split-bf16 MFMA GEMM body: C = diag*I + pm*(X * W^T).
// 128x128 tile, BK=64. COALESCED staging: GLD16 p stages 8 rows x 128B,
// lane L -> row +(L>>3), 16B chunk (L&7); adjacent lanes contiguous.
// Arrays are pre-swizzled (see header) so the linear LDS image is
// [row][64] with chunk XOR; ds_reads apply the same XOR (2/bank free).
// Schedule (race-free per round 4):
//   barrier#1 -> STAGE(k+1)->nxt -> vmcnt(16) -> barrier#2 -> compute(cur)
// LDS 2 x 64KB = 128KB -> 1 block/CU.
__device__ __forceinline__ void nn_body(
    u16* lds, const u16* __restrict__ Xh, const u16* __restrict__ Xl,
    const u16* __restrict__ Wh, const u16* __restrict__ Wl,
    u16* __restrict__ Crh, u16* __restrict__ Crl, u16* __restrict__ Cch,
    u16* __restrict__ Ccl, float* __restrict__ scal, int K, float diag,
    float pmul, int flags, int tidx, int bi, int bj) {
  const int tid = threadIdx.x;
  const int lane = tid & 63;
  const int w = tid >> 6;
  const int I = bi * 128;
  const int J = bj * 128;

  // per-lane global element offsets; lbase = wave-uniform LDS u16 offset
  size_t xro[4], wro[4];
  int lbase[4];
#pragma unroll
  for (int p = 0; p < 4; ++p) {
    int rl = w * 32 + p * 8;  // first row of this GLD16 (wave-uniform)
    xro[p] = (size_t)(I + rl + (lane >> 3)) * K + (lane & 7) * 8;
    wro[p] = (size_t)(J + rl + (lane >> 3)) * K + (lane & 7) * 8;
    lbase[p] = rl * 64;
  }

  f32x4 acc[2][8];
#pragma unroll
  for (int i = 0; i < 2; ++i)
#pragma unroll
    for (int j = 0; j < 8; ++j) acc[i][j] = (f32x4){0.f, 0.f, 0.f, 0.f};

// 16 global_load_lds per wave per stage (X h/l + W h/l, 4 each).
// Buffer layout (u16): Xh @0, Xl @8192, Wh @16384, Wl @24576; stride 32768.
#define NN_STAGE(k1, buf)                                         \
  {                                                               \
    _Pragma("unroll") for (int p = 0; p < 4; ++p) {               \
      GLD16(Xh + xro[p] + (k1), &lds[(buf) + lbase[p]]);          \
      GLD16(Xl + xro[p] + (k1), &lds[(buf) + 8192 + lbase[p]]);   \
      GLD16(Wh + wro[p] + (k1), &lds[(buf) + 16384 + lbase[p]]);  \
      GLD16(Wl + wro[p] + (k1), &lds[(buf) + 24576 + lbase[p]]);  \
    }                                                             \
  }

// compute: 2 k-slices (ks) x 2 jb half-passes (4 W-fragments live -> VGPR cap)
// frag element k = ks*32 + (lane>>4)*8 -> chunk c = ks*4 + (lane>>4);
// LDS slot = c ^ (row & 7).
#define NN_COMPUTE(CUR)                                                   \
  {                                                                       \
    _Pragma("unroll") for (int ks = 0; ks < 2; ++ks) {                    \
      bf16x8 fxh[2], fxl[2];                                              \
      _Pragma("unroll") for (int i = 0; i < 2; ++i) {                     \
        int m = w * 32 + i * 16 + (lane & 15);                            \
        int sl = m * 64 + (((ks * 4 + (lane >> 4)) ^ (m & 7)) << 3);      \
        fxh[i] = *(const bf16x8*)&lds[(CUR) + sl];                        \
        fxl[i] = *(const bf16x8*)&lds[(CUR) + 8192 + sl];                 \
      }                                                                   \
      _Pragma("unroll") for (int jb = 0; jb < 2; ++jb) {                  \
        bf16x8 fwh[4], fwl[4];                                            \
        _Pragma("unroll") for (int jj = 0; jj < 4; ++jj) {                \
          int n = (jb * 4 + jj) * 16 + (lane & 15);                       \
          int sl = n * 64 + (((ks * 4 + (lane >> 4)) ^ (n & 7)) << 3);    \
          fwh[jj] = *(const bf16x8*)&lds[(CUR) + 16384 + sl];             \
          fwl[jj] = *(const bf16x8*)&lds[(CUR) + 24576 + sl];             \
        }                                                                 \
        _Pragma("unroll") for (int i = 0; i < 2; ++i)                     \
          _Pragma("unroll") for (int jj = 0; jj < 4; ++jj) {              \
            acc[i][jb * 4 + jj] = __builtin_amdgcn_mfma_f32_16x16x32_bf16(\
                fxh[i], fwh[jj], acc[i][jb * 4 + jj], 0, 0, 0);           \
            acc[i][jb * 4 + jj] = __builtin_amdgcn_mfma_f32_16x16x32_bf16(\
                fxh[i], fwl[jj], acc[i][jb * 4 + jj], 0, 0, 0);           \
            acc[i][jb * 4 + jj] = __builtin_amdgcn_mfma_f32_16x16x32_bf16(\
                fxl[i], fwh[jj], acc[i][jb * 4 + jj], 0, 0, 0);           \
          }                                                               \
      }                                                                   \
    }                                                                     \
  }

  const int nk = K >> 6;  // K divisible by 64 everywhere (2048 / 4096)
  NN_STAGE(0, 0);
  for (int k = 0; k < nk; ++k) {
    const int cur = (k & 1) * 32768;
    const int nxt = 32768 - cur;
    // barrier #1: every wave finished its compute(k-1) reads of nxt.
    __builtin_amdgcn_s_barrier();
    __builtin_amdgcn_sched_barrier(0);
    if (k + 1 < nk) {
      NN_STAGE((k + 1) * 64, nxt);
      __builtin_amdgcn_sched_barrier(0);
      // own stage(k) landed (oldest 16 of 32); stage(k+1) stays in flight.
      asm volatile("s_waitcnt vmcnt(16)" ::: "memory");
    } else {
      asm volatile("s_waitcnt vmcnt(0)" ::: "memory");
    }
    // barrier #2: ALL waves' stage(k) landed -> cur fully populated.
    __builtin_amdgcn_s_barrier();
    __builtin_amdgcn_sched_barrier(0);
    NN_COMPUTE(cur);
  }
  __syncthreads();  // separate K-loop LDS reads from epilogue LDS writes
#undef NN_COMPUTE
#undef NN_STAGE

  const int qd = lane >> 4;
  const int nl = lane & 15;
  float pm = pmul;
  if (flags & FINVC) pm = pmul / scal[5];

#define NN_VAL(i, j, r, out)                           \
  {                                                    \
    int gi_ = I + w * 32 + (i)*16 + qd * 4 + (r);      \
    int gj_ = J + (j)*16 + nl;                         \
    out = pm * acc[i][j][r];                           \
    if (gi_ == gj_) out += diag;                       \
  }

  if (flags & FTRACE) {
    float ts = 0.f;
#pragma unroll
    for (int i = 0; i < 2; ++i)
#pragma unroll
      for (int j = 0; j < 8; ++j)
#pragma unroll
        for (int r = 0; r < 4; ++r) {
          int gi = I + w * 32 + i * 16 + qd * 4 + r;
          int gj = J + j * 16 + nl;
          if (gi == gj) {
            float v;
            NN_VAL(i, j, r, v);
            ts += v;
          }
        }
#pragma unroll
    for (int o = 32; o > 0; o >>= 1) ts += __shfl_down(ts, o, 64);
    float* red = (float*)lds;
    if (lane == 0) red[w] = ts;
    __syncthreads();
    if (tid == 0) atomicAdd(&scal[tidx], red[0] + red[1] + red[2] + red[3]);
    __syncthreads();
  }

  // dual-layout store via per-wave LDS transpose (wave region: 32x136 u16)
  // Global writes apply the chunk XOR (pre-swizzled layout convention).
  const int wbp = w * 4352;
  for (int half = 0; half < 2; ++half) {
#pragma unroll
    for (int i = 0; i < 2; ++i)
#pragma unroll
      for (int j = 0; j < 8; ++j)
#pragma unroll
        for (int r = 0; r < 4; ++r) {
          float v;
          NN_VAL(i, j, r, v);
          u16 hv = f2bf(v);
          u16 sv = half ? f2bf(v - bf2f(hv)) : hv;
          lds[wbp + (i * 16 + qd * 4 + r) * 136 + j * 16 + nl] = sv;
        }
    __syncthreads();
    if (flags & FROW) {
      u16* dst = half ? Crl : Crh;
#pragma unroll
      for (int p2 = 0; p2 < 8; ++p2) {
        int rr = lane >> 1;
        int ch = (lane & 1) + p2 * 2;  // 0..15 (16B chunks across 128 cols)
        bf16x8 vv = *(const bf16x8*)&lds[wbp + rr * 136 + ch * 8];
        int gi = I + w * 32 + rr;
        int slot = (ch & 7) ^ (gi & 7);
        size_t o = (size_t)gi * D_DIM + J + ((ch >> 3) << 6) + (slot << 3);
        *(bf16x8*)(dst + o) = vv;
      }
    }
    if (flags & FCOL) {
      u16* dst = half ? Ccl : Cch;
#pragma unroll
      for (int jj = 0; jj < 8; ++jj) {
        int cmaj = J + jj * 16 + (lane >> 2);
        int run = (lane & 3) * 8;
        int m = I + w * 32 + run;
        u16 tp[8];
#pragma unroll
        for (int r2 = 0; r2 < 8; ++r2) tp[r2] = lds[wbp + (run + r2) * 136 +
                                                    jj * 16 + (lane >> 2)];
        uint4 pk;
        pk.x = (u32)tp[0] | ((u32)tp[1] << 16);
        pk.y = (u32)tp[2] | ((u32)tp[3] << 16);
        pk.z = (u32)tp[4] | ((u32)tp[5] << 16);
        pk.w = (u32)tp[6] | ((u32)tp[7] << 16);
        int slot = ((m >> 3) & 7) ^ (cmaj & 7);
        size_t o = (size_t)cmaj * D_DIM + (m & ~63) + (slot << 3);
        *(uint4*)(dst + o) = pk;
      }
    }
    __syncthreads();
  }
#undef NN_VAL
}

// plain GEMM over 256 tiles (16x16), XCD column-ownership swizzle
__global__ __launch_bounds__(256)
void k_nn(const u16* Xh, const u16* Xl, const u16* Wh, const u16* Wl, u16* Crh,
          u16* Crl, u16* Cch, u16* Ccl, float* scal, int K, float diag,
          float pmul, int flags, int tidx) {
  __shared__ u16 lds[65536];
  int bi, bj;
  swz256(blockIdx.x + (blockIdx.y << 4), bi, bj);
  nn_body(lds, Xh, Xl, Wh, Wl, Crh, Crl, Cch, Ccl, scal, K, diag, pmul, flags,
          tidx, bi, bj);
}

// both triangle grams in ONE launch: 272 blocks (2 x 136 lower-tri tiles)
__global__ __launch_bounds__(256)
void k_nn_tri2(const u16* Xh0, const u16* Xl0, u16* Ch0, u16* Cl0,
               const u16* Xh1, const u16* Xl1, u16* Ch1, u16* Cl1,
               float* scal) {
  __shared__ u16 lds[65536];
  int x = blockIdx.x;
  int f5 = (x & 7) * 34 + (x >> 3);  // bijective on [0,272)
  int g = (f5 >= 136) ? 1 : 0;
  int f = f5 - g * 136;
  int bi = (int)((sqrtf(8.f * (float)f + 1.f) - 1.f) * 0.5f);
  while (bi * (bi + 1) / 2 > f) --bi;
  while ((bi + 1) * (bi + 2) / 2 <= f) ++bi;
  int bj = f - bi * (bi + 1) / 2;  // 0 <= bj <= bi
  if (g)
    nn_body(lds, Xh1, Xl1, Xh1, Xl1, Ch1, Cl1, Ch1, Cl1, scal, N_ROWS,
            EPS_DIAG, 1.0f, FROW | FCOL | FTRACE, 2, bi, bj);
  else
    nn_body(lds, Xh0, Xl0, Xh0, Xl0, Ch0, Cl0, Ch0, Cl0, scal, N_ROWS,
            EPS_DIAG, 1.0f, FROW | FCOL | FTRACE, 1, bi, bj);
}

// fused pair: grid (16,16,2)
struct NN2Args {
  const u16 *xh0, *xl0, *wh0, *wl0;
  u16 *crh0, *crl0, *cch0, *ccl0;
  const u16 *xh1, *xl1, *wh1, *wl1;
  u16 *crh1, *crl1, *cch1, *ccl1;
  float pm0, pm1;
};

__global__ __launch_bounds__(256)
void k_nn2(NN2Args a, float* scal) {
  __shared__ u16 lds[65536];
  int bi, bj;
  swz256(blockIdx.x + (blockIdx.y << 4), bi, bj);
  if (blockIdx.z == 0)
    nn_body(lds, a.xh0, a.xl0, a.wh0, a.wl0, a.crh0, a.crl0, a.cch0, a.ccl0,
            scal, D_DIM, 0.f, a.pm0, FROW | FCOL, 0, bi, bj);
  else
    nn_body(lds, a.xh1, a.xl1, a.wh1, a.wl1, a.crh1, a.crl1, a.cch1, a.ccl1,
            scal, D_DIM, 0.f, a.pm1, FROW | FCOL, 0, bi, bj);
}

// ---------------- power iteration (both chains fused) ----------------

__global__ __launch_bounds__(256)
void k_pones2(float* __restrict__ va, float* __restrict__ vb,
              float* __restrict__ snA, float* __restrict__ snB) {
  int t = blockIdx.x * 256 + threadIdx.x;  // 0..4095
  if (t < D_DIM)
    va[t] = 1.0f;
  else
    vb[t - D_DIM] = 1.0f;
  if (t == 0) {
    snA[0] = 1.0f;
    snB[0] = 1.0f;
  }
}

// gram arrays are swizzled: compensate chunk XOR when indexing vs[].
__global__ __launch_bounds__(256)
void k_gemv2(const u16* __restrict__ Ah, const u16* __restrict__ Bh,
             const float* viA, float* voA, const float* viB, float* voB,
             const float* snA, const float* snB, u32* smA, u32* smB) {
  const int zc = blockIdx.y;
  const u16* Mh = zc ? Bh : Ah;
  const float* vin = zc ? viB : viA;
  float* vout = zc ? voB : voA;
  const float* snorm = zc ? snB : snA;
  u32* smax = zc ? smB : smA;
  __shared__ float vs[D_DIM];
  float inv = 1.0f / snorm[0];
  for (int i = threadIdx.x; i < D_DIM; i += 256) vs[i] = vin[i] * inv;
  __syncthreads();
  int row = blockIdx.x * 4 + (threadIdx.x >> 6);
  int lane = threadIdx.x & 63;
  const u16* r = Mh + (size_t)row * D_DIM;
  float s = 0.f;
  for (int c0 = lane * 8; c0 < D_DIM; c0 += 512) {
    int k0 = (c0 & ~63) | ((((c0 >> 3) & 7) ^ (row & 7)) << 3);
    uint4 p = *(const uint4*)(r + c0);
    u32 w4[4] = {p.x, p.y, p.z, p.w};
#pragma unroll
    for (int q = 0; q < 4; ++q) {
      s += bf2f((u16)(w4[q] & 0xffff)) * vs[k0 + 2 * q];
      s += bf2f((u16)(w4[q] >> 16)) * vs[k0 + 2 * q + 1];
    }
  }
#pragma unroll
  for (int o = 32; o > 0; o >>= 1) s += __shfl_down(s, o, 64);
  if (lane == 0) {
    vout[row] = s;
    atomicMax(smax, __float_as_uint(fabsf(s)));
  }
}

__global__ void k_setc(float* scal) {
  scal[5] = 1.1f * scal[11] * scal[21];
}

// T1 = 3I - M/c in BOTH layouts (c = scal[5]); swizzle-aware diagonal.
__global__ __launch_bounds__(256)
void k_t1(const u16* __restrict__ Mrh, const u16* __restrict__ Mrl,
          const u16* __restrict__ Mth, const u16* __restrict__ Mtl,
          const float* __restrict__ scal, u16* __restrict__ Trh,
          u16* __restrict__ Trl, u16* __restrict__ Tth, u16* __restrict__ Ttl) {
  size_t t = (size_t)blockIdx.x * 256 + threadIdx.x;
  float invc = 1.0f / scal[5];
  size_t e = t * 4;
  int i = (int)(e >> 11);              // flat major
  int u0 = (int)(e & (D_DIM - 1));     // flat minor (slot space)
  // actual logical minor of the first of the 4 elements:
  int jb = (u0 & ~63) | ((((u0 >> 3) & 7) ^ (i & 7)) << 3) | (u0 & 7);
#pragma unroll
  for (int pass = 0; pass < 2; ++pass) {
    const u16* sh = pass ? Mth : Mrh;
    const u16* sl = pass ? Mtl : Mrl;
    u16* dh = pass ? Tth : Trh;
    u16* dl = pass ? Ttl : Trl;
    uint2 hv = ((const uint2*)sh)[t];
    uint2 lv = ((const uint2*)sl)[t];
    u16 hs[4] = {(u16)(hv.x & 0xffff), (u16)(hv.x >> 16), (u16)(hv.y & 0xffff),
                 (u16)(hv.y >> 16)};
    u16 ls[4] = {(u16)(lv.x & 0xffff), (u16)(lv.x >> 16), (u16)(lv.y & 0xffff),
                 (u16)(lv.y >> 16)};
    u16 th[4], tl[4];
#pragma unroll
    for (int c = 0; c < 4; ++c) {
      float m = bf2f(hs[c]) + bf2f(ls[c]);
      float tv = ((i == jb + c) ? 3.0f : 0.0f) - m * invc;
      th[c] = f2bf(tv);
      tl[c] = f2bf(tv - bf2f(th[c]));
    }
    ((uint2*)dh)[t] = make_uint2((u32)th[0] | ((u32)th[1] << 16),
                                 (u32)th[2] | ((u32)th[3] << 16));
    ((uint2*)dl)[t] = make_uint2((u32)tl[0] | ((u32)tl[1] << 16),
                                 (u32)tl[2] | ((u32)tl[3] << 16));
  }
}

// tr(Y*T) via row-layout x col-layout flat dot: invariant under the shared
// major-XOR swizzle convention (both sides permute the minor identically).
__global__ __launch_bounds__(256)
void k_trdot(const u16* __restrict__ Ah, const u16* __restrict__ Al,
             const u16* __restrict__ Bh, const u16* __restrict__ Bl,
             double* __restrict__ acc) {
  size_t t = (size_t)blockIdx.x * 256 + threadIdx.x;
  uint2 ah = ((const uint2*)Ah)[t], al = ((const uint2*)Al)[t];
  uint2 bh = ((const uint2*)Bh)[t], bl = ((const uint2*)Bl)[t];
  float s = 0.f;
  u32 ha[4] = {ah.x & 0xffffu, ah.x >> 16, ah.y & 0xffffu, ah.y >> 16};
  u32 la[4] = {al.x & 0xffffu, al.x >> 16, al.y & 0xffffu, al.y >> 16};
  u32 hb[4] = {bh.x & 0xffffu, bh.x >> 16, bh.y & 0xffffu, bh.y >> 16};
  u32 lb[4] = {bl.x & 0xffffu, bl.x >> 16, bl.y & 0xffffu, bl.y >> 16};
#pragma unroll
  for (int c = 0; c < 4; ++c)
    s += (bf2f((u16)ha[c]) + bf2f((u16)la[c])) *
         (bf2f((u16)hb[c]) + bf2f((u16)lb[c]));
#pragma unroll
  for (int o = 32; o > 0; o >>= 1) s += __shfl_down(s, o, 64);
  __shared__ float red[4];
  if ((threadIdx.x & 63) == 0) red[threadIdx.x >> 6] = s;
  __syncthreads();
  if (threadIdx.x == 0)
    atomicAdd(acc, (double)(red[0] + red[1] + red[2] + red[3]));
}

__global__ void k_final2(const float* __restrict__ scal,
                         const double* __restrict__ dot,
                         float* __restrict__ out) {
  out[0] = scal[1] + scal[2] - sqrtf(scal[5]) * (float)dot[0];
}

// ================== FALLBACK PATH (round-4, 64MB-proven) ==================

__global__ __launch_bounds__(256)
void k_zsplit(const float* __restrict__ z, const float* __restrict__ mean,
              const float* __restrict__ rstd, u16* __restrict__ zh,
              u16* __restrict__ zl) {
  size_t t = (size_t)blockIdx.x * 256 + threadIdx.x;
  int ci = (int)(t & 511);
  float4 v = ((const float4*)z)[t];
  float4 m = ((const float4*)mean)[ci];
  float4 r = ((const float4*)rstd)[ci];
  float x[4] = {(v.x - m.x) * r.x, (v.y - m.y) * r.y, (v.z - m.z) * r.z,
                (v.w - m.w) * r.w};
  u16 h[4], l[4];
#pragma unroll
  for (int i = 0; i < 4; ++i) {
    h[i] = f2bf(x[i]);
    l[i] = f2bf(x[i] - bf2f(h[i]));
  }
  ((uint2*)zh)[t] = make_uint2((u32)h[0] | ((u32)h[1] << 16),
                               (u32)h[2] | ((u32)h[3] << 16));
  ((uint2*)zl)[t] = make_uint2((u32)l[0] | ((u32)l[1] << 16),
                               (u32)l[2] | ((u32)l[3] << 16));
}

__global__ __launch_bounds__(256)
void k_gram_mm(const u16* __restrict__ zh, const u16* __restrict__ zl,
               u16* __restrict__ Oh, u16* __restrict__ Ol) {
  __shared__ u16 lds[24576];
  const int tid = threadIdx.x;
  const int lane = tid & 63;
  const int w = tid >> 6;
  const int I = blockIdx.y * 128;
  const int J = blockIdx.x * 64;
  const int kp = tid >> 4;
  const int nc = tid & 15;
  const int qq = kp >> 2;
  const int kd = (kp & 3) * 2;
  const size_t aro = (size_t)(2 * kp) * D_DIM + I + nc * 8;
  const size_t bro = (size_t)(2 * kp) * D_DIM + J + nc * 4;
  union U4 { uint4 v; u16 s[8]; };
  union U2 { uint2 v; u16 s[4]; };
  U4 ah0, ah1, al0, al1;
  U2 bh0, bh1, bl0, bl1;
  f32x4 acc[2][4];
#pragma unroll
  for (int i = 0; i < 2; ++i)
#pragma unroll
    for (int j = 0; j < 4; ++j) acc[i][j] = (f32x4){0.f, 0.f, 0.f, 0.f};
#define GRAM_LOAD(k1)                         \
  {                                           \
    size_t ao = aro + (size_t)(k1)*D_DIM;     \
    size_t bo = bro + (size_t)(k1)*D_DIM;     \
    ah0.v = *(const uint4*)(zh + ao);         \
    ah1.v = *(const uint4*)(zh + ao + D_DIM); \
    al0.v = *(const uint4*)(zl + ao);         \
    al1.v = *(const uint4*)(zl + ao + D_DIM); \
    bh0.v = *(const uint2*)(zh + bo);         \
    bh1.v = *(const uint2*)(zh + bo + D_DIM); \
    bl0.v = *(const uint2*)(zl + bo);         \
    bl1.v = *(const uint2*)(zl + bo + D_DIM); \
  }
#define GRAM_PACK(buf)                                                       \
  {                                                                          \
    _Pragma("unroll") for (int j = 0; j < 8; ++j) {                          \
      int mc = nc * 8 + j;                                                   \
      int t2 = mc >> 4, ml = mc & 15;                                        \
      int slot = (t2 * 64 + qq * 16 + ml) ^ t2;                              \
      *(u32*)&lds[(buf) + slot * 8 + kd] =                                   \
          (u32)ah0.s[j] | ((u32)ah1.s[j] << 16);                             \
      *(u32*)&lds[(buf) + 4096 + slot * 8 + kd] =                            \
          (u32)al0.s[j] | ((u32)al1.s[j] << 16);                             \
    }                                                                        \
    _Pragma("unroll") for (int j = 0; j < 4; ++j) {                          \
      int n = nc * 4 + j;                                                    \
      int u = n >> 4, nl = n & 15;                                           \
      int slot = (u * 64 + qq * 16 + nl) ^ u;                                \
      *(u32*)&lds[(buf) + 8192 + slot * 8 + kd] =                            \
          (u32)bh0.s[j] | ((u32)bh1.s[j] << 16);                             \
      *(u32*)&lds[(buf) + 10240 + slot * 8 + kd] =                           \
          (u32)bl0.s[j] | ((u32)bl1.s[j] << 16);                             \
    }                                                                        \
  }
  GRAM_LOAD(0);
  GRAM_PACK(0);
  __syncthreads();
  for (int k = 0; k < N_ROWS / 32; ++k) {
    const int cur = (k & 1) * 12288;
    const int nxt = 12288 - cur;
    if (k < N_ROWS / 32 - 1) GRAM_LOAD((k + 1) * 32);
    bf16x8 fah[2], fal[2], fbh[4], fbl[4];
#pragma unroll
    for (int i = 0; i < 2; ++i) {
      int t2 = w * 2 + i;
      int sl = (t2 * 64 + lane) ^ t2;
      fah[i] = *(const bf16x8*)&lds[cur + sl * 8];
      fal[i] = *(const bf16x8*)&lds[cur + 4096 + sl * 8];
    }
#pragma unroll
    for (int j = 0; j < 4; ++j) {
      int sl = (j * 64 + lane) ^ j;
      fbh[j] = *(const bf16x8*)&lds[cur + 8192 + sl * 8];
      fbl[j] = *(const bf16x8*)&lds[cur + 10240 + sl * 8];
    }
#pragma unroll
    for (int i = 0; i < 2; ++i)
#pragma unroll
      for (int j = 0; j < 4; ++j) {
        acc[i][j] = __builtin_amdgcn_mfma_f32_16x16x32_bf16(fah[i], fbh[j],
                                                            acc[i][j], 0, 0, 0);
        acc[i][j] = __builtin_amdgcn_mfma_f32_16x16x32_bf16(fah[i], fbl[j],
                                                            acc[i][j], 0, 0, 0);
        acc[i][j] = __builtin_amdgcn_mfma_f32_16x16x32_bf16(fal[i], fbh[j],
                                                            acc[i][j], 0, 0, 0);
      }
    if (k < N_ROWS / 32 - 1) GRAM_PACK(nxt);
    __syncthreads();
  }
  const int qd = lane >> 4;
  const int nl = lane & 15;
#pragma unroll
  for (int i = 0; i < 2; ++i)
#pragma unroll
    for (int j = 0; j < 4; ++j)
#pragma unroll
      for (int r = 0; r < 4; ++r) {
        int gi = I + w * 32 + i * 16 + qd * 4 + r;
        int gj = J + j * 16 + nl;
        float v = acc[i][j][r] + ((gi == gj) ? EPS_DIAG : 0.f);
        u16 h = f2bf(v);
        u16 l = f2bf(v - bf2f(h));
        Oh[(size_t)gi * D_DIM + gj] = h;
        Ol[(size_t)gi * D_DIM + gj] = l;
      }
#undef GRAM_LOAD
#undef GRAM_PACK
}

template <int MODE>
__global__ __launch_bounds__(256)
void k_mm(const u16* __restrict__ Ph, const u16* __restrict__ Pl,
          const u16* __restrict__ Qh, const u16* __restrict__ Ql,
          u16* __restrict__ Ch, u16* __restrict__ Cl,
          const float* __restrict__ scal) {
  __shared__ u16 lds[24576];
  const int tid = threadIdx.x;
  const int lane = tid & 63;
  const int w = tid >> 6;
  const int I = blockIdx.y * 128;
  const int J = blockIdx.x * 64;
  const int kp = tid >> 4;
  const int nc = tid & 15;
  const int qq = kp >> 2;
  const int kd = (kp & 3) * 2;
  size_t aro[2];
  int acl[2], abase[2];
#pragma unroll
  for (int p = 0; p < 2; ++p) {
    int s = p * 256 + w * 64 + lane;
    aro[p] = (size_t)(I + (s >> 6) * 16 + (s & 15)) * D_DIM;
    acl[p] = ((s >> 4) & 3) * 8;
    abase[p] = (p * 256 + w * 64) * 8;
  }
  const size_t bro = (size_t)(2 * kp) * D_DIM + J + nc * 4;
  union U2 { uint2 v; u16 s[4]; };
  U2 bh0, bh1, bl0, bl1;
  f32x4 acc[2][4];
#pragma unroll
  for (int i = 0; i < 2; ++i)
#pragma unroll
    for (int j = 0; j < 4; ++j) acc[i][j] = (f32x4){0.f, 0.f, 0.f, 0.f};
#define MM_STAGE_A(k1, buf)                                              \
  {                                                                      \
    _Pragma("unroll") for (int p = 0; p < 2; ++p) {                      \
      GLD16(Ph + aro[p] + (k1) + acl[p], &lds[(buf) + abase[p]]);        \
      GLD16(Pl + aro[p] + (k1) + acl[p], &lds[(buf) + 4096 + abase[p]]); \
    }                                                                    \
  }
#define MM_LOAD_B(k1)                         \
  {                                           \
    size_t bo = bro + (size_t)(k1)*D_DIM;     \
    bh0.v = *(const uint2*)(Qh + bo);         \
    bh1.v = *(const uint2*)(Qh + bo + D_DIM); \
    bl0.v = *(const uint2*)(Ql + bo);         \
    bl1.v = *(const uint2*)(Ql + bo + D_DIM); \
  }
#define MM_PACK_B(buf)                                                       \
  {                                                                          \
    _Pragma("unroll") for (int j = 0; j < 4; ++j) {                          \
      int n = nc * 4 + j;                                                    \
      int u = n >> 4, nl2 = n & 15;                                          \
      int slot = (u * 64 + qq * 16 + nl2) ^ u;                               \
      *(u32*)&lds[(buf) + 8192 + slot * 8 + kd] =                            \
          (u32)bh0.s[j] | ((u32)bh1.s[j] << 16);                             \
      *(u32*)&lds[(buf) + 10240 + slot * 8 + kd] =                           \
          (u32)bl0.s[j] | ((u32)bl1.s[j] << 16);                             \
    }                                                                        \
  }
  MM_STAGE_A(0, 0);
  MM_LOAD_B(0);
  MM_PACK_B(0);
  __syncthreads();
  for (int k = 0; k < D_DIM / 32; ++k) {
    const int cur = (k & 1) * 12288;
    const int nxt = 12288 - cur;
    if (k < D_DIM / 32 - 1) {
      MM_STAGE_A((k + 1) * 32, nxt);
      MM_LOAD_B((k + 1) * 32);
    }
    bf16x8 fah[2], fal[2], fbh[4], fbl[4];
#pragma unroll
    for (int i = 0; i < 2; ++i) {
      int t2 = w * 2 + i;
      fah[i] = *(const bf16x8*)&lds[cur + (t2 * 64 + lane) * 8];
      fal[i] = *(const bf16x8*)&lds[cur + 4096 + (t2 * 64 + lane) * 8];
    }
#pragma unroll
    for (int j = 0; j < 4; ++j) {
      int sl = (j * 64 + lane) ^ j;
      fbh[j] = *(const bf16x8*)&lds[cur + 8192 + sl * 8];
      fbl[j] = *(const bf16x8*)&lds[cur + 10240 + sl * 8];
    }
#pragma unroll
    for (int i = 0; i < 2; ++i)
#pragma unroll
      for (int j = 0; j < 4; ++j) {
        acc[i][j] = __builtin_amdgcn_mfma_f32_16x16x32_bf16(fah[i], fbh[j],
                                                            acc[i][j], 0, 0, 0);
        acc[i][j] = __builtin_amdgcn_mfma_f32_16x16x32_bf16(fah[i], fbl[j],
                                                            acc[i][j], 0, 0, 0);
        acc[i][j] = __builtin_amdgcn_mfma_f32_16x16x32_bf16(fal[i], fbh[j],
                                                            acc[i][j], 0, 0, 0);
      }
    if (k < D_DIM / 32 - 1) MM_PACK_B(nxt);
    __syncthreads();
  }
  float mul = (MODE == 2) ? 0.5f : 1.0f;
  if (MODE == 3) mul = 0.5f / sqrtf(scal[0]);
  const int qd = lane >> 4;
  const int nl = lane & 15;
#pragma unroll
  for (int i = 0; i < 2; ++i)
#pragma unroll
    for (int j = 0; j < 4; ++j)
#pragma unroll
      for (int r = 0; r < 4; ++r) {
        int gi = I + w * 32 + i * 16 + qd * 4 + r;
        int gj = J + j * 16 + nl;
        float v = acc[i][j][r];
        if (MODE == 1)
          v = ((gi == gj) ? 3.0f : 0.0f) - v;
        else
          v *= mul;
        u16 h = f2bf(v);
        u16 l = f2bf(v - bf2f(h));
        Ch[(size_t)gi * D_DIM + gj] = h;
        Cl[(size_t)gi * D_DIM + gj] = l;
      }
#undef MM_STAGE_A
#undef MM_LOAD_B
#undef MM_PACK_B
}

__global__ __launch_bounds__(256)
void k_frob_hl(const u16* __restrict__ mh, const u16* __restrict__ ml,
               float* __restrict__ c2) {
  size_t t = (size_t)blockIdx.x * 256 + threadIdx.x;
  uint2 hv = ((const uint2*)mh)[t];
  uint2 lv = ((const uint2*)ml)[t];
  float v0 = bf2f((u16)(hv.x & 0xffff)) + bf2f((u16)(lv.x & 0xffff));
  float v1 = bf2f((u16)(hv.x >> 16)) + bf2f((u16)(lv.x >> 16));
  float v2 = bf2f((u16)(hv.y & 0xffff)) + bf2f((u16)(lv.y & 0xffff));
  float v3 = bf2f((u16)(hv.y >> 16)) + bf2f((u16)(lv.y >> 16));
  float q = v0 * v0 + v1 * v1 + v2 * v2 + v3 * v3;
#pragma unroll
  for (int o = 32; o > 0; o >>= 1) q += __shfl_down(q, o, 64);
  __shared__ float red[4];
  if ((threadIdx.x & 63) == 0) red[threadIdx.x >> 6] = q;
  __syncthreads();
  if (threadIdx.x == 0) atomicAdd(c2, red[0] + red[1] + red[2] + red[3]);
}

__global__ __launch_bounds__(256)
void k_t1z1(const u16* __restrict__ Mh, const u16* __restrict__ Ml,
            const float* __restrict__ scal, u16* __restrict__ Th,
            u16* __restrict__ Tl, u16* __restrict__ Zh, u16* __restrict__ Zl) {
  size_t t = (size_t)blockIdx.x * 256 + threadIdx.x;
  float invc = 1.0f / sqrtf(scal[0]);
  size_t e = t * 4;
  int i = (int)(e >> 11);
  int j0 = (int)(e & (D_DIM - 1));
  uint2 hv = ((const uint2*)Mh)[t];
  uint2 lv = ((const uint2*)Ml)[t];
  u16 hs[4] = {(u16)(hv.x & 0xffff), (u16)(hv.x >> 16), (u16)(hv.y & 0xffff),
               (u16)(hv.y >> 16)};
  u16 ls[4] = {(u16)(lv.x & 0xffff), (u16)(lv.x >> 16), (u16)(lv.y & 0xffff),
               (u16)(lv.y >> 16)};
  u16 th[4], tl[4], zh[4], zl[4];
#pragma unroll
  for (int c = 0; c < 4; ++c) {
    float m = bf2f(hs[c]) + bf2f(ls[c]);
    float tv = ((i == j0 + c) ? 3.0f : 0.0f) - m * invc;
    th[c] = f2bf(tv);
    tl[c] = f2bf(tv - bf2f(th[c]));
    float zv = 0.5f * tv;
    zh[c] = f2bf(zv);
    zl[c] = f2bf(zv - bf2f(zh[c]));
  }
  ((uint2*)Th)[t] = make_uint2((u32)th[0] | ((u32)th[1] << 16),
                               (u32)th[2] | ((u32)th[3] << 16));
  ((uint2*)Tl)[t] = make_uint2((u32)tl[0] | ((u32)tl[1] << 16),
                               (u32)tl[2] | ((u32)tl[3] << 16));
  ((uint2*)Zh)[t] = make_uint2((u32)zh[0] | ((u32)zh[1] << 16),
                               (u32)zh[2] | ((u32)zh[3] << 16));
  ((uint2*)Zl)[t] = make_uint2((u32)zl[0] | ((u32)zl[1] << 16),
                               (u32)zl[2] | ((u32)zl[3] << 16));
}

__global__ __launch_bounds__(256)
void k_trace_hl(const u16* __restrict__ mh, const u16* __restrict__ ml,
                float* __restrict__ out) {
  __shared__ float red[256];
  float s = 0.f;
  for (int i = threadIdx.x; i < D_DIM; i += 256) {
    size_t d = (size_t)i * (D_DIM + 1);
    s += bf2f(mh[d]) + bf2f(ml[d]);
  }
  red[threadIdx.x] = s;
  __syncthreads();
  for (int o = 128; o > 0; o >>= 1) {
    if (threadIdx.x < o) red[threadIdx.x] += red[threadIdx.x + o];
    __syncthreads();
  }
  if (threadIdx.x == 0) out[0] = red[0];
}

__global__ __launch_bounds__(256)
void k_final(const u16* __restrict__ Yh, const u16* __restrict__ Yl,
             const float* __restrict__ scal, float* __restrict__ out) {
  __shared__ float red[256];
  float s = 0.f;
  for (int i = threadIdx.x; i < D_DIM; i += 256) {
    size_t d = (size_t)i * (D_DIM + 1);
    s += bf2f(Yh[d]) + bf2f(Yl[d]);
  }
  red[threadIdx.x] = s;
  __syncthreads();
  for (int o = 128; o > 0; o >>= 1) {
    if (threadIdx.x < o) red[threadIdx.x] += red[threadIdx.x + o];
    __syncthreads();
  }
  if (threadIdx.x == 0) {
    float sqrtc = sqrtf(sqrtf(scal[0]));
    out[0] = scal[1] + scal[2] - 2.0f * sqrtc * red[0];
  }
}

// ---------------- launch ----------------

extern "C" void kernel_launch(void* const* d_in, const int* in_sizes, int n_in,
                              void* d_out, int out_size, void* d_ws,
                              size_t ws_size, hipStream_t stream) {
  (void)in_sizes; (void)n_in; (void)out_size;
  const float* za = (const float*)d_in[0];
  const float* zb = (const float*)d_in[1];
  float* out = (float*)d_out;
  float* ws = (float*)d_ws;
  float* stat = ws;
  float* scal = ws + 4 * D_DIM;

  hipMemsetAsync(ws, 0, (4 * D_DIM + 32) * sizeof(float), stream);
  dim3 blk(256);

  const size_t NEED = 65536ull + 8ull * 16 * 1024 * 1024;
  if (ws_size >= NEED) {
    // ================= FAST PATH =================
    char* pool = (char*)d_ws + 65536;
    auto uh = [&](int u) { return (u16*)(pool + (size_t)u * 16777216); };
    auto ul = [&](int u) {
      return (u16*)(pool + (size_t)u * 16777216 + 8388608);
    };
    // z-split A: whole U0 (h) + whole U1 (l); B: whole U4 + whole U5
    u16* ZhA = (u16*)(pool);
    u16* ZlA = (u16*)(pool + 1ull * 16777216);
    u16* ZhB = (u16*)(pool + 4ull * 16777216);
    u16* ZlB = (u16*)(pool + 5ull * 16777216);
    dim3 gm(16, 16);

    k_colstats2<<<dim3(8, 16, 2), blk, 0, stream>>>(za, zb, stat);
    k_finalize_stats<<<16, blk, 0, stream>>>(stat);
    k_zsplit_t2<<<dim3(64, 32, 2), blk, 0, stream>>>(za, zb, stat, ZhA, ZlA,
                                                     ZhB, ZlB);
    // both grams, one launch: A -> U2 (trace scal[1]), B -> U3 (scal[2])
    k_nn_tri2<<<272, blk, 0, stream>>>(ZhA, ZlA, uh(2), ul(2), ZhB, ZlB,
                                       uh(3), ul(3), scal);

    // paired power iteration: lambda_max(A)->scal[11], lambda_max(B)->scal[21]
    k_pones2<<<16, blk, 0, stream>>>(stat, stat + 2 * D_DIM, scal + 6,
                                     scal + 16);
    for (int s = 0; s < 5; ++s) {
      const float* viA = (s & 1) ? stat + D_DIM : stat;
      float* voA = (s & 1) ? stat : stat + D_DIM;
      const float* viB = (s & 1) ? stat + 3 * D_DIM : stat + 2 * D_DIM;
      float* voB = (s & 1) ? stat + 2 * D_DIM : stat + 3 * D_DIM;
      k_gemv2<<<dim3(512, 2), blk, 0, stream>>>(
          uh(2), uh(3), viA, voA, viB, voB, scal + 6 + s, scal + 16 + s,
          (u32*)(scal + 7 + s), (u32*)(scal + 17 + s));
    }
    k_setc<<<1, 1, 0, stream>>>(scal);

    // M = A*B -> row U4, col U5 (zsplit-B dead; B symmetric => W=B row)
    k_nn<<<gm, blk, 0, stream>>>(uh(2), ul(2), uh(3), ul(3), uh(4), ul(4),
                                 uh(5), ul(5), scal, D_DIM, 0.f, 1.0f,
                                 FROW | FCOL, 0);
    // T1 = 3I - M/c -> row U6, col U7
    k_t1<<<4096, blk, 0, stream>>>(uh(4), ul(4), uh(5), ul(5), scal, uh(6),
                                   ul(6), uh(7), ul(7));
    // Y1 = (0.5/c) M*T1 -> row U0, col U1 (zsplit-A dead)
    k_nn<<<gm, blk, 0, stream>>>(uh(4), ul(4), uh(7), ul(7), uh(0), ul(0),
                                 uh(1), ul(1), scal, D_DIM, 0.f, 0.5f,
                                 FROW | FCOL | FINVC, 0);
    // T2 = 3I - 0.5*T1*Y1 -> row U4, col U5 (M dead; Z1 = T1/2 implicit)
    k_nn<<<gm, blk, 0, stream>>>(uh(6), ul(6), uh(1), ul(1), uh(4), ul(4),
                                 uh(5), ul(5), scal, D_DIM, 3.f, -0.5f,
                                 FROW | FCOL, 0);
    // fused: Y2 = 0.5*Y1*T2 -> U1(row),U2(col) ; Z2 = 0.25*T2*T1 -> U3,U6
    {
      NN2Args a;
      a.xh0 = uh(0); a.xl0 = ul(0); a.wh0 = uh(5); a.wl0 = ul(5);
      a.crh0 = uh(1); a.crl0 = ul(1); a.cch0 = uh(2); a.ccl0 = ul(2);
      a.pm0 = 0.5f;
      a.xh1 = uh(4); a.xl1 = ul(4); a.wh1 = uh(7); a.wl1 = ul(7);
      a.crh1 = uh(3); a.crl1 = ul(3); a.cch1 = uh(6); a.ccl1 = ul(6);
      a.pm1 = 0.25f;
      k_nn2<<<dim3(16, 16, 2), blk, 0, stream>>>(a, scal);
    }
    int Yr = 1, Yt = 2, Zr = 3, Zt = 6;
    int fr0 = 0, fr1 = 4, fr2 = 5, fr3 = 7;
    for (int it = 3; it <= 10; ++it) {
      // T = 3I - Z*Y -> row fr0, col fr1
      k_nn<<<gm, blk, 0, stream>>>(uh(Zr), ul(Zr), uh(Yt), ul(Yt), uh(fr0),
                                   ul(fr0), uh(fr1), ul(fr1), scal, D_DIM, 3.f,
                                   -1.f, FROW | FCOL, 0);
      // fused: Yn = 0.5*Y*T -> fr2,fr3 ; Zn = 0.5*T*Z -> Yt,Zr (dead units)
      NN2Args a;
      a.xh0 = uh(Yr); a.xl0 = ul(Yr); a.wh0 = uh(fr1); a.wl0 = ul(fr1);
      a.crh0 = uh(fr2); a.crl0 = ul(fr2); a.cch0 = uh(fr3); a.ccl0 = ul(fr3);
      a.pm0 = 0.5f;
      a.xh1 = uh(fr0); a.xl1 = ul(fr0); a.wh1 = uh(Zt); a.wl1 = ul(Zt);
      a.crh1 = uh(Yt); a.crl1 = ul(Yt); a.cch1 = uh(Zr); a.ccl1 = ul(Zr);
      a.pm1 = 0.5f;
      k_nn2<<<dim3(16, 16, 2), blk, 0, stream>>>(a, scal);
      int nYr = fr2, nYt = fr3, nZr = Yt, nZt = Zr;
      int nf0 = Yr, nf1 = Zt, nf2 = fr0, nf3 = fr1;
      Yr = nYr; Yt = nYt; Zr = nZr; Zt = nZt;
      fr0 = nf0; fr1 = nf1; fr2 = nf2; fr3 = nf3;
    }
    // step 11: T11 col-only -> fr0 ; trY11 = 0.5*dot(Y10 row, T11 col)
    k_nn<<<gm, blk, 0, stream>>>(uh(Zr), ul(Zr), uh(Yt), ul(Yt), uh(fr1),
                                 ul(fr1), uh(fr0), ul(fr0), scal, D_DIM, 3.f,
                                 -1.f, FCOL, 0);
    k_trdot<<<4096, blk, 0, stream>>>(uh(Yr), ul(Yr), uh(fr0), ul(fr0),
                                      (double*)(scal + 24));
    k_final2<<<1, 1, 0, stream>>>(scal, (const double*)(scal + 24), out);
    return;
  }

  // ================= FALLBACK (round-4, 64MB) =================
  k_colstats2<<<dim3(8, 16, 2), blk, 0, stream>>>(za, zb, stat);
  k_finalize_stats<<<16, blk, 0, stream>>>(stat);
  u16* b[8];
  {
    char* pool = (char*)d_ws + 65536;
    for (int i = 0; i < 8; ++i) b[i] = (u16*)(pool + (size_t)i * 8388608);
  }
#define PH(p) b[2 * (p)]
#define PL(p) b[2 * (p) + 1]
  u16* zh = b[4];
  u16* zl = b[6];
  dim3 gm(32, 16);
  k_zsplit<<<8192, blk, 0, stream>>>(za, stat, stat + D_DIM, zh, zl);
  k_gram_mm<<<gm, blk, 0, stream>>>(zh, zl, PH(0), PL(0));
  k_zsplit<<<8192, blk, 0, stream>>>(zb, stat + 2 * D_DIM, stat + 3 * D_DIM,
                                     zh, zl);
  k_gram_mm<<<gm, blk, 0, stream>>>(zh, zl, PH(1), PL(1));
  k_trace_hl<<<1, blk, 0, stream>>>(PH(0), PL(0), scal + 1);
  k_trace_hl<<<1, blk, 0, stream>>>(PH(1), PL(1), scal + 2);
  k_mm<0><<<gm, blk, 0, stream>>>(PH(0), PL(0), PH(1), PL(1), PH(2), PL(2),
                                  scal);
  k_frob_hl<<<4096, blk, 0, stream>>>(PH(2), PL(2), scal);
  k_t1z1<<<4096, blk, 0, stream>>>(PH(2), PL(2), scal, PH(0), PL(0), PH(1),
                                   PL(1));
  k_mm<3><<<gm, blk, 0, stream>>>(PH(2), PL(2), PH(0), PL(0), PH(3), PL(3),
                                  scal);
  int Y = 3, Z = 1, fA = 0, fB = 2;
  for (int it = 2; it <= NS_ITERS; ++it) {
    k_mm<1><<<gm, blk, 0, stream>>>(PH(Z), PL(Z), PH(Y), PL(Y), PH(fA), PL(fA),
                                    scal);
    k_mm<2><<<gm, blk, 0, stream>>>(PH(Y), PL(Y), PH(fA), PL(fA), PH(fB),
                                    PL(fB), scal);
    if (it < NS_ITERS)
      k_mm<2><<<gm, blk, 0, stream>>>(PH(fA), PL(fA), PH(Z), PL(Z), PH(Y),
                                      PL(Y), scal);
    int oy = Y, oz = Z, oa = fA, ob = fB;
    Y = ob; Z = oy; fA = oz; fB = oa;
  }
  k_final<<<1, blk, 0, stream>>>(PH(Y), PL(Y), scal, out);
#undef PH
#undef PL
}

// Round 9
// 2391.435 us; speedup vs baseline: 1.2159x; 1.0099x over previous
//
#include <hip/hip_runtime.h>
#include <math.h>

typedef unsigned short u16;
typedef unsigned int u32;

#define D_DIM 2048
#define N_ROWS 4096
#define EPS_DIAG 1e-3f
#define NS_ITERS 16  // fallback path only

typedef __attribute__((ext_vector_type(8))) short bf16x8;
typedef __attribute__((ext_vector_type(4))) float f32x4;

__device__ __forceinline__ u16 f2bf(float f) {
  u32 u = __float_as_uint(f);
  u += 0x7fffu + ((u >> 16) & 1u);
  return (u16)(u >> 16);
}
__device__ __forceinline__ float bf2f(u16 h) {
  return __uint_as_float(((u32)h) << 16);
}

#define GLD16(g, l)                                        \
  __builtin_amdgcn_global_load_lds(                        \
      (const __attribute__((address_space(1))) void*)(g),  \
      (__attribute__((address_space(3))) void*)(l), 16, 0, 0)

// ---------------------------------------------------------------------------
// TILED-CONTIGUOUS SWIZZLED GLOBAL LAYOUT (fast path only).
// Every GEMM operand array [r][K] is stored as 1KB tiles of (8 rows x 64 k):
//   off(r,k) = ((r>>3)*(K>>6) + (k>>6))*512
//            + (r&7)*64 + ((((k>>3)&7) ^ (r&7)) << 3) + (k&7)
// The 1KB tile holds exactly the XOR-swizzled LDS image, so global_load_lds
// is a single CONTIGUOUS 1KB burst per instruction (round-9: kills the
// remaining 8-way segmentation of round 8) and ds_reads keep the same XOR
// (2 lanes/bank = free). Producers write with this map; elementwise
// consumers decode it. trdot stays invariant (shared map on both operands).
// ---------------------------------------------------------------------------

// scal layout (floats): [1]=trA [2]=trB [5]=c  [6..11]=powerA  [16..21]=powerB
// [24..25] = trdot double accumulator

// XCD column-ownership swizzle for 256-tile grids (16 bi x 16 bj).
__device__ __forceinline__ void swz256(int id, int& bi, int& bj) {
  int s = id & 7;   // XCD (dispatch round-robin)
  int j = id >> 3;  // 0..31 within XCD
  bj = s * 2 + (j & 1);
  bi = j >> 1;
}

// ---------------- column statistics (both inputs, one launch) ----------------

__global__ __launch_bounds__(256)
void k_colstats2(const float* __restrict__ za, const float* __restrict__ zb,
                 float* __restrict__ stat) {
  const float* z = blockIdx.z ? zb : za;
  float* sum_ = stat + blockIdx.z * 2 * D_DIM;
  float* ssq_ = sum_ + D_DIM;
  const int c = blockIdx.x * 256 + threadIdx.x;
  const int r0 = blockIdx.y * (N_ROWS / 16);
  float s = 0.f, q = 0.f;
#pragma unroll 8
  for (int r = 0; r < N_ROWS / 16; ++r) {
    float v = z[(size_t)(r0 + r) * D_DIM + c];
    s += v;
    q += v * v;
  }
  atomicAdd(&sum_[c], s);
  atomicAdd(&ssq_[c], q);
}

__global__ __launch_bounds__(256)
void k_finalize_stats(float* stat) {
  const int t = blockIdx.x * 256 + threadIdx.x;
  const int g = t >> 11;
  const int c = t & (D_DIM - 1);
  float* base = stat + g * 2 * D_DIM;
  float s = base[c];
  float q = base[D_DIM + c];
  float mean = s * (1.0f / N_ROWS);
  float var = (q - (float)N_ROWS * mean * mean) * (1.0f / (N_ROWS - 1));
  var = fmaxf(var, 1e-30f);
  base[c] = mean;
  base[D_DIM + c] = 1.0f / sqrtf(var);
}

// ================== FAST PATH (needs 128MB + 64KB workspace) ==================

// standardize + split + TRANSPOSE both inputs: z[N][D] -> Zt[D][N] bf16 h/l
// Output in TILED swizzled layout (major d, minor n, K=N_ROWS).
__global__ __launch_bounds__(256)
void k_zsplit_t2(const float* __restrict__ za, const float* __restrict__ zb,
                 const float* __restrict__ stat, u16* __restrict__ Zh0,
                 u16* __restrict__ Zl0, u16* __restrict__ Zh1,
                 u16* __restrict__ Zl1) {
  __shared__ float T[64 * 72];
  const float* z = blockIdx.z ? zb : za;
  const float* mean = stat + blockIdx.z * 2 * D_DIM;
  const float* rstd = mean + D_DIM;
  u16* Zth = blockIdx.z ? Zh1 : Zh0;
  u16* Ztl = blockIdx.z ? Zl1 : Zl0;
  const int t = threadIdx.x;
  const int r0 = blockIdx.x * 64;
  const int c0 = blockIdx.y * 64;
#pragma unroll
  for (int p = 0; p < 4; ++p) {
    int row = p * 16 + (t >> 4);
    int c4 = t & 15;
    float4 v = *(const float4*)(z + (size_t)(r0 + row) * D_DIM + c0 + c4 * 4);
    *(float4*)&T[row * 72 + c4 * 4] = v;
  }
  __syncthreads();
  const int c = c0 + (t >> 2);
  const float m = mean[c];
  const float r = rstd[c];
  const int cc = t >> 2;
#pragma unroll
  for (int g = 0; g < 2; ++g) {
    int rbase = g * 32 + (t & 3) * 8;
    u16 hs[8], ls[8];
#pragma unroll
    for (int i = 0; i < 8; ++i) {
      float x = (T[(rbase + i) * 72 + cc] - m) * r;
      hs[i] = f2bf(x);
      ls[i] = f2bf(x - bf2f(hs[i]));
    }
    uint4 ph, pl;
    ph.x = (u32)hs[0] | ((u32)hs[1] << 16);
    ph.y = (u32)hs[2] | ((u32)hs[3] << 16);
    ph.z = (u32)hs[4] | ((u32)hs[5] << 16);
    ph.w = (u32)hs[6] | ((u32)hs[7] << 16);
    pl.x = (u32)ls[0] | ((u32)ls[1] << 16);
    pl.y = (u32)ls[2] | ((u32)ls[3] << 16);
    pl.z = (u32)ls[4] | ((u32)ls[5] << 16);
    pl.w = (u32)ls[6] | ((u32)ls[7] << 16);
    int n = r0 + rbase;  // multiple of 8
    int slot = ((n >> 3) & 7) ^ (c & 7);
    size_t o = ((size_t)(c >> 3) * (N_ROWS >> 6) + (n >> 6)) * 512 +
               (c & 7) * 64 + (slot << 3);
    *(uint4*)(Zth + o) = ph;
    *(uint4*)(Ztl + o) = pl;
  }
}

#define FINVC 1
#define FTRACE 4
#define FCOL 8
#define FROW 16

// Unified split-bf16 MFMA GEMM body: C = diag*I + pm*(X * W^T).
// 128x128 tile, BK=64. Tiled-contiguous layout: each GLD16 is ONE
// contiguous 1KB burst (base + lane*16B) -- LDS image identical to round 8
// (XOR-swizzled [8][64] tiles), NN_COMPUTE unchanged.
// Schedule (race-free per round 4):
//   barrier#1 -> STAGE(k+1)->nxt -> vmcnt(16) -> barrier#2 -> compute(cur)
// LDS 2 x 64KB = 128KB -> 1 block/CU.
__device__ __forceinline__ void nn_body(
    u16* lds, const u16* __restrict__ Xh, const u16* __restrict__ Xl,
    const u16* __restrict__ Wh, const u16* __restrict__ Wl,
    u16* __restrict__ Crh, u16* __restrict__ Crl, u16* __restrict__ Cch,
    u16* __restrict__ Ccl, float* __restrict__ scal, int K, float diag,
    float pmul, int flags, int tidx, int bi, int bj) {
  const int tid = threadIdx.x;
  const int lane = tid & 63;
  const int w = tid >> 6;
  const int I = bi * 128;
  const int J = bj * 128;

  // tile-contiguous staging: GLD16 p covers rows [rl, rl+8) x one k-block.
  // global base = (I+rl)*K + lane*8 elems; K-step k1 adds k1*8 elems.
  size_t xro[4], wro[4];
  int lbase[4];
#pragma unroll
  for (int p = 0; p < 4; ++p) {
    int rl = w * 32 + p * 8;  // multiple of 8 (wave-uniform)
    xro[p] = (size_t)(I + rl) * K + lane * 8;
    wro[p] = (size_t)(J + rl) * K + lane * 8;
    lbase[p] = rl * 64;
  }

  f32x4 acc[2][8];
#pragma unroll
  for (int i = 0; i < 2; ++i)
#pragma unroll
    for (int j = 0; j < 8; ++j) acc[i][j] = (f32x4){0.f, 0.f, 0.f, 0.f};

// 16 global_load_lds per wave per stage (X h/l + W h/l, 4 each).
// Buffer layout (u16): Xh @0, Xl @8192, Wh @16384, Wl @24576; stride 32768.
#define NN_STAGE(k1, buf)                                                  \
  {                                                                        \
    _Pragma("unroll") for (int p = 0; p < 4; ++p) {                        \
      GLD16(Xh + xro[p] + (size_t)(k1) * 8, &lds[(buf) + lbase[p]]);       \
      GLD16(Xl + xro[p] + (size_t)(k1) * 8,                                \
            &lds[(buf) + 8192 + lbase[p]]);                                \
      GLD16(Wh + wro[p] + (size_t)(k1) * 8,                                \
            &lds[(buf) + 16384 + lbase[p]]);                               \
      GLD16(Wl + wro[p] + (size_t)(k1) * 8,                                \
            &lds[(buf) + 24576 + lbase[p]]);                               \
    }                                                                      \
  }

// compute: 2 k-slices (ks) x 2 jb half-passes (4 W-fragments live -> VGPR cap)
// frag element k = ks*32 + (lane>>4)*8 -> chunk c = ks*4 + (lane>>4);
// LDS slot = c ^ (row & 7).
#define NN_COMPUTE(CUR)                                                   \
  {                                                                       \
    _Pragma("unroll") for (int ks = 0; ks < 2; ++ks) {                    \
      bf16x8 fxh[2], fxl[2];                                              \
      _Pragma("unroll") for (int i = 0; i < 2; ++i) {                     \
        int m = w * 32 + i * 16 + (lane & 15);                            \
        int sl = m * 64 + (((ks * 4 + (lane >> 4)) ^ (m & 7)) << 3);      \
        fxh[i] = *(const bf16x8*)&lds[(CUR) + sl];                        \
        fxl[i] = *(const bf16x8*)&lds[(CUR) + 8192 + sl];                 \
      }                                                                   \
      _Pragma("unroll") for (int jb = 0; jb < 2; ++jb) {                  \
        bf16x8 fwh[4], fwl[4];                                            \
        _Pragma("unroll") for (int jj = 0; jj < 4; ++jj) {                \
          int n = (jb * 4 + jj) * 16 + (lane & 15);                       \
          int sl = n * 64 + (((ks * 4 + (lane >> 4)) ^ (n & 7)) << 3);    \
          fwh[jj] = *(const bf16x8*)&lds[(CUR) + 16384 + sl];             \
          fwl[jj] = *(const bf16x8*)&lds[(CUR) + 24576 + sl];             \
        }                                                                 \
        _Pragma("unroll") for (int i = 0; i < 2; ++i)                     \
          _Pragma("unroll") for (int jj = 0; jj < 4; ++jj) {              \
            acc[i][jb * 4 + jj] = __builtin_amdgcn_mfma_f32_16x16x32_bf16(\
                fxh[i], fwh[jj], acc[i][jb * 4 + jj], 0, 0, 0);           \
            acc[i][jb * 4 + jj] = __builtin_amdgcn_mfma_f32_16x16x32_bf16(\
                fxh[i], fwl[jj], acc[i][jb * 4 + jj], 0, 0, 0);           \
            acc[i][jb * 4 + jj] = __builtin_amdgcn_mfma_f32_16x16x32_bf16(\
                fxl[i], fwh[jj], acc[i][jb * 4 + jj], 0, 0, 0);           \
          }                                                               \
      }                                                                   \
    }                                                                     \
  }

  const int nk = K >> 6;  // K divisible by 64 everywhere (2048 / 4096)
  NN_STAGE(0, 0);
  for (int k = 0; k < nk; ++k) {
    const int cur = (k & 1) * 32768;
    const int nxt = 32768 - cur;
    // barrier #1: every wave finished its compute(k-1) reads of nxt.
    __builtin_amdgcn_s_barrier();
    __builtin_amdgcn_sched_barrier(0);
    if (k + 1 < nk) {
      NN_STAGE((k + 1) * 64, nxt);
      __builtin_amdgcn_sched_barrier(0);
      // own stage(k) landed (oldest 16 of 32); stage(k+1) stays in flight.
      asm volatile("s_waitcnt vmcnt(16)" ::: "memory");
    } else {
      asm volatile("s_waitcnt vmcnt(0)" ::: "memory");
    }
    // barrier #2: ALL waves' stage(k) landed -> cur fully populated.
    __builtin_amdgcn_s_barrier();
    __builtin_amdgcn_sched_barrier(0);
    NN_COMPUTE(cur);
  }
  __syncthreads();  // separate K-loop LDS reads from epilogue LDS writes
#undef NN_COMPUTE
#undef NN_STAGE

  const int qd = lane >> 4;
  const int nl = lane & 15;
  float pm = pmul;
  if (flags & FINVC) pm = pmul / scal[5];

#define NN_VAL(i, j, r, out)                           \
  {                                                    \
    int gi_ = I + w * 32 + (i)*16 + qd * 4 + (r);      \
    int gj_ = J + (j)*16 + nl;                         \
    out = pm * acc[i][j][r];                           \
    if (gi_ == gj_) out += diag;                       \
  }

  if (flags & FTRACE) {
    float ts = 0.f;
#pragma unroll
    for (int i = 0; i < 2; ++i)
#pragma unroll
      for (int j = 0; j < 8; ++j)
#pragma unroll
        for (int r = 0; r < 4; ++r) {
          int gi = I + w * 32 + i * 16 + qd * 4 + r;
          int gj = J + j * 16 + nl;
          if (gi == gj) {
            float v;
            NN_VAL(i, j, r, v);
            ts += v;
          }
        }
#pragma unroll
    for (int o = 32; o > 0; o >>= 1) ts += __shfl_down(ts, o, 64);
    float* red = (float*)lds;
    if (lane == 0) red[w] = ts;
    __syncthreads();
    if (tid == 0) atomicAdd(&scal[tidx], red[0] + red[1] + red[2] + red[3]);
    __syncthreads();
  }

  // dual-layout store via per-wave LDS transpose (wave region: 32x136 u16)
  // Global writes use the tiled swizzled map.
  const int wbp = w * 4352;
  for (int half = 0; half < 2; ++half) {
#pragma unroll
    for (int i = 0; i < 2; ++i)
#pragma unroll
      for (int j = 0; j < 8; ++j)
#pragma unroll
        for (int r = 0; r < 4; ++r) {
          float v;
          NN_VAL(i, j, r, v);
          u16 hv = f2bf(v);
          u16 sv = half ? f2bf(v - bf2f(hv)) : hv;
          lds[wbp + (i * 16 + qd * 4 + r) * 136 + j * 16 + nl] = sv;
        }
    __syncthreads();
    if (flags & FROW) {
      u16* dst = half ? Crl : Crh;
#pragma unroll
      for (int p2 = 0; p2 < 8; ++p2) {
        int rr = lane >> 1;
        int ch = (lane & 1) + p2 * 2;  // 0..15 (16B chunks across 128 cols)
        bf16x8 vv = *(const bf16x8*)&lds[wbp + rr * 136 + ch * 8];
        int gi = I + w * 32 + rr;
        size_t o = ((size_t)(gi >> 3) * (D_DIM >> 6) + (J >> 6) + (ch >> 3)) *
                       512 +
                   (gi & 7) * 64 + (((ch & 7) ^ (gi & 7)) << 3);
        *(bf16x8*)(dst + o) = vv;
      }
    }
    if (flags & FCOL) {
      u16* dst = half ? Ccl : Cch;
#pragma unroll
      for (int jj = 0; jj < 8; ++jj) {
        int cmaj = J + jj * 16 + (lane >> 2);
        int run = (lane & 3) * 8;
        int m = I + w * 32 + run;  // multiple of 8
        u16 tp[8];
#pragma unroll
        for (int r2 = 0; r2 < 8; ++r2) tp[r2] = lds[wbp + (run + r2) * 136 +
                                                    jj * 16 + (lane >> 2)];
        uint4 pk;
        pk.x = (u32)tp[0] | ((u32)tp[1] << 16);
        pk.y = (u32)tp[2] | ((u32)tp[3] << 16);
        pk.z = (u32)tp[4] | ((u32)tp[5] << 16);
        pk.w = (u32)tp[6] | ((u32)tp[7] << 16);
        size_t o = ((size_t)(cmaj >> 3) * (D_DIM >> 6) + (m >> 6)) * 512 +
                   (cmaj & 7) * 64 + ((((m >> 3) & 7) ^ (cmaj & 7)) << 3);
        *(uint4*)(dst + o) = pk;
      }
    }
    __syncthreads();
  }
#undef NN_VAL
}

// plain GEMM over 256 tiles (16x16), XCD column-ownership swizzle
__global__ __launch_bounds__(256)
void k_nn(const u16* Xh, const u16* Xl, const u16* Wh, const u16* Wl, u16* Crh,
          u16* Crl, u16* Cch, u16* Ccl, float* scal, int K, float diag,
          float pmul, int flags, int tidx) {
  __shared__ u16 lds[65536];
  int bi, bj;
  swz256(blockIdx.x + (blockIdx.y << 4), bi, bj);
  nn_body(lds, Xh, Xl, Wh, Wl, Crh, Crl, Cch, Ccl, scal, K, diag, pmul, flags,
          tidx, bi, bj);
}

// both triangle grams in ONE launch: 272 blocks (2 x 136 lower-tri tiles)
__global__ __launch_bounds__(256)
void k_nn_tri2(const u16* Xh0, const u16* Xl0, u16* Ch0, u16* Cl0,
               const u16* Xh1, const u16* Xl1, u16* Ch1, u16* Cl1,
               float* scal) {
  __shared__ u16 lds[65536];
  int x = blockIdx.x;
  int f5 = (x & 7) * 34 + (x >> 3);  // bijective on [0,272)
  int g = (f5 >= 136) ? 1 : 0;
  int f = f5 - g * 136;
  int bi = (int)((sqrtf(8.f * (float)f + 1.f) - 1.f) * 0.5f);
  while (bi * (bi + 1) / 2 > f) --bi;
  while ((bi + 1) * (bi + 2) / 2 <= f) ++bi;
  int bj = f - bi * (bi + 1) / 2;  // 0 <= bj <= bi
  if (g)
    nn_body(lds, Xh1, Xl1, Xh1, Xl1, Ch1, Cl1, Ch1, Cl1, scal, N_ROWS,
            EPS_DIAG, 1.0f, FROW | FCOL | FTRACE, 2, bi, bj);
  else
    nn_body(lds, Xh0, Xl0, Xh0, Xl0, Ch0, Cl0, Ch0, Cl0, scal, N_ROWS,
            EPS_DIAG, 1.0f, FROW | FCOL | FTRACE, 1, bi, bj);
}

// fused pair: grid (16,16,2)
struct NN2Args {
  const u16 *xh0, *xl0, *wh0, *wl0;
  u16 *crh0, *crl0, *cch0, *ccl0;
  const u16 *xh1, *xl1, *wh1, *wl1;
  u16 *crh1, *crl1, *cch1, *ccl1;
  float pm0, pm1;
};

__global__ __launch_bounds__(256)
void k_nn2(NN2Args a, float* scal) {
  __shared__ u16 lds[65536];
  int bi, bj;
  swz256(blockIdx.x + (blockIdx.y << 4), bi, bj);
  if (blockIdx.z == 0)
    nn_body(lds, a.xh0, a.xl0, a.wh0, a.wl0, a.crh0, a.crl0, a.cch0, a.ccl0,
            scal, D_DIM, 0.f, a.pm0, FROW | FCOL, 0, bi, bj);
  else
    nn_body(lds, a.xh1, a.xl1, a.wh1, a.wl1, a.crh1, a.crl1, a.cch1, a.ccl1,
            scal, D_DIM, 0.f, a.pm1, FROW | FCOL, 0, bi, bj);
}

// ---------------- power iteration (both chains fused) ----------------

__global__ __launch_bounds__(256)
void k_pones2(float* __restrict__ va, float* __restrict__ vb,
              float* __restrict__ snA, float* __restrict__ snB) {
  int t = blockIdx.x * 256 + threadIdx.x;  // 0..4095
  if (t < D_DIM)
    va[t] = 1.0f;
  else
    vb[t - D_DIM] = 1.0f;
  if (t == 0) {
    snA[0] = 1.0f;
    snB[0] = 1.0f;
  }
}

// gram arrays are tiled-swizzled: compute physical addr from logical k.
__global__ __launch_bounds__(256)
void k_gemv2(const u16* __restrict__ Ah, const u16* __restrict__ Bh,
             const float* viA, float* voA, const float* viB, float* voB,
             const float* snA, const float* snB, u32* smA, u32* smB) {
  const int zc = blockIdx.y;
  const u16* Mh = zc ? Bh : Ah;
  const float* vin = zc ? viB : viA;
  float* vout = zc ? voB : voA;
  const float* snorm = zc ? snB : snA;
  u32* smax = zc ? smB : smA;
  __shared__ float vs[D_DIM];
  float inv = 1.0f / snorm[0];
  for (int i = threadIdx.x; i < D_DIM; i += 256) vs[i] = vin[i] * inv;
  __syncthreads();
  int row = blockIdx.x * 4 + (threadIdx.x >> 6);
  int lane = threadIdx.x & 63;
  const size_t rb = (size_t)(row >> 3) * (D_DIM >> 6);
  const int rsub = (row & 7) * 64;
  float s = 0.f;
  for (int c0 = lane * 8; c0 < D_DIM; c0 += 512) {
    size_t addr = (rb + (c0 >> 6)) * 512 + rsub +
                  ((((c0 >> 3) & 7) ^ (row & 7)) << 3);
    uint4 p = *(const uint4*)(Mh + addr);
    u32 w4[4] = {p.x, p.y, p.z, p.w};
#pragma unroll
    for (int q = 0; q < 4; ++q) {
      s += bf2f((u16)(w4[q] & 0xffff)) * vs[c0 + 2 * q];
      s += bf2f((u16)(w4[q] >> 16)) * vs[c0 + 2 * q + 1];
    }
  }
#pragma unroll
  for (int o = 32; o > 0; o >>= 1) s += __shfl_down(s, o, 64);
  if (lane == 0) {
    vout[row] = s;
    atomicMax(smax, __float_as_uint(fabsf(s)));
  }
}

__global__ void k_setc(float* scal) {
  scal[5] = 1.1f * scal[11] * scal[21];
}

// T1 = 3I - M/c in BOTH layouts (c = scal[5]); tiled-layout diagonal decode.
__global__ __launch_bounds__(256)
void k_t1(const u16* __restrict__ Mrh, const u16* __restrict__ Mrl,
          const u16* __restrict__ Mth, const u16* __restrict__ Mtl,
          const float* __restrict__ scal, u16* __restrict__ Trh,
          u16* __restrict__ Trl, u16* __restrict__ Tth, u16* __restrict__ Ttl) {
  size_t t = (size_t)blockIdx.x * 256 + threadIdx.x;
  float invc = 1.0f / scal[5];
  size_t e = t * 4;                    // flat element offset (mult of 4)
  int tile = (int)(e >> 9);
  int within = (int)(e & 511);
  int rl = within >> 6;                // 0..7
  int slot = (within >> 3) & 7;
  int i = (tile / (D_DIM >> 6)) * 8 + rl;              // logical major
  int jb = (tile % (D_DIM >> 6)) * 64 + ((slot ^ rl) << 3) + (within & 7);
#pragma unroll
  for (int pass = 0; pass < 2; ++pass) {
    const u16* sh = pass ? Mth : Mrh;
    const u16* sl = pass ? Mtl : Mrl;
    u16* dh = pass ? Tth : Trh;
    u16* dl = pass ? Ttl : Trl;
    uint2 hv = ((const uint2*)sh)[t];
    uint2 lv = ((const uint2*)sl)[t];
    u16 hs[4] = {(u16)(hv.x & 0xffff), (u16)(hv.x >> 16), (u16)(hv.y & 0xffff),
                 (u16)(hv.y >> 16)};
    u16 ls[4] = {(u16)(lv.x & 0xffff), (u16)(lv.x >> 16), (u16)(lv.y & 0xffff),
                 (u16)(lv.y >> 16)};
    u16 th[4], tl[4];
#pragma unroll
    for (int c = 0; c < 4; ++c) {
      float m = bf2f(hs[c]) + bf2f(ls[c]);
      float tv = ((i == jb + c) ? 3.0f : 0.0f) - m * invc;
      th[c] = f2bf(tv);
      tl[c] = f2bf(tv - bf2f(th[c]));
    }
    ((uint2*)dh)[t] = make_uint2((u32)th[0] | ((u32)th[1] << 16),
                                 (u32)th[2] | ((u32)th[3] << 16));
    ((uint2*)dl)[t] = make_uint2((u32)tl[0] | ((u32)tl[1] << 16),
                                 (u32)tl[2] | ((u32)tl[3] << 16));
  }
}

// tr(Y*T) via row-layout x col-layout flat dot: invariant under the shared
// tiled map (flat pos f holds Y[i(f),j(f)] and T[j(f),i(f)] resp.).
__global__ __launch_bounds__(256)
void k_trdot(const u16* __restrict__ Ah, const u16* __restrict__ Al,
             const u16* __restrict__ Bh, const u16* __restrict__ Bl,
             double* __restrict__ acc) {
  size_t t = (size_t)blockIdx.x * 256 + threadIdx.x;
  uint2 ah = ((const uint2*)Ah)[t], al = ((const uint2*)Al)[t];
  uint2 bh = ((const uint2*)Bh)[t], bl = ((const uint2*)Bl)[t];
  float s = 0.f;
  u32 ha[4] = {ah.x & 0xffffu, ah.x >> 16, ah.y & 0xffffu, ah.y >> 16};
  u32 la[4] = {al.x & 0xffffu, al.x >> 16, al.y & 0xffffu, al.y >> 16};
  u32 hb[4] = {bh.x & 0xffffu, bh.x >> 16, bh.y & 0xffffu, bh.y >> 16};
  u32 lb[4] = {bl.x & 0xffffu, bl.x >> 16, bl.y & 0xffffu, bl.y >> 16};
#pragma unroll
  for (int c = 0; c < 4; ++c)
    s += (bf2f((u16)ha[c]) + bf2f((u16)la[c])) *
         (bf2f((u16)hb[c]) + bf2f((u16)lb[c]));
#pragma unroll
  for (int o = 32; o > 0; o >>= 1) s += __shfl_down(s, o, 64);
  __shared__ float red[4];
  if ((threadIdx.x & 63) == 0) red[threadIdx.x >> 6] = s;
  __syncthreads();
  if (threadIdx.x == 0)
    atomicAdd(acc, (double)(red[0] + red[1] + red[2] + red[3]));
}

__global__ void k_final2(const float* __restrict__ scal,
                         const double* __restrict__ dot,
                         float* __restrict__ out) {
  out[0] = scal[1] + scal[2] - sqrtf(scal[5]) * (float)dot[0];
}

// ================== FALLBACK PATH (round-4, 64MB-proven) ==================

__global__ __launch_bounds__(256)
void k_zsplit(const float* __restrict__ z, const float* __restrict__ mean,
              const float* __restrict__ rstd, u16* __restrict__ zh,
              u16* __restrict__ zl) {
  size_t t = (size_t)blockIdx.x * 256 + threadIdx.x;
  int ci = (int)(t & 511);
  float4 v = ((const float4*)z)[t];
  float4 m = ((const float4*)mean)[ci];
  float4 r = ((const float4*)rstd)[ci];
  float x[4] = {(v.x - m.x) * r.x, (v.y - m.y) * r.y, (v.z - m.z) * r.z,
                (v.w - m.w) * r.w};
  u16 h[4], l[4];
#pragma unroll
  for (int i = 0; i < 4; ++i) {
    h[i] = f2bf(x[i]);
    l[i] = f2bf(x[i] - bf2f(h[i]));
  }
  ((uint2*)zh)[t] = make_uint2((u32)h[0] | ((u32)h[1] << 16),
                               (u32)h[2] | ((u32)h[3] << 16));
  ((uint2*)zl)[t] = make_uint2((u32)l[0] | ((u32)l[1] << 16),
                               (u32)l[2] | ((u32)l[3] << 16));
}

__global__ __launch_bounds__(256)
void k_gram_mm(const u16* __restrict__ zh, const u16* __restrict__ zl,
               u16* __restrict__ Oh, u16* __restrict__ Ol) {
  __shared__ u16 lds[24576];
  const int tid = threadIdx.x;
  const int lane = tid & 63;
  const int w = tid >> 6;
  const int I = blockIdx.y * 128;
  const int J = blockIdx.x * 64;
  const int kp = tid >> 4;
  const int nc = tid & 15;
  const int qq = kp >> 2;
  const int kd = (kp & 3) * 2;
  const size_t aro = (size_t)(2 * kp) * D_DIM + I + nc * 8;
  const size_t bro = (size_t)(2 * kp) * D_DIM + J + nc * 4;
  union U4 { uint4 v; u16 s[8]; };
  union U2 { uint2 v; u16 s[4]; };
  U4 ah0, ah1, al0, al1;
  U2 bh0, bh1, bl0, bl1;
  f32x4 acc[2][4];
#pragma unroll
  for (int i = 0; i < 2; ++i)
#pragma unroll
    for (int j = 0; j < 4; ++j) acc[i][j] = (f32x4){0.f, 0.f, 0.f, 0.f};
#define GRAM_LOAD(k1)                         \
  {                                           \
    size_t ao = aro + (size_t)(k1)*D_DIM;     \
    size_t bo = bro + (size_t)(k1)*D_DIM;     \
    ah0.v = *(const uint4*)(zh + ao);         \
    ah1.v = *(const uint4*)(zh + ao + D_DIM); \
    al0.v = *(const uint4*)(zl + ao);         \
    al1.v = *(const uint4*)(zl + ao + D_DIM); \
    bh0.v = *(const uint2*)(zh + bo);         \
    bh1.v = *(const uint2*)(zh + bo + D_DIM); \
    bl0.v = *(const uint2*)(zl + bo);         \
    bl1.v = *(const uint2*)(zl + bo + D_DIM); \
  }
#define GRAM_PACK(buf)                                                       \
  {                                                                          \
    _Pragma("unroll") for (int j = 0; j < 8; ++j) {                          \
      int mc = nc * 8 + j;                                                   \
      int t2 = mc >> 4, ml = mc & 15;                                        \
      int slot = (t2 * 64 + qq * 16 + ml) ^ t2;                              \
      *(u32*)&lds[(buf) + slot * 8 + kd] =                                   \
          (u32)ah0.s[j] | ((u32)ah1.s[j] << 16);                             \
      *(u32*)&lds[(buf) + 4096 + slot * 8 + kd] =                            \
          (u32)al0.s[j] | ((u32)al1.s[j] << 16);                             \
    }                                                                        \
    _Pragma("unroll") for (int j = 0; j < 4; ++j) {                          \
      int n = nc * 4 + j;                                                    \
      int u = n >> 4, nl = n & 15;                                           \
      int slot = (u * 64 + qq * 16 + nl) ^ u;                                \
      *(u32*)&lds[(buf) + 8192 + slot * 8 + kd] =                            \
          (u32)bh0.s[j] | ((u32)bh1.s[j] << 16);                             \
      *(u32*)&lds[(buf) + 10240 + slot * 8 + kd] =                           \
          (u32)bl0.s[j] | ((u32)bl1.s[j] << 16);                             \
    }                                                                        \
  }
  GRAM_LOAD(0);
  GRAM_PACK(0);
  __syncthreads();
  for (int k = 0; k < N_ROWS / 32; ++k) {
    const int cur = (k & 1) * 12288;
    const int nxt = 12288 - cur;
    if (k < N_ROWS / 32 - 1) GRAM_LOAD((k + 1) * 32);
    bf16x8 fah[2], fal[2], fbh[4], fbl[4];
#pragma unroll
    for (int i = 0; i < 2; ++i) {
      int t2 = w * 2 + i;
      int sl = (t2 * 64 + lane) ^ t2;
      fah[i] = *(const bf16x8*)&lds[cur + sl * 8];
      fal[i] = *(const bf16x8*)&lds[cur + 4096 + sl * 8];
    }
#pragma unroll
    for (int j = 0; j < 4; ++j) {
      int sl = (j * 64 + lane) ^ j;
      fbh[j] = *(const bf16x8*)&lds[cur + 8192 + sl * 8];
      fbl[j] = *(const bf16x8*)&lds[cur + 10240 + sl * 8];
    }
#pragma unroll
    for (int i = 0; i < 2; ++i)
#pragma unroll
      for (int j = 0; j < 4; ++j) {
        acc[i][j] = __builtin_amdgcn_mfma_f32_16x16x32_bf16(fah[i], fbh[j],
                                                            acc[i][j], 0, 0, 0);
        acc[i][j] = __builtin_amdgcn_mfma_f32_16x16x32_bf16(fah[i], fbl[j],
                                                            acc[i][j], 0, 0, 0);
        acc[i][j] = __builtin_amdgcn_mfma_f32_16x16x32_bf16(fal[i], fbh[j],
                                                            acc[i][j], 0, 0, 0);
      }
    if (k < N_ROWS / 32 - 1) GRAM_PACK(nxt);
    __syncthreads();
  }
  const int qd = lane >> 4;
  const int nl = lane & 15;
#pragma unroll
  for (int i = 0; i < 2; ++i)
#pragma unroll
    for (int j = 0; j < 4; ++j)
#pragma unroll
      for (int r = 0; r < 4; ++r) {
        int gi = I + w * 32 + i * 16 + qd * 4 + r;
        int gj = J + j * 16 + nl;
        float v = acc[i][j][r] + ((gi == gj) ? EPS_DIAG : 0.f);
        u16 h = f2bf(v);
        u16 l = f2bf(v - bf2f(h));
        Oh[(size_t)gi * D_DIM + gj] = h;
        Ol[(size_t)gi * D_DIM + gj] = l;
      }
#undef GRAM_LOAD
#undef GRAM_PACK
}

template <int MODE>
__global__ __launch_bounds__(256)
void k_mm(const u16* __restrict__ Ph, const u16* __restrict__ Pl,
          const u16* __restrict__ Qh, const u16* __restrict__ Ql,
          u16* __restrict__ Ch, u16* __restrict__ Cl,
          const float* __restrict__ scal) {
  __shared__ u16 lds[24576];
  const int tid = threadIdx.x;
  const int lane = tid & 63;
  const int w = tid >> 6;
  const int I = blockIdx.y * 128;
  const int J = blockIdx.x * 64;
  const int kp = tid >> 4;
  const int nc = tid & 15;
  const int qq = kp >> 2;
  const int kd = (kp & 3) * 2;
  size_t aro[2];
  int acl[2], abase[2];
#pragma unroll
  for (int p = 0; p < 2; ++p) {
    int s = p * 256 + w * 64 + lane;
    aro[p] = (size_t)(I + (s >> 6) * 16 + (s & 15)) * D_DIM;
    acl[p] = ((s >> 4) & 3) * 8;
    abase[p] = (p * 256 + w * 64) * 8;
  }
  const size_t bro = (size_t)(2 * kp) * D_DIM + J + nc * 4;
  union U2 { uint2 v; u16 s[4]; };
  U2 bh0, bh1, bl0, bl1;
  f32x4 acc[2][4];
#pragma unroll
  for (int i = 0; i < 2; ++i)
#pragma unroll
    for (int j = 0; j < 4; ++j) acc[i][j] = (f32x4){0.f, 0.f, 0.f, 0.f};
#define MM_STAGE_A(k1, buf)                                              \
  {                                                                      \
    _Pragma("unroll") for (int p = 0; p < 2; ++p) {                      \
      GLD16(Ph + aro[p] + (k1) + acl[p], &lds[(buf) + abase[p]]);        \
      GLD16(Pl + aro[p] + (k1) + acl[p], &lds[(buf) + 4096 + abase[p]]); \
    }                                                                    \
  }
#define MM_LOAD_B(k1)                         \
  {                                           \
    size_t bo = bro + (size_t)(k1)*D_DIM;     \
    bh0.v = *(const uint2*)(Qh + bo);         \
    bh1.v = *(const uint2*)(Qh + bo + D_DIM); \
    bl0.v = *(const uint2*)(Ql + bo);         \
    bl1.v = *(const uint2*)(Ql + bo + D_DIM); \
  }
#define MM_PACK_B(buf)                                                       \
  {                                                                          \
    _Pragma("unroll") for (int j = 0; j < 4; ++j) {                          \
      int n = nc * 4 + j;                                                    \
      int u = n >> 4, nl2 = n & 15;                                          \
      int slot = (u * 64 + qq * 16 + nl2) ^ u;                               \
      *(u32*)&lds[(buf) + 8192 + slot * 8 + kd] =                            \
          (u32)bh0.s[j] | ((u32)bh1.s[j] << 16);                             \
      *(u32*)&lds[(buf) + 10240 + slot * 8 + kd] =                           \
          (u32)bl0.s[j] | ((u32)bl1.s[j] << 16);                             \
    }                                                                        \
  }
  MM_STAGE_A(0, 0);
  MM_LOAD_B(0);
  MM_PACK_B(0);
  __syncthreads();
  for (int k = 0; k < D_DIM / 32; ++k) {
    const int cur = (k & 1) * 12288;
    const int nxt = 12288 - cur;
    if (k < D_DIM / 32 - 1) {
      MM_STAGE_A((k + 1) * 32, nxt);
      MM_LOAD_B((k + 1) * 32);
    }
    bf16x8 fah[2], fal[2], fbh[4], fbl[4];
#pragma unroll
    for (int i = 0; i < 2; ++i) {
      int t2 = w * 2 + i;
      fah[i] = *(const bf16x8*)&lds[cur + (t2 * 64 + lane) * 8];
      fal[i] = *(const bf16x8*)&lds[cur + 4096 + (t2 * 64 + lane) * 8];
    }
#pragma unroll
    for (int j = 0; j < 4; ++j) {
      int sl = (j * 64 + lane) ^ j;
      fbh[j] = *(const bf16x8*)&lds[cur + 8192 + sl * 8];
      fbl[j] = *(const bf16x8*)&lds[cur + 10240 + sl * 8];
    }
#pragma unroll
    for (int i = 0; i < 2; ++i)
#pragma unroll
      for (int j = 0; j < 4; ++j) {
        acc[i][j] = __builtin_amdgcn_mfma_f32_16x16x32_bf16(fah[i], fbh[j],
                                                            acc[i][j], 0, 0, 0);
        acc[i][j] = __builtin_amdgcn_mfma_f32_16x16x32_bf16(fah[i], fbl[j],
                                                            acc[i][j], 0, 0, 0);
        acc[i][j] = __builtin_amdgcn_mfma_f32_16x16x32_bf16(fal[i], fbh[j],
                                                            acc[i][j], 0, 0, 0);
      }
    if (k < D_DIM / 32 - 1) MM_PACK_B(nxt);
    __syncthreads();
  }
  float mul = (MODE == 2) ? 0.5f : 1.0f;
  if (MODE == 3) mul = 0.5f / sqrtf(scal[0]);
  const int qd = lane >> 4;
  const int nl = lane & 15;
#pragma unroll
  for (int i = 0; i < 2; ++i)
#pragma unroll
    for (int j = 0; j < 4; ++j)
#pragma unroll
      for (int r = 0; r < 4; ++r) {
        int gi = I + w * 32 + i * 16 + qd * 4 + r;
        int gj = J + j * 16 + nl;
        float v = acc[i][j][r];
        if (MODE == 1)
          v = ((gi == gj) ? 3.0f : 0.0f) - v;
        else
          v *= mul;
        u16 h = f2bf(v);
        u16 l = f2bf(v - bf2f(h));
        Ch[(size_t)gi * D_DIM + gj] = h;
        Cl[(size_t)gi * D_DIM + gj] = l;
      }
#undef MM_STAGE_A
#undef MM_LOAD_B
#undef MM_PACK_B
}

__global__ __launch_bounds__(256)
void k_frob_hl(const u16* __restrict__ mh, const u16* __restrict__ ml,
               float* __restrict__ c2) {
  size_t t = (size_t)blockIdx.x * 256 + threadIdx.x;
  uint2 hv = ((const uint2*)mh)[t];
  uint2 lv = ((const uint2*)ml)[t];
  float v0 = bf2f((u16)(hv.x & 0xffff)) + bf2f((u16)(lv.x & 0xffff));
  float v1 = bf2f((u16)(hv.x >> 16)) + bf2f((u16)(lv.x >> 16));
  float v2 = bf2f((u16)(hv.y & 0xffff)) + bf2f((u16)(lv.y & 0xffff));
  float v3 = bf2f((u16)(hv.y >> 16)) + bf2f((u16)(lv.y >> 16));
  float q = v0 * v0 + v1 * v1 + v2 * v2 + v3 * v3;
#pragma unroll
  for (int o = 32; o > 0; o >>= 1) q += __shfl_down(q, o, 64);
  __shared__ float red[4];
  if ((threadIdx.x & 63) == 0) red[threadIdx.x >> 6] = q;
  __syncthreads();
  if (threadIdx.x == 0) atomicAdd(c2, red[0] + red[1] + red[2] + red[3]);
}

__global__ __launch_bounds__(256)
void k_t1z1(const u16* __restrict__ Mh, const u16* __restrict__ Ml,
            const float* __restrict__ scal, u16* __restrict__ Th,
            u16* __restrict__ Tl, u16* __restrict__ Zh, u16* __restrict__ Zl) {
  size_t t = (size_t)blockIdx.x * 256 + threadIdx.x;
  float invc = 1.0f / sqrtf(scal[0]);
  size_t e = t * 4;
  int i = (int)(e >> 11);
  int j0 = (int)(e & (D_DIM - 1));
  uint2 hv = ((const uint2*)Mh)[t];
  uint2 lv = ((const uint2*)Ml)[t];
  u16 hs[4] = {(u16)(hv.x & 0xffff), (u16)(hv.x >> 16), (u16)(hv.y & 0xffff),
               (u16)(hv.y >> 16)};
  u16 ls[4] = {(u16)(lv.x & 0xffff), (u16)(lv.x >> 16), (u16)(lv.y & 0xffff),
               (u16)(lv.y >> 16)};
  u16 th[4], tl[4], zh[4], zl[4];
#pragma unroll
  for (int c = 0; c < 4; ++c) {
    float m = bf2f(hs[c]) + bf2f(ls[c]);
    float tv = ((i == j0 + c) ? 3.0f : 0.0f) - m * invc;
    th[c] = f2bf(tv);
    tl[c] = f2bf(tv - bf2f(th[c]));
    float zv = 0.5f * tv;
    zh[c] = f2bf(zv);
    zl[c] = f2bf(zv - bf2f(zh[c]));
  }
  ((uint2*)Th)[t] = make_uint2((u32)th[0] | ((u32)th[1] << 16),
                               (u32)th[2] | ((u32)th[3] << 16));
  ((uint2*)Tl)[t] = make_uint2((u32)tl[0] | ((u32)tl[1] << 16),
                               (u32)tl[2] | ((u32)tl[3] << 16));
  ((uint2*)Zh)[t] = make_uint2((u32)zh[0] | ((u32)zh[1] << 16),
                               (u32)zh[2] | ((u32)zh[3] << 16));
  ((uint2*)Zl)[t] = make_uint2((u32)zl[0] | ((u32)zl[1] << 16),
                               (u32)zl[2] | ((u32)zl[3] << 16));
}

__global__ __launch_bounds__(256)
void k_trace_hl(const u16* __restrict__ mh, const u16* __restrict__ ml,
                float* __restrict__ out) {
  __shared__ float red[256];
  float s = 0.f;
  for (int i = threadIdx.x; i < D_DIM; i += 256) {
    size_t d = (size_t)i * (D_DIM + 1);
    s += bf2f(mh[d]) + bf2f(ml[d]);
  }
  red[threadIdx.x] = s;
  __syncthreads();
  for (int o = 128; o > 0; o >>= 1) {
    if (threadIdx.x < o) red[threadIdx.x] += red[threadIdx.x + o];
    __syncthreads();
  }
  if (threadIdx.x == 0) out[0] = red[0];
}

__global__ __launch_bounds__(256)
void k_final(const u16* __restrict__ Yh, const u16* __restrict__ Yl,
             const float* __restrict__ scal, float* __restrict__ out) {
  __shared__ float red[256];
  float s = 0.f;
  for (int i = threadIdx.x; i < D_DIM; i += 256) {
    size_t d = (size_t)i * (D_DIM + 1);
    s += bf2f(Yh[d]) + bf2f(Yl[d]);
  }
  red[threadIdx.x] = s;
  __syncthreads();
  for (int o = 128; o > 0; o >>= 1) {
    if (threadIdx.x < o) red[threadIdx.x] += red[threadIdx.x + o];
    __syncthreads();
  }
  if (threadIdx.x == 0) {
    float sqrtc = sqrtf(sqrtf(scal[0]));
    out[0] = scal[1] + scal[2] - 2.0f * sqrtc * red[0];
  }
}

// ---------------- launch ----------------

extern "C" void kernel_launch(void* const* d_in, const int* in_sizes, int n_in,
                              void* d_out, int out_size, void* d_ws,
                              size_t ws_size, hipStream_t stream) {
  (void)in_sizes; (void)n_in; (void)out_size;
  const float* za = (const float*)d_in[0];
  const float* zb = (const float*)d_in[1];
  float* out = (float*)d_out;
  float* ws = (float*)d_ws;
  float* stat = ws;
  float* scal = ws + 4 * D_DIM;

  hipMemsetAsync(ws, 0, (4 * D_DIM + 32) * sizeof(float), stream);
  dim3 blk(256);

  const size_t NEED = 65536ull + 8ull * 16 * 1024 * 1024;
  if (ws_size >= NEED) {
    // ================= FAST PATH =================
    char* pool = (char*)d_ws + 65536;
    auto uh = [&](int u) { return (u16*)(pool + (size_t)u * 16777216); };
    auto ul = [&](int u) {
      return (u16*)(pool + (size_t)u * 16777216 + 8388608);
    };
    // z-split A: whole U0 (h) + whole U1 (l); B: whole U4 + whole U5
    u16* ZhA = (u16*)(pool);
    u16* ZlA = (u16*)(pool + 1ull * 16777216);
    u16* ZhB = (u16*)(pool + 4ull * 16777216);
    u16* ZlB = (u16*)(pool + 5ull * 16777216);
    dim3 gm(16, 16);

    k_colstats2<<<dim3(8, 16, 2), blk, 0, stream>>>(za, zb, stat);
    k_finalize_stats<<<16, blk, 0, stream>>>(stat);
    k_zsplit_t2<<<dim3(64, 32, 2), blk, 0, stream>>>(za, zb, stat, ZhA, ZlA,
                                                     ZhB, ZlB);
    // both grams, one launch: A -> U2 (trace scal[1]), B -> U3 (scal[2])
    k_nn_tri2<<<272, blk, 0, stream>>>(ZhA, ZlA, uh(2), ul(2), ZhB, ZlB,
                                       uh(3), ul(3), scal);

    // paired power iteration: lambda_max(A)->scal[11], lambda_max(B)->scal[21]
    k_pones2<<<16, blk, 0, stream>>>(stat, stat + 2 * D_DIM, scal + 6,
                                     scal + 16);
    for (int s = 0; s < 5; ++s) {
      const float* viA = (s & 1) ? stat + D_DIM : stat;
      float* voA = (s & 1) ? stat : stat + D_DIM;
      const float* viB = (s & 1) ? stat + 3 * D_DIM : stat + 2 * D_DIM;
      float* voB = (s & 1) ? stat + 2 * D_DIM : stat + 3 * D_DIM;
      k_gemv2<<<dim3(512, 2), blk, 0, stream>>>(
          uh(2), uh(3), viA, voA, viB, voB, scal + 6 + s, scal + 16 + s,
          (u32*)(scal + 7 + s), (u32*)(scal + 17 + s));
    }
    k_setc<<<1, 1, 0, stream>>>(scal);

    // M = A*B -> row U4, col U5 (zsplit-B dead; B symmetric => W=B row)
    k_nn<<<gm, blk, 0, stream>>>(uh(2), ul(2), uh(3), ul(3), uh(4), ul(4),
                                 uh(5), ul(5), scal, D_DIM, 0.f, 1.0f,
                                 FROW | FCOL, 0);
    // T1 = 3I - M/c -> row U6, col U7
    k_t1<<<4096, blk, 0, stream>>>(uh(4), ul(4), uh(5), ul(5), scal, uh(6),
                                   ul(6), uh(7), ul(7));
    // Y1 = (0.5/c) M*T1 -> row U0, col U1 (zsplit-A dead)
    k_nn<<<gm, blk, 0, stream>>>(uh(4), ul(4), uh(7), ul(7), uh(0), ul(0),
                                 uh(1), ul(1), scal, D_DIM, 0.f, 0.5f,
                                 FROW | FCOL | FINVC, 0);
    // T2 = 3I - 0.5*T1*Y1 -> row U4, col U5 (M dead; Z1 = T1/2 implicit)
    k_nn<<<gm, blk, 0, stream>>>(uh(6), ul(6), uh(1), ul(1), uh(4), ul(4),
                                 uh(5), ul(5), scal, D_DIM, 3.f, -0.5f,
                                 FROW | FCOL, 0);
    // fused: Y2 = 0.5*Y1*T2 -> U1(row),U2(col) ; Z2 = 0.25*T2*T1 -> U3,U6
    {
      NN2Args a;
      a.xh0 = uh(0); a.xl0 = ul(0); a.wh0 = uh(5); a.wl0 = ul(5);
      a.crh0 = uh(1); a.crl0 = ul(1); a.cch0 = uh(2); a.ccl0 = ul(2);
      a.pm0 = 0.5f;
      a.xh1 = uh(4); a.xl1 = ul(4); a.wh1 = uh(7); a.wl1 = ul(7);
      a.crh1 = uh(3); a.crl1 = ul(3); a.cch1 = uh(6); a.ccl1 = ul(6);
      a.pm1 = 0.25f;
      k_nn2<<<dim3(16, 16, 2), blk, 0, stream>>>(a, scal);
    }
    int Yr = 1, Yt = 2, Zr = 3, Zt = 6;
    int fr0 = 0, fr1 = 4, fr2 = 5, fr3 = 7;
    for (int it = 3; it <= 10; ++it) {
      // T = 3I - Z*Y -> row fr0, col fr1
      k_nn<<<gm, blk, 0, stream>>>(uh(Zr), ul(Zr), uh(Yt), ul(Yt), uh(fr0),
                                   ul(fr0), uh(fr1), ul(fr1), scal, D_DIM, 3.f,
                                   -1.f, FROW | FCOL, 0);
      // fused: Yn = 0.5*Y*T -> fr2,fr3 ; Zn = 0.5*T*Z -> Yt,Zr (dead units)
      NN2Args a;
      a.xh0 = uh(Yr); a.xl0 = ul(Yr); a.wh0 = uh(fr1); a.wl0 = ul(fr1);
      a.crh0 = uh(fr2); a.crl0 = ul(fr2); a.cch0 = uh(fr3); a.ccl0 = ul(fr3);
      a.pm0 = 0.5f;
      a.xh1 = uh(fr0); a.xl1 = ul(fr0); a.wh1 = uh(Zt); a.wl1 = ul(Zt);
      a.crh1 = uh(Yt); a.crl1 = ul(Yt); a.cch1 = uh(Zr); a.ccl1 = ul(Zr);
      a.pm1 = 0.5f;
      k_nn2<<<dim3(16, 16, 2), blk, 0, stream>>>(a, scal);
      int nYr = fr2, nYt = fr3, nZr = Yt, nZt = Zr;
      int nf0 = Yr, nf1 = Zt, nf2 = fr0, nf3 = fr1;
      Yr = nYr; Yt = nYt; Zr = nZr; Zt = nZt;
      fr0 = nf0; fr1 = nf1; fr2 = nf2; fr3 = nf3;
    }
    // step 11: T11 col-only -> fr0 ; trY11 = 0.5*dot(Y10 row, T11 col)
    k_nn<<<gm, blk, 0, stream>>>(uh(Zr), ul(Zr), uh(Yt), ul(Yt), uh(fr1),
                                 ul(fr1), uh(fr0), ul(fr0), scal, D_DIM, 3.f,
                                 -1.f, FCOL, 0);
    k_trdot<<<4096, blk, 0, stream>>>(uh(Yr), ul(Yr), uh(fr0), ul(fr0),
                                      (double*)(scal + 24));
    k_final2<<<1, 1, 0, stream>>>(scal, (const double*)(scal + 24), out);
    return;
  }

  // ================= FALLBACK (round-4, 64MB) =================
  k_colstats2<<<dim3(8, 16, 2), blk, 0, stream>>>(za, zb, stat);
  k_finalize_stats<<<16, blk, 0, stream>>>(stat);
  u16* b[8];
  {
    char* pool = (char*)d_ws + 65536;
    for (int i = 0; i < 8; ++i) b[i] = (u16*)(pool + (size_t)i * 8388608);
  }
#define PH(p) b[2 * (p)]
#define PL(p) b[2 * (p) + 1]
  u16* zh = b[4];
  u16* zl = b[6];
  dim3 gm(32, 16);
  k_zsplit<<<8192, blk, 0, stream>>>(za, stat, stat + D_DIM, zh, zl);
  k_gram_mm<<<gm, blk, 0, stream>>>(zh, zl, PH(0), PL(0));
  k_zsplit<<<8192, blk, 0, stream>>>(zb, stat + 2 * D_DIM, stat + 3 * D_DIM,
                                     zh, zl);
  k_gram_mm<<<gm, blk, 0, stream>>>(zh, zl, PH(1), PL(1));
  k_trace_hl<<<1, blk, 0, stream>>>(PH(0), PL(0), scal + 1);
  k_trace_hl<<<1, blk, 0, stream>>>(PH(1), PL(1), scal + 2);
  k_mm<0><<<gm, blk, 0, stream>>>(PH(0), PL(0), PH(1), PL(1), PH(2), PL(2),
                                  scal);
  k_frob_hl<<<4096, blk, 0, stream>>>(PH(2), PL(2), scal);
  k_t1z1<<<4096, blk, 0, stream>>>(PH(2), PL(2), scal, PH(0), PL(0), PH(1),
                                   PL(1));
  k_mm<3><<<gm, blk, 0, stream>>>(PH(2), PL(2), PH(0), PL(0), PH(3), PL(3),
                                  scal);
  int Y = 3, Z = 1, fA = 0, fB = 2;
  for (int it = 2; it <= NS_ITERS; ++it) {
    k_mm<1><<<gm, blk, 0, stream>>>(PH(Z), PL(Z), PH(Y), PL(Y), PH(fA), PL(fA),
                                    scal);
    k_mm<2><<<gm, blk, 0, stream>>>(PH(Y), PL(Y), PH(fA), PL(fA), PH(fB),
                                    PL(fB), scal);
    if (it < NS_ITERS)
      k_mm<2><<<gm, blk, 0, stream>>>(PH(fA), PL(fA), PH(Z), PL(Z), PH(Y),
                                      PL(Y), scal);
    int oy = Y, oz = Z, oa = fA, ob = fB;
    Y = ob; Z = oy; fA = oz; fB = oa;
  }
  k_final<<<1, blk, 0, stream>>>(PH(Y), PL(Y), scal, out);
#undef PH
#undef PL
}

// Round 10
// 2215.329 us; speedup vs baseline: 1.3126x; 1.0795x over previous
//
#include <hip/hip_runtime.h>
#include <math.h>

typedef unsigned short u16;
typedef unsigned int u32;

#define D_DIM 2048
#define N_ROWS 4096
#define EPS_DIAG 1e-3f
#define NS_ITERS 16  // fallback path only

typedef __attribute__((ext_vector_type(8))) short bf16x8;
typedef __attribute__((ext_vector_type(4))) float f32x4;

__device__ __forceinline__ u16 f2bf(float f) {
  u32 u = __float_as_uint(f);
  u += 0x7fffu + ((u >> 16) & 1u);
  return (u16)(u >> 16);
}
__device__ __forceinline__ float bf2f(u16 h) {
  return __uint_as_float(((u32)h) << 16);
}

#define GLD16(g, l)                                        \
  __builtin_amdgcn_global_load_lds(                        \
      (const __attribute__((address_space(1))) void*)(g),  \
      (__attribute__((address_space(3))) void*)(l), 16, 0, 0)

// ---------------------------------------------------------------------------
// KB-MAJOR TILED SWIZZLED GLOBAL LAYOUT (fast path only).
// All GEMM operands are [2048][K] stored as 512B tiles (8 rows x 32 k),
// k-block-major so that one staging pass (one kb, many rows) is contiguous:
//   off(r,k) = ((k>>5)*256 + (r>>3))*256
//            + (r&7)*32 + ((((k>>3)&3) ^ (r&3)) << 3) + (k&7)     [elems]
// SLAB = 256*256 = 65536 elems per k-block (major dim always 2048).
// Each GLD16 stages 16 rows x 32k = ONE contiguous 1KB burst; the frag
// ds_read is a balanced bijection onto 1KB (bank-balanced). BK=32 ->
// 32KB buffers -> 64KB LDS -> 2 blocks/CU (duty-cycle occupancy: fill the
// per-step VMEM idle window that caps 1-block/CU staging at ~14.6 B/cyc).
// ---------------------------------------------------------------------------
#define SLAB 65536

// scal layout (floats): [1]=trA [2]=trB [5]=c  [6..11]=powerA  [16..21]=powerB
// [24..25] = trdot double accumulator

// XCD column-ownership swizzle for 256-tile grids (16 bi x 16 bj).
__device__ __forceinline__ void swz256(int id, int& bi, int& bj) {
  int s = id & 7;   // XCD (dispatch round-robin)
  int j = id >> 3;  // 0..31 within XCD
  bj = s * 2 + (j & 1);
  bi = j >> 1;
}

// ---------------- column statistics (both inputs, one launch) ----------------

__global__ __launch_bounds__(256)
void k_colstats2(const float* __restrict__ za, const float* __restrict__ zb,
                 float* __restrict__ stat) {
  const float* z = blockIdx.z ? zb : za;
  float* sum_ = stat + blockIdx.z * 2 * D_DIM;
  float* ssq_ = sum_ + D_DIM;
  const int c = blockIdx.x * 256 + threadIdx.x;
  const int r0 = blockIdx.y * (N_ROWS / 16);
  float s = 0.f, q = 0.f;
#pragma unroll 8
  for (int r = 0; r < N_ROWS / 16; ++r) {
    float v = z[(size_t)(r0 + r) * D_DIM + c];
    s += v;
    q += v * v;
  }
  atomicAdd(&sum_[c], s);
  atomicAdd(&ssq_[c], q);
}

__global__ __launch_bounds__(256)
void k_finalize_stats(float* stat) {
  const int t = blockIdx.x * 256 + threadIdx.x;
  const int g = t >> 11;
  const int c = t & (D_DIM - 1);
  float* base = stat + g * 2 * D_DIM;
  float s = base[c];
  float q = base[D_DIM + c];
  float mean = s * (1.0f / N_ROWS);
  float var = (q - (float)N_ROWS * mean * mean) * (1.0f / (N_ROWS - 1));
  var = fmaxf(var, 1e-30f);
  base[c] = mean;
  base[D_DIM + c] = 1.0f / sqrtf(var);
}

// ================== FAST PATH (needs 128MB + 64KB workspace) ==================

// standardize + split + TRANSPOSE both inputs: z[N][D] -> Zt[D][N] bf16 h/l
// Output in kb-major tiled swizzled layout (major d, minor n, K=N_ROWS).
__global__ __launch_bounds__(256)
void k_zsplit_t2(const float* __restrict__ za, const float* __restrict__ zb,
                 const float* __restrict__ stat, u16* __restrict__ Zh0,
                 u16* __restrict__ Zl0, u16* __restrict__ Zh1,
                 u16* __restrict__ Zl1) {
  __shared__ float T[64 * 72];
  const float* z = blockIdx.z ? zb : za;
  const float* mean = stat + blockIdx.z * 2 * D_DIM;
  const float* rstd = mean + D_DIM;
  u16* Zth = blockIdx.z ? Zh1 : Zh0;
  u16* Ztl = blockIdx.z ? Zl1 : Zl0;
  const int t = threadIdx.x;
  const int r0 = blockIdx.x * 64;
  const int c0 = blockIdx.y * 64;
#pragma unroll
  for (int p = 0; p < 4; ++p) {
    int row = p * 16 + (t >> 4);
    int c4 = t & 15;
    float4 v = *(const float4*)(z + (size_t)(r0 + row) * D_DIM + c0 + c4 * 4);
    *(float4*)&T[row * 72 + c4 * 4] = v;
  }
  __syncthreads();
  const int c = c0 + (t >> 2);
  const float m = mean[c];
  const float r = rstd[c];
  const int cc = t >> 2;
#pragma unroll
  for (int g = 0; g < 2; ++g) {
    int rbase = g * 32 + (t & 3) * 8;
    u16 hs[8], ls[8];
#pragma unroll
    for (int i = 0; i < 8; ++i) {
      float x = (T[(rbase + i) * 72 + cc] - m) * r;
      hs[i] = f2bf(x);
      ls[i] = f2bf(x - bf2f(hs[i]));
    }
    uint4 ph, pl;
    ph.x = (u32)hs[0] | ((u32)hs[1] << 16);
    ph.y = (u32)hs[2] | ((u32)hs[3] << 16);
    ph.z = (u32)hs[4] | ((u32)hs[5] << 16);
    ph.w = (u32)hs[6] | ((u32)hs[7] << 16);
    pl.x = (u32)ls[0] | ((u32)ls[1] << 16);
    pl.y = (u32)ls[2] | ((u32)ls[3] << 16);
    pl.z = (u32)ls[4] | ((u32)ls[5] << 16);
    pl.w = (u32)ls[6] | ((u32)ls[7] << 16);
    int n = r0 + rbase;  // multiple of 8
    size_t o = (size_t)(n >> 5) * SLAB + (size_t)(c >> 3) * 256 +
               (c & 7) * 32 + ((((n >> 3) & 3) ^ (c & 3)) << 3);
    *(uint4*)(Zth + o) = ph;
    *(uint4*)(Ztl + o) = pl;
  }
}

#define FINVC 1
#define FTRACE 4
#define FCOL 8
#define FROW 16

// Unified split-bf16 MFMA GEMM body: C = diag*I + pm*(X * W^T).
// 128x128 tile, BK=32, kb-major contiguous staging (8 GLD16/wave/step),
// 32KB buffers -> 2 blocks/CU. Schedule (race-free per round 4):
//   barrier#1 -> STAGE(k+1)->nxt -> vmcnt(8) -> barrier#2 -> compute(cur)
__device__ __forceinline__ void nn_body(
    u16* lds, const u16* __restrict__ Xh, const u16* __restrict__ Xl,
    const u16* __restrict__ Wh, const u16* __restrict__ Wl,
    u16* __restrict__ Crh, u16* __restrict__ Crl, u16* __restrict__ Cch,
    u16* __restrict__ Ccl, float* __restrict__ scal, int K, float diag,
    float pmul, int flags, int tidx, int bi, int bj) {
  const int tid = threadIdx.x;
  const int lane = tid & 63;
  const int w = tid >> 6;
  const int I = bi * 128;
  const int J = bj * 128;

  // staging: GLD16 q covers 16 rows x one k-block, contiguous 1KB.
  size_t xro[2], wro[2];
  int lbase[2];
#pragma unroll
  for (int q = 0; q < 2; ++q) {
    int rl = w * 32 + q * 16;  // multiple of 16 (wave-uniform)
    xro[q] = (size_t)((I + rl) >> 3) * 256 + lane * 8;
    wro[q] = (size_t)((J + rl) >> 3) * 256 + lane * 8;
    lbase[q] = rl * 32;
  }

  f32x4 acc[2][8];
#pragma unroll
  for (int i = 0; i < 2; ++i)
#pragma unroll
    for (int j = 0; j < 8; ++j) acc[i][j] = (f32x4){0.f, 0.f, 0.f, 0.f};

// 8 global_load_lds per wave per stage (X h/l + W h/l, 2 each).
// Buffer layout (u16 elems): Xh @0, Xl @4096, Wh @8192, Wl @12288;
// buffer stride 16384 (32KB).
#define NN_STAGE(kb, buf)                                      \
  {                                                            \
    _Pragma("unroll") for (int q = 0; q < 2; ++q) {            \
      size_t so = (size_t)(kb)*SLAB;                           \
      GLD16(Xh + so + xro[q], &lds[(buf) + lbase[q]]);         \
      GLD16(Xl + so + xro[q], &lds[(buf) + 4096 + lbase[q]]);  \
      GLD16(Wh + so + wro[q], &lds[(buf) + 8192 + lbase[q]]);  \
      GLD16(Wl + so + wro[q], &lds[(buf) + 12288 + lbase[q]]); \
    }                                                          \
  }

// compute: one K=32 pass; 2 jb half-passes (4 W-fragments live -> VGPR cap)
// frag: lane chunk c = lane>>4; LDS slot XOR with (row&3).
#define NN_COMPUTE(CUR)                                                   \
  {                                                                       \
    const int c_ = lane >> 4;                                             \
    bf16x8 fxh[2], fxl[2];                                                \
    _Pragma("unroll") for (int i = 0; i < 2; ++i) {                       \
      int m = w * 32 + i * 16 + (lane & 15);                              \
      int sl = (m >> 3) * 256 + (m & 7) * 32 + ((c_ ^ (m & 3)) << 3);     \
      fxh[i] = *(const bf16x8*)&lds[(CUR) + sl];                          \
      fxl[i] = *(const bf16x8*)&lds[(CUR) + 4096 + sl];                   \
    }                                                                     \
    _Pragma("unroll") for (int jb = 0; jb < 2; ++jb) {                    \
      bf16x8 fwh[4], fwl[4];                                              \
      _Pragma("unroll") for (int jj = 0; jj < 4; ++jj) {                  \
        int n = (jb * 4 + jj) * 16 + (lane & 15);                         \
        int sl = (n >> 3) * 256 + (n & 7) * 32 + ((c_ ^ (n & 3)) << 3);   \
        fwh[jj] = *(const bf16x8*)&lds[(CUR) + 8192 + sl];                \
        fwl[jj] = *(const bf16x8*)&lds[(CUR) + 12288 + sl];               \
      }                                                                   \
      _Pragma("unroll") for (int i = 0; i < 2; ++i)                       \
        _Pragma("unroll") for (int jj = 0; jj < 4; ++jj) {                \
          acc[i][jb * 4 + jj] = __builtin_amdgcn_mfma_f32_16x16x32_bf16(  \
              fxh[i], fwh[jj], acc[i][jb * 4 + jj], 0, 0, 0);             \
          acc[i][jb * 4 + jj] = __builtin_amdgcn_mfma_f32_16x16x32_bf16(  \
              fxh[i], fwl[jj], acc[i][jb * 4 + jj], 0, 0, 0);             \
          acc[i][jb * 4 + jj] = __builtin_amdgcn_mfma_f32_16x16x32_bf16(  \
              fxl[i], fwh[jj], acc[i][jb * 4 + jj], 0, 0, 0);             \
        }                                                                 \
    }                                                                     \
  }

  const int nk = K >> 5;
  NN_STAGE(0, 0);
  for (int k = 0; k < nk; ++k) {
    const int cur = (k & 1) * 16384;
    const int nxt = 16384 - cur;
    // barrier #1: every wave finished its compute(k-1) reads of nxt.
    __builtin_amdgcn_s_barrier();
    __builtin_amdgcn_sched_barrier(0);
    if (k + 1 < nk) {
      NN_STAGE(k + 1, nxt);
      __builtin_amdgcn_sched_barrier(0);
      // own stage(k) landed (oldest 8 of 16); stage(k+1) stays in flight.
      asm volatile("s_waitcnt vmcnt(8)" ::: "memory");
    } else {
      asm volatile("s_waitcnt vmcnt(0)" ::: "memory");
    }
    // barrier #2: ALL waves' stage(k) landed -> cur fully populated.
    __builtin_amdgcn_s_barrier();
    __builtin_amdgcn_sched_barrier(0);
    NN_COMPUTE(cur);
  }
  __syncthreads();  // separate K-loop LDS reads from epilogue LDS writes
#undef NN_COMPUTE
#undef NN_STAGE

  const int qd = lane >> 4;
  const int nl = lane & 15;
  float pm = pmul;
  if (flags & FINVC) pm = pmul / scal[5];

#define NN_VAL(i, j, r, out)                           \
  {                                                    \
    int gi_ = I + w * 32 + (i)*16 + qd * 4 + (r);      \
    int gj_ = J + (j)*16 + nl;                         \
    out = pm * acc[i][j][r];                           \
    if (gi_ == gj_) out += diag;                       \
  }

  if (flags & FTRACE) {
    float ts = 0.f;
#pragma unroll
    for (int i = 0; i < 2; ++i)
#pragma unroll
      for (int j = 0; j < 8; ++j)
#pragma unroll
        for (int r = 0; r < 4; ++r) {
          int gi = I + w * 32 + i * 16 + qd * 4 + r;
          int gj = J + j * 16 + nl;
          if (gi == gj) {
            float v;
            NN_VAL(i, j, r, v);
            ts += v;
          }
        }
#pragma unroll
    for (int o = 32; o > 0; o >>= 1) ts += __shfl_down(ts, o, 64);
    float* red = (float*)lds;
    if (lane == 0) red[w] = ts;
    __syncthreads();
    if (tid == 0) atomicAdd(&scal[tidx], red[0] + red[1] + red[2] + red[3]);
    __syncthreads();
  }

  // dual-layout store via per-wave LDS transpose (wave region: 32x136 u16)
  // Global writes use the kb-major tiled swizzled map.
  const int wbp = w * 4352;
  for (int half = 0; half < 2; ++half) {
#pragma unroll
    for (int i = 0; i < 2; ++i)
#pragma unroll
      for (int j = 0; j < 8; ++j)
#pragma unroll
        for (int r = 0; r < 4; ++r) {
          float v;
          NN_VAL(i, j, r, v);
          u16 hv = f2bf(v);
          u16 sv = half ? f2bf(v - bf2f(hv)) : hv;
          lds[wbp + (i * 16 + qd * 4 + r) * 136 + j * 16 + nl] = sv;
        }
    __syncthreads();
    if (flags & FROW) {
      u16* dst = half ? Crl : Crh;
#pragma unroll
      for (int p2 = 0; p2 < 8; ++p2) {
        int rr = lane >> 1;
        int ch = (lane & 1) + p2 * 2;  // 0..15 (16B chunks across 128 cols)
        bf16x8 vv = *(const bf16x8*)&lds[wbp + rr * 136 + ch * 8];
        int gi = I + w * 32 + rr;
        size_t o = (size_t)((J >> 5) + (ch >> 2)) * SLAB +
                   (size_t)(gi >> 3) * 256 + (gi & 7) * 32 +
                   (((ch & 3) ^ (gi & 3)) << 3);
        *(bf16x8*)(dst + o) = vv;
      }
    }
    if (flags & FCOL) {
      u16* dst = half ? Ccl : Cch;
#pragma unroll
      for (int jj = 0; jj < 8; ++jj) {
        int cmaj = J + jj * 16 + (lane >> 2);
        int run = (lane & 3) * 8;
        int m = I + w * 32 + run;  // multiple of 8
        u16 tp[8];
#pragma unroll
        for (int r2 = 0; r2 < 8; ++r2) tp[r2] = lds[wbp + (run + r2) * 136 +
                                                    jj * 16 + (lane >> 2)];
        uint4 pk;
        pk.x = (u32)tp[0] | ((u32)tp[1] << 16);
        pk.y = (u32)tp[2] | ((u32)tp[3] << 16);
        pk.z = (u32)tp[4] | ((u32)tp[5] << 16);
        pk.w = (u32)tp[6] | ((u32)tp[7] << 16);
        size_t o = (size_t)(m >> 5) * SLAB + (size_t)(cmaj >> 3) * 256 +
                   (cmaj & 7) * 32 + ((((m >> 3) & 3) ^ (cmaj & 3)) << 3);
        *(uint4*)(dst + o) = pk;
      }
    }
    __syncthreads();
  }
#undef NN_VAL
}

// plain GEMM over 256 tiles (16x16), XCD column-ownership swizzle
__global__ __launch_bounds__(256, 2)
void k_nn(const u16* Xh, const u16* Xl, const u16* Wh, const u16* Wl, u16* Crh,
          u16* Crl, u16* Cch, u16* Ccl, float* scal, int K, float diag,
          float pmul, int flags, int tidx) {
  __shared__ u16 lds[32768];
  int bi, bj;
  swz256(blockIdx.x + (blockIdx.y << 4), bi, bj);
  nn_body(lds, Xh, Xl, Wh, Wl, Crh, Crl, Cch, Ccl, scal, K, diag, pmul, flags,
          tidx, bi, bj);
}

// both triangle grams in ONE launch: 272 blocks (2 x 136 lower-tri tiles)
__global__ __launch_bounds__(256, 2)
void k_nn_tri2(const u16* Xh0, const u16* Xl0, u16* Ch0, u16* Cl0,
               const u16* Xh1, const u16* Xl1, u16* Ch1, u16* Cl1,
               float* scal) {
  __shared__ u16 lds[32768];
  int x = blockIdx.x;
  int f5 = (x & 7) * 34 + (x >> 3);  // bijective on [0,272)
  int g = (f5 >= 136) ? 1 : 0;
  int f = f5 - g * 136;
  int bi = (int)((sqrtf(8.f * (float)f + 1.f) - 1.f) * 0.5f);
  while (bi * (bi + 1) / 2 > f) --bi;
  while ((bi + 1) * (bi + 2) / 2 <= f) ++bi;
  int bj = f - bi * (bi + 1) / 2;  // 0 <= bj <= bi
  if (g)
    nn_body(lds, Xh1, Xl1, Xh1, Xl1, Ch1, Cl1, Ch1, Cl1, scal, N_ROWS,
            EPS_DIAG, 1.0f, FROW | FCOL | FTRACE, 2, bi, bj);
  else
    nn_body(lds, Xh0, Xl0, Xh0, Xl0, Ch0, Cl0, Ch0, Cl0, scal, N_ROWS,
            EPS_DIAG, 1.0f, FROW | FCOL | FTRACE, 1, bi, bj);
}

// fused pair: grid (16,16,2)
struct NN2Args {
  const u16 *xh0, *xl0, *wh0, *wl0;
  u16 *crh0, *crl0, *cch0, *ccl0;
  const u16 *xh1, *xl1, *wh1, *wl1;
  u16 *crh1, *crl1, *cch1, *ccl1;
  float pm0, pm1;
};

__global__ __launch_bounds__(256, 2)
void k_nn2(NN2Args a, float* scal) {
  __shared__ u16 lds[32768];
  int bi, bj;
  swz256(blockIdx.x + (blockIdx.y << 4), bi, bj);
  if (blockIdx.z == 0)
    nn_body(lds, a.xh0, a.xl0, a.wh0, a.wl0, a.crh0, a.crl0, a.cch0, a.ccl0,
            scal, D_DIM, 0.f, a.pm0, FROW | FCOL, 0, bi, bj);
  else
    nn_body(lds, a.xh1, a.xl1, a.wh1, a.wl1, a.crh1, a.crl1, a.cch1, a.ccl1,
            scal, D_DIM, 0.f, a.pm1, FROW | FCOL, 0, bi, bj);
}

// ---------------- power iteration (both chains fused) ----------------

__global__ __launch_bounds__(256)
void k_pones2(float* __restrict__ va, float* __restrict__ vb,
              float* __restrict__ snA, float* __restrict__ snB) {
  int t = blockIdx.x * 256 + threadIdx.x;  // 0..4095
  if (t < D_DIM)
    va[t] = 1.0f;
  else
    vb[t - D_DIM] = 1.0f;
  if (t == 0) {
    snA[0] = 1.0f;
    snB[0] = 1.0f;
  }
}

// gram arrays are kb-major tiled: compute physical addr from logical k.
__global__ __launch_bounds__(256)
void k_gemv2(const u16* __restrict__ Ah, const u16* __restrict__ Bh,
             const float* viA, float* voA, const float* viB, float* voB,
             const float* snA, const float* snB, u32* smA, u32* smB) {
  const int zc = blockIdx.y;
  const u16* Mh = zc ? Bh : Ah;
  const float* vin = zc ? viB : viA;
  float* vout = zc ? voB : voA;
  const float* snorm = zc ? snB : snA;
  u32* smax = zc ? smB : smA;
  __shared__ float vs[D_DIM];
  float inv = 1.0f / snorm[0];
  for (int i = threadIdx.x; i < D_DIM; i += 256) vs[i] = vin[i] * inv;
  __syncthreads();
  int row = blockIdx.x * 4 + (threadIdx.x >> 6);
  int lane = threadIdx.x & 63;
  const size_t rb = (size_t)(row >> 3) * 256 + (row & 7) * 32;
  float s = 0.f;
  for (int c0 = lane * 8; c0 < D_DIM; c0 += 512) {
    size_t addr = (size_t)(c0 >> 5) * SLAB + rb +
                  ((((c0 >> 3) & 3) ^ (row & 3)) << 3);
    uint4 p = *(const uint4*)(Mh + addr);
    u32 w4[4] = {p.x, p.y, p.z, p.w};
#pragma unroll
    for (int q = 0; q < 4; ++q) {
      s += bf2f((u16)(w4[q] & 0xffff)) * vs[c0 + 2 * q];
      s += bf2f((u16)(w4[q] >> 16)) * vs[c0 + 2 * q + 1];
    }
  }
#pragma unroll
  for (int o = 32; o > 0; o >>= 1) s += __shfl_down(s, o, 64);
  if (lane == 0) {
    vout[row] = s;
    atomicMax(smax, __float_as_uint(fabsf(s)));
  }
}

__global__ void k_setc(float* scal) {
  scal[5] = 1.1f * scal[11] * scal[21];
}

// T1 = 3I - M/c in BOTH layouts (c = scal[5]); kb-major diagonal decode.
__global__ __launch_bounds__(256)
void k_t1(const u16* __restrict__ Mrh, const u16* __restrict__ Mrl,
          const u16* __restrict__ Mth, const u16* __restrict__ Mtl,
          const float* __restrict__ scal, u16* __restrict__ Trh,
          u16* __restrict__ Trl, u16* __restrict__ Tth, u16* __restrict__ Ttl) {
  size_t t = (size_t)blockIdx.x * 256 + threadIdx.x;
  float invc = 1.0f / scal[5];
  size_t e = t * 4;                  // flat element offset (mult of 4)
  int kb = (int)(e >> 16);
  int rem = (int)(e & 65535);
  int rg = rem >> 8;
  int within = rem & 255;
  int rr = within >> 5;
  int slot = (within >> 3) & 3;
  int e0 = within & 7;               // 0 or 4
  int i = rg * 8 + rr;               // logical major
  int jb = kb * 32 + ((slot ^ (rr & 3)) << 3) + e0;  // logical minor
#pragma unroll
  for (int pass = 0; pass < 2; ++pass) {
    const u16* sh = pass ? Mth : Mrh;
    const u16* sl = pass ? Mtl : Mrl;
    u16* dh = pass ? Tth : Trh;
    u16* dl = pass ? Ttl : Trl;
    uint2 hv = ((const uint2*)sh)[t];
    uint2 lv = ((const uint2*)sl)[t];
    u16 hs[4] = {(u16)(hv.x & 0xffff), (u16)(hv.x >> 16), (u16)(hv.y & 0xffff),
                 (u16)(hv.y >> 16)};
    u16 ls[4] = {(u16)(lv.x & 0xffff), (u16)(lv.x >> 16), (u16)(lv.y & 0xffff),
                 (u16)(lv.y >> 16)};
    u16 th[4], tl[4];
#pragma unroll
    for (int c = 0; c < 4; ++c) {
      float m = bf2f(hs[c]) + bf2f(ls[c]);
      float tv = ((i == jb + c) ? 3.0f : 0.0f) - m * invc;
      th[c] = f2bf(tv);
      tl[c] = f2bf(tv - bf2f(th[c]));
    }
    ((uint2*)dh)[t] = make_uint2((u32)th[0] | ((u32)th[1] << 16),
                                 (u32)th[2] | ((u32)th[3] << 16));
    ((uint2*)dl)[t] = make_uint2((u32)tl[0] | ((u32)tl[1] << 16),
                                 (u32)tl[2] | ((u32)tl[3] << 16));
  }
}

// tr(Y*T) via row-layout x col-layout flat dot: invariant under the shared
// kb-major map (flat pos f holds Y[i(f),j(f)] and T[j(f),i(f)] resp.).
__global__ __launch_bounds__(256)
void k_trdot(const u16* __restrict__ Ah, const u16* __restrict__ Al,
             const u16* __restrict__ Bh, const u16* __restrict__ Bl,
             double* __restrict__ acc) {
  size_t t = (size_t)blockIdx.x * 256 + threadIdx.x;
  uint2 ah = ((const uint2*)Ah)[t], al = ((const uint2*)Al)[t];
  uint2 bh = ((const uint2*)Bh)[t], bl = ((const uint2*)Bl)[t];
  float s = 0.f;
  u32 ha[4] = {ah.x & 0xffffu, ah.x >> 16, ah.y & 0xffffu, ah.y >> 16};
  u32 la[4] = {al.x & 0xffffu, al.x >> 16, al.y & 0xffffu, al.y >> 16};
  u32 hb[4] = {bh.x & 0xffffu, bh.x >> 16, bh.y & 0xffffu, bh.y >> 16};
  u32 lb[4] = {bl.x & 0xffffu, bl.x >> 16, bl.y & 0xffffu, bl.y >> 16};
#pragma unroll
  for (int c = 0; c < 4; ++c)
    s += (bf2f((u16)ha[c]) + bf2f((u16)la[c])) *
         (bf2f((u16)hb[c]) + bf2f((u16)lb[c]));
#pragma unroll
  for (int o = 32; o > 0; o >>= 1) s += __shfl_down(s, o, 64);
  __shared__ float red[4];
  if ((threadIdx.x & 63) == 0) red[threadIdx.x >> 6] = s;
  __syncthreads();
  if (threadIdx.x == 0)
    atomicAdd(acc, (double)(red[0] + red[1] + red[2] + red[3]));
}

__global__ void k_final2(const float* __restrict__ scal,
                         const double* __restrict__ dot,
                         float* __restrict__ out) {
  out[0] = scal[1] + scal[2] - sqrtf(scal[5]) * (float)dot[0];
}

// ================== FALLBACK PATH (round-4, 64MB-proven) ==================

__global__ __launch_bounds__(256)
void k_zsplit(const float* __restrict__ z, const float* __restrict__ mean,
              const float* __restrict__ rstd, u16* __restrict__ zh,
              u16* __restrict__ zl) {
  size_t t = (size_t)blockIdx.x * 256 + threadIdx.x;
  int ci = (int)(t & 511);
  float4 v = ((const float4*)z)[t];
  float4 m = ((const float4*)mean)[ci];
  float4 r = ((const float4*)rstd)[ci];
  float x[4] = {(v.x - m.x) * r.x, (v.y - m.y) * r.y, (v.z - m.z) * r.z,
                (v.w - m.w) * r.w};
  u16 h[4], l[4];
#pragma unroll
  for (int i = 0; i < 4; ++i) {
    h[i] = f2bf(x[i]);
    l[i] = f2bf(x[i] - bf2f(h[i]));
  }
  ((uint2*)zh)[t] = make_uint2((u32)h[0] | ((u32)h[1] << 16),
                               (u32)h[2] | ((u32)h[3] << 16));
  ((uint2*)zl)[t] = make_uint2((u32)l[0] | ((u32)l[1] << 16),
                               (u32)l[2] | ((u32)l[3] << 16));
}

__global__ __launch_bounds__(256)
void k_gram_mm(const u16* __restrict__ zh, const u16* __restrict__ zl,
               u16* __restrict__ Oh, u16* __restrict__ Ol) {
  __shared__ u16 lds[24576];
  const int tid = threadIdx.x;
  const int lane = tid & 63;
  const int w = tid >> 6;
  const int I = blockIdx.y * 128;
  const int J = blockIdx.x * 64;
  const int kp = tid >> 4;
  const int nc = tid & 15;
  const int qq = kp >> 2;
  const int kd = (kp & 3) * 2;
  const size_t aro = (size_t)(2 * kp) * D_DIM + I + nc * 8;
  const size_t bro = (size_t)(2 * kp) * D_DIM + J + nc * 4;
  union U4 { uint4 v; u16 s[8]; };
  union U2 { uint2 v; u16 s[4]; };
  U4 ah0, ah1, al0, al1;
  U2 bh0, bh1, bl0, bl1;
  f32x4 acc[2][4];
#pragma unroll
  for (int i = 0; i < 2; ++i)
#pragma unroll
    for (int j = 0; j < 4; ++j) acc[i][j] = (f32x4){0.f, 0.f, 0.f, 0.f};
#define GRAM_LOAD(k1)                         \
  {                                           \
    size_t ao = aro + (size_t)(k1)*D_DIM;     \
    size_t bo = bro + (size_t)(k1)*D_DIM;     \
    ah0.v = *(const uint4*)(zh + ao);         \
    ah1.v = *(const uint4*)(zh + ao + D_DIM); \
    al0.v = *(const uint4*)(zl + ao);         \
    al1.v = *(const uint4*)(zl + ao + D_DIM); \
    bh0.v = *(const uint2*)(zh + bo);         \
    bh1.v = *(const uint2*)(zh + bo + D_DIM); \
    bl0.v = *(const uint2*)(zl + bo);         \
    bl1.v = *(const uint2*)(zl + bo + D_DIM); \
  }
#define GRAM_PACK(buf)                                                       \
  {                                                                          \
    _Pragma("unroll") for (int j = 0; j < 8; ++j) {                          \
      int mc = nc * 8 + j;                                                   \
      int t2 = mc >> 4, ml = mc & 15;                                        \
      int slot = (t2 * 64 + qq * 16 + ml) ^ t2;                              \
      *(u32*)&lds[(buf) + slot * 8 + kd] =                                   \
          (u32)ah0.s[j] | ((u32)ah1.s[j] << 16);                             \
      *(u32*)&lds[(buf) + 4096 + slot * 8 + kd] =                            \
          (u32)al0.s[j] | ((u32)al1.s[j] << 16);                             \
    }                                                                        \
    _Pragma("unroll") for (int j = 0; j < 4; ++j) {                          \
      int n = nc * 4 + j;                                                    \
      int u = n >> 4, nl = n & 15;                                           \
      int slot = (u * 64 + qq * 16 + nl) ^ u;                                \
      *(u32*)&lds[(buf) + 8192 + slot * 8 + kd] =                            \
          (u32)bh0.s[j] | ((u32)bh1.s[j] << 16);                             \
      *(u32*)&lds[(buf) + 10240 + slot * 8 + kd] =                           \
          (u32)bl0.s[j] | ((u32)bl1.s[j] << 16);                             \
    }                                                                        \
  }
  GRAM_LOAD(0);
  GRAM_PACK(0);
  __syncthreads();
  for (int k = 0; k < N_ROWS / 32; ++k) {
    const int cur = (k & 1) * 12288;
    const int nxt = 12288 - cur;
    if (k < N_ROWS / 32 - 1) GRAM_LOAD((k + 1) * 32);
    bf16x8 fah[2], fal[2], fbh[4], fbl[4];
#pragma unroll
    for (int i = 0; i < 2; ++i) {
      int t2 = w * 2 + i;
      int sl = (t2 * 64 + lane) ^ t2;
      fah[i] = *(const bf16x8*)&lds[cur + sl * 8];
      fal[i] = *(const bf16x8*)&lds[cur + 4096 + sl * 8];
    }
#pragma unroll
    for (int j = 0; j < 4; ++j) {
      int sl = (j * 64 + lane) ^ j;
      fbh[j] = *(const bf16x8*)&lds[cur + 8192 + sl * 8];
      fbl[j] = *(const bf16x8*)&lds[cur + 10240 + sl * 8];
    }
#pragma unroll
    for (int i = 0; i < 2; ++i)
#pragma unroll
      for (int j = 0; j < 4; ++j) {
        acc[i][j] = __builtin_amdgcn_mfma_f32_16x16x32_bf16(fah[i], fbh[j],
                                                            acc[i][j], 0, 0, 0);
        acc[i][j] = __builtin_amdgcn_mfma_f32_16x16x32_bf16(fah[i], fbl[j],
                                                            acc[i][j], 0, 0, 0);
        acc[i][j] = __builtin_amdgcn_mfma_f32_16x16x32_bf16(fal[i], fbh[j],
                                                            acc[i][j], 0, 0, 0);
      }
    if (k < N_ROWS / 32 - 1) GRAM_PACK(nxt);
    __syncthreads();
  }
  const int qd = lane >> 4;
  const int nl = lane & 15;
#pragma unroll
  for (int i = 0; i < 2; ++i)
#pragma unroll
    for (int j = 0; j < 4; ++j)
#pragma unroll
      for (int r = 0; r < 4; ++r) {
        int gi = I + w * 32 + i * 16 + qd * 4 + r;
        int gj = J + j * 16 + nl;
        float v = acc[i][j][r] + ((gi == gj) ? EPS_DIAG : 0.f);
        u16 h = f2bf(v);
        u16 l = f2bf(v - bf2f(h));
        Oh[(size_t)gi * D_DIM + gj] = h;
        Ol[(size_t)gi * D_DIM + gj] = l;
      }
#undef GRAM_LOAD
#undef GRAM_PACK
}

template <int MODE>
__global__ __launch_bounds__(256)
void k_mm(const u16* __restrict__ Ph, const u16* __restrict__ Pl,
          const u16* __restrict__ Qh, const u16* __restrict__ Ql,
          u16* __restrict__ Ch, u16* __restrict__ Cl,
          const float* __restrict__ scal) {
  __shared__ u16 lds[24576];
  const int tid = threadIdx.x;
  const int lane = tid & 63;
  const int w = tid >> 6;
  const int I = blockIdx.y * 128;
  const int J = blockIdx.x * 64;
  const int kp = tid >> 4;
  const int nc = tid & 15;
  const int qq = kp >> 2;
  const int kd = (kp & 3) * 2;
  size_t aro[2];
  int acl[2], abase[2];
#pragma unroll
  for (int p = 0; p < 2; ++p) {
    int s = p * 256 + w * 64 + lane;
    aro[p] = (size_t)(I + (s >> 6) * 16 + (s & 15)) * D_DIM;
    acl[p] = ((s >> 4) & 3) * 8;
    abase[p] = (p * 256 + w * 64) * 8;
  }
  const size_t bro = (size_t)(2 * kp) * D_DIM + J + nc * 4;
  union U2 { uint2 v; u16 s[4]; };
  U2 bh0, bh1, bl0, bl1;
  f32x4 acc[2][4];
#pragma unroll
  for (int i = 0; i < 2; ++i)
#pragma unroll
    for (int j = 0; j < 4; ++j) acc[i][j] = (f32x4){0.f, 0.f, 0.f, 0.f};
#define MM_STAGE_A(k1, buf)                                              \
  {                                                                      \
    _Pragma("unroll") for (int p = 0; p < 2; ++p) {                      \
      GLD16(Ph + aro[p] + (k1) + acl[p], &lds[(buf) + abase[p]]);        \
      GLD16(Pl + aro[p] + (k1) + acl[p], &lds[(buf) + 4096 + abase[p]]); \
    }                                                                    \
  }
#define MM_LOAD_B(k1)                         \
  {                                           \
    size_t bo = bro + (size_t)(k1)*D_DIM;     \
    bh0.v = *(const uint2*)(Qh + bo);         \
    bh1.v = *(const uint2*)(Qh + bo + D_DIM); \
    bl0.v = *(const uint2*)(Ql + bo);         \
    bl1.v = *(const uint2*)(Ql + bo + D_DIM); \
  }
#define MM_PACK_B(buf)                                                       \
  {                                                                          \
    _Pragma("unroll") for (int j = 0; j < 4; ++j) {                          \
      int n = nc * 4 + j;                                                    \
      int u = n >> 4, nl2 = n & 15;                                          \
      int slot = (u * 64 + qq * 16 + nl2) ^ u;                               \
      *(u32*)&lds[(buf) + 8192 + slot * 8 + kd] =                            \
          (u32)bh0.s[j] | ((u32)bh1.s[j] << 16);                             \
      *(u32*)&lds[(buf) + 10240 + slot * 8 + kd] =                           \
          (u32)bl0.s[j] | ((u32)bl1.s[j] << 16);                             \
    }                                                                        \
  }
  MM_STAGE_A(0, 0);
  MM_LOAD_B(0);
  MM_PACK_B(0);
  __syncthreads();
  for (int k = 0; k < D_DIM / 32; ++k) {
    const int cur = (k & 1) * 12288;
    const int nxt = 12288 - cur;
    if (k < D_DIM / 32 - 1) {
      MM_STAGE_A((k + 1) * 32, nxt);
      MM_LOAD_B((k + 1) * 32);
    }
    bf16x8 fah[2], fal[2], fbh[4], fbl[4];
#pragma unroll
    for (int i = 0; i < 2; ++i) {
      int t2 = w * 2 + i;
      fah[i] = *(const bf16x8*)&lds[cur + (t2 * 64 + lane) * 8];
      fal[i] = *(const bf16x8*)&lds[cur + 4096 + (t2 * 64 + lane) * 8];
    }
#pragma unroll
    for (int j = 0; j < 4; ++j) {
      int sl = (j * 64 + lane) ^ j;
      fbh[j] = *(const bf16x8*)&lds[cur + 8192 + sl * 8];
      fbl[j] = *(const bf16x8*)&lds[cur + 10240 + sl * 8];
    }
#pragma unroll
    for (int i = 0; i < 2; ++i)
#pragma unroll
      for (int j = 0; j < 4; ++j) {
        acc[i][j] = __builtin_amdgcn_mfma_f32_16x16x32_bf16(fah[i], fbh[j],
                                                            acc[i][j], 0, 0, 0);
        acc[i][j] = __builtin_amdgcn_mfma_f32_16x16x32_bf16(fah[i], fbl[j],
                                                            acc[i][j], 0, 0, 0);
        acc[i][j] = __builtin_amdgcn_mfma_f32_16x16x32_bf16(fal[i], fbh[j],
                                                            acc[i][j], 0, 0, 0);
      }
    if (k < D_DIM / 32 - 1) MM_PACK_B(nxt);
    __syncthreads();
  }
  float mul = (MODE == 2) ? 0.5f : 1.0f;
  if (MODE == 3) mul = 0.5f / sqrtf(scal[0]);
  const int qd = lane >> 4;
  const int nl = lane & 15;
#pragma unroll
  for (int i = 0; i < 2; ++i)
#pragma unroll
    for (int j = 0; j < 4; ++j)
#pragma unroll
      for (int r = 0; r < 4; ++r) {
        int gi = I + w * 32 + i * 16 + qd * 4 + r;
        int gj = J + j * 16 + nl;
        float v = acc[i][j][r];
        if (MODE == 1)
          v = ((gi == gj) ? 3.0f : 0.0f) - v;
        else
          v *= mul;
        u16 h = f2bf(v);
        u16 l = f2bf(v - bf2f(h));
        Ch[(size_t)gi * D_DIM + gj] = h;
        Cl[(size_t)gi * D_DIM + gj] = l;
      }
#undef MM_STAGE_A
#undef MM_LOAD_B
#undef MM_PACK_B
}

__global__ __launch_bounds__(256)
void k_frob_hl(const u16* __restrict__ mh, const u16* __restrict__ ml,
               float* __restrict__ c2) {
  size_t t = (size_t)blockIdx.x * 256 + threadIdx.x;
  uint2 hv = ((const uint2*)mh)[t];
  uint2 lv = ((const uint2*)ml)[t];
  float v0 = bf2f((u16)(hv.x & 0xffff)) + bf2f((u16)(lv.x & 0xffff));
  float v1 = bf2f((u16)(hv.x >> 16)) + bf2f((u16)(lv.x >> 16));
  float v2 = bf2f((u16)(hv.y & 0xffff)) + bf2f((u16)(lv.y & 0xffff));
  float v3 = bf2f((u16)(hv.y >> 16)) + bf2f((u16)(lv.y >> 16));
  float q = v0 * v0 + v1 * v1 + v2 * v2 + v3 * v3;
#pragma unroll
  for (int o = 32; o > 0; o >>= 1) q += __shfl_down(q, o, 64);
  __shared__ float red[4];
  if ((threadIdx.x & 63) == 0) red[threadIdx.x >> 6] = q;
  __syncthreads();
  if (threadIdx.x == 0) atomicAdd(c2, red[0] + red[1] + red[2] + red[3]);
}

__global__ __launch_bounds__(256)
void k_t1z1(const u16* __restrict__ Mh, const u16* __restrict__ Ml,
            const float* __restrict__ scal, u16* __restrict__ Th,
            u16* __restrict__ Tl, u16* __restrict__ Zh, u16* __restrict__ Zl) {
  size_t t = (size_t)blockIdx.x * 256 + threadIdx.x;
  float invc = 1.0f / sqrtf(scal[0]);
  size_t e = t * 4;
  int i = (int)(e >> 11);
  int j0 = (int)(e & (D_DIM - 1));
  uint2 hv = ((const uint2*)Mh)[t];
  uint2 lv = ((const uint2*)Ml)[t];
  u16 hs[4] = {(u16)(hv.x & 0xffff), (u16)(hv.x >> 16), (u16)(hv.y & 0xffff),
               (u16)(hv.y >> 16)};
  u16 ls[4] = {(u16)(lv.x & 0xffff), (u16)(lv.x >> 16), (u16)(lv.y & 0xffff),
               (u16)(lv.y >> 16)};
  u16 th[4], tl[4], zh[4], zl[4];
#pragma unroll
  for (int c = 0; c < 4; ++c) {
    float m = bf2f(hs[c]) + bf2f(ls[c]);
    float tv = ((i == j0 + c) ? 3.0f : 0.0f) - m * invc;
    th[c] = f2bf(tv);
    tl[c] = f2bf(tv - bf2f(th[c]));
    float zv = 0.5f * tv;
    zh[c] = f2bf(zv);
    zl[c] = f2bf(zv - bf2f(zh[c]));
  }
  ((uint2*)Th)[t] = make_uint2((u32)th[0] | ((u32)th[1] << 16),
                               (u32)th[2] | ((u32)th[3] << 16));
  ((uint2*)Tl)[t] = make_uint2((u32)tl[0] | ((u32)tl[1] << 16),
                               (u32)tl[2] | ((u32)tl[3] << 16));
  ((uint2*)Zh)[t] = make_uint2((u32)zh[0] | ((u32)zh[1] << 16),
                               (u32)zh[2] | ((u32)zh[3] << 16));
  ((uint2*)Zl)[t] = make_uint2((u32)zl[0] | ((u32)zl[1] << 16),
                               (u32)zl[2] | ((u32)zl[3] << 16));
}

__global__ __launch_bounds__(256)
void k_trace_hl(const u16* __restrict__ mh, const u16* __restrict__ ml,
                float* __restrict__ out) {
  __shared__ float red[256];
  float s = 0.f;
  for (int i = threadIdx.x; i < D_DIM; i += 256) {
    size_t d = (size_t)i * (D_DIM + 1);
    s += bf2f(mh[d]) + bf2f(ml[d]);
  }
  red[threadIdx.x] = s;
  __syncthreads();
  for (int o = 128; o > 0; o >>= 1) {
    if (threadIdx.x < o) red[threadIdx.x] += red[threadIdx.x + o];
    __syncthreads();
  }
  if (threadIdx.x == 0) out[0] = red[0];
}

__global__ __launch_bounds__(256)
void k_final(const u16* __restrict__ Yh, const u16* __restrict__ Yl,
             const float* __restrict__ scal, float* __restrict__ out) {
  __shared__ float red[256];
  float s = 0.f;
  for (int i = threadIdx.x; i < D_DIM; i += 256) {
    size_t d = (size_t)i * (D_DIM + 1);
    s += bf2f(Yh[d]) + bf2f(Yl[d]);
  }
  red[threadIdx.x] = s;
  __syncthreads();
  for (int o = 128; o > 0; o >>= 1) {
    if (threadIdx.x < o) red[threadIdx.x] += red[threadIdx.x + o];
    __syncthreads();
  }
  if (threadIdx.x == 0) {
    float sqrtc = sqrtf(sqrtf(scal[0]));
    out[0] = scal[1] + scal[2] - 2.0f * sqrtc * red[0];
  }
}

// ---------------- launch ----------------

extern "C" void kernel_launch(void* const* d_in, const int* in_sizes, int n_in,
                              void* d_out, int out_size, void* d_ws,
                              size_t ws_size, hipStream_t stream) {
  (void)in_sizes; (void)n_in; (void)out_size;
  const float* za = (const float*)d_in[0];
  const float* zb = (const float*)d_in[1];
  float* out = (float*)d_out;
  float* ws = (float*)d_ws;
  float* stat = ws;
  float* scal = ws + 4 * D_DIM;

  hipMemsetAsync(ws, 0, (4 * D_DIM + 32) * sizeof(float), stream);
  dim3 blk(256);

  const size_t NEED = 65536ull + 8ull * 16 * 1024 * 1024;
  if (ws_size >= NEED) {
    // ================= FAST PATH =================
    char* pool = (char*)d_ws + 65536;
    auto uh = [&](int u) { return (u16*)(pool + (size_t)u * 16777216); };
    auto ul = [&](int u) {
      return (u16*)(pool + (size_t)u * 16777216 + 8388608);
    };
    // z-split A: whole U0 (h) + whole U1 (l); B: whole U4 + whole U5
    u16* ZhA = (u16*)(pool);
    u16* ZlA = (u16*)(pool + 1ull * 16777216);
    u16* ZhB = (u16*)(pool + 4ull * 16777216);
    u16* ZlB = (u16*)(pool + 5ull * 16777216);
    dim3 gm(16, 16);

    k_colstats2<<<dim3(8, 16, 2), blk, 0, stream>>>(za, zb, stat);
    k_finalize_stats<<<16, blk, 0, stream>>>(stat);
    k_zsplit_t2<<<dim3(64, 32, 2), blk, 0, stream>>>(za, zb, stat, ZhA, ZlA,
                                                     ZhB, ZlB);
    // both grams, one launch: A -> U2 (trace scal[1]), B -> U3 (scal[2])
    k_nn_tri2<<<272, blk, 0, stream>>>(ZhA, ZlA, uh(2), ul(2), ZhB, ZlB,
                                       uh(3), ul(3), scal);

    // paired power iteration: lambda_max(A)->scal[11], lambda_max(B)->scal[21]
    k_pones2<<<16, blk, 0, stream>>>(stat, stat + 2 * D_DIM, scal + 6,
                                     scal + 16);
    for (int s = 0; s < 5; ++s) {
      const float* viA = (s & 1) ? stat + D_DIM : stat;
      float* voA = (s & 1) ? stat : stat + D_DIM;
      const float* viB = (s & 1) ? stat + 3 * D_DIM : stat + 2 * D_DIM;
      float* voB = (s & 1) ? stat + 2 * D_DIM : stat + 3 * D_DIM;
      k_gemv2<<<dim3(512, 2), blk, 0, stream>>>(
          uh(2), uh(3), viA, voA, viB, voB, scal + 6 + s, scal + 16 + s,
          (u32*)(scal + 7 + s), (u32*)(scal + 17 + s));
    }
    k_setc<<<1, 1, 0, stream>>>(scal);

    // M = A*B -> row U4, col U5 (zsplit-B dead; B symmetric => W=B row)
    k_nn<<<gm, blk, 0, stream>>>(uh(2), ul(2), uh(3), ul(3), uh(4), ul(4),
                                 uh(5), ul(5), scal, D_DIM, 0.f, 1.0f,
                                 FROW | FCOL, 0);
    // T1 = 3I - M/c -> row U6, col U7
    k_t1<<<4096, blk, 0, stream>>>(uh(4), ul(4), uh(5), ul(5), scal, uh(6),
                                   ul(6), uh(7), ul(7));
    // Y1 = (0.5/c) M*T1 -> row U0, col U1 (zsplit-A dead)
    k_nn<<<gm, blk, 0, stream>>>(uh(4), ul(4), uh(7), ul(7), uh(0), ul(0),
                                 uh(1), ul(1), scal, D_DIM, 0.f, 0.5f,
                                 FROW | FCOL | FINVC, 0);
    // T2 = 3I - 0.5*T1*Y1 -> row U4, col U5 (M dead; Z1 = T1/2 implicit)
    k_nn<<<gm, blk, 0, stream>>>(uh(6), ul(6), uh(1), ul(1), uh(4), ul(4),
                                 uh(5), ul(5), scal, D_DIM, 3.f, -0.5f,
                                 FROW | FCOL, 0);
    // fused: Y2 = 0.5*Y1*T2 -> U1(row),U2(col) ; Z2 = 0.25*T2*T1 -> U3,U6
    {
      NN2Args a;
      a.xh0 = uh(0); a.xl0 = ul(0); a.wh0 = uh(5); a.wl0 = ul(5);
      a.crh0 = uh(1); a.crl0 = ul(1); a.cch0 = uh(2); a.ccl0 = ul(2);
      a.pm0 = 0.5f;
      a.xh1 = uh(4); a.xl1 = ul(4); a.wh1 = uh(7); a.wl1 = ul(7);
      a.crh1 = uh(3); a.crl1 = ul(3); a.cch1 = uh(6); a.ccl1 = ul(6);
      a.pm1 = 0.25f;
      k_nn2<<<dim3(16, 16, 2), blk, 0, stream>>>(a, scal);
    }
    int Yr = 1, Yt = 2, Zr = 3, Zt = 6;
    int fr0 = 0, fr1 = 4, fr2 = 5, fr3 = 7;
    for (int it = 3; it <= 10; ++it) {
      // T = 3I - Z*Y -> row fr0, col fr1
      k_nn<<<gm, blk, 0, stream>>>(uh(Zr), ul(Zr), uh(Yt), ul(Yt), uh(fr0),
                                   ul(fr0), uh(fr1), ul(fr1), scal, D_DIM, 3.f,
                                   -1.f, FROW | FCOL, 0);
      // fused: Yn = 0.5*Y*T -> fr2,fr3 ; Zn = 0.5*T*Z -> Yt,Zr (dead units)
      NN2Args a;
      a.xh0 = uh(Yr); a.xl0 = ul(Yr); a.wh0 = uh(fr1); a.wl0 = ul(fr1);
      a.crh0 = uh(fr2); a.crl0 = ul(fr2); a.cch0 = uh(fr3); a.ccl0 = ul(fr3);
      a.pm0 = 0.5f;
      a.xh1 = uh(fr0); a.xl1 = ul(fr0); a.wh1 = uh(Zt); a.wl1 = ul(Zt);
      a.crh1 = uh(Yt); a.crl1 = ul(Yt); a.cch1 = uh(Zr); a.ccl1 = ul(Zr);
      a.pm1 = 0.5f;
      k_nn2<<<dim3(16, 16, 2), blk, 0, stream>>>(a, scal);
      int nYr = fr2, nYt = fr3, nZr = Yt, nZt = Zr;
      int nf0 = Yr, nf1 = Zt, nf2 = fr0, nf3 = fr1;
      Yr = nYr; Yt = nYt; Zr = nZr; Zt = nZt;
      fr0 = nf0; fr1 = nf1; fr2 = nf2; fr3 = nf3;
    }
    // step 11: T11 col-only -> fr0 ; trY11 = 0.5*dot(Y10 row, T11 col)
    k_nn<<<gm, blk, 0, stream>>>(uh(Zr), ul(Zr), uh(Yt), ul(Yt), uh(fr1),
                                 ul(fr1), uh(fr0), ul(fr0), scal, D_DIM, 3.f,
                                 -1.f, FCOL, 0);
    k_trdot<<<4096, blk, 0, stream>>>(uh(Yr), ul(Yr), uh(fr0), ul(fr0),
                                      (double*)(scal + 24));
    k_final2<<<1, 1, 0, stream>>>(scal, (const double*)(scal + 24), out);
    return;
  }

  // ================= FALLBACK (round-4, 64MB) =================
  k_colstats2<<<dim3(8, 16, 2), blk, 0, stream>>>(za, zb, stat);
  k_finalize_stats<<<16, blk, 0, stream>>>(stat);
  u16* b[8];
  {
    char* pool = (char*)d_ws + 65536;
    for (int i = 0; i < 8; ++i) b[i] = (u16*)(pool + (size_t)i * 8388608);
  }
#define PH(p) b[2 * (p)]
#define PL(p) b[2 * (p) + 1]
  u16* zh = b[4];
  u16* zl = b[6];
  dim3 gm(32, 16);
  k_zsplit<<<8192, blk, 0, stream>>>(za, stat, stat + D_DIM, zh, zl);
  k_gram_mm<<<gm, blk, 0, stream>>>(zh, zl, PH(0), PL(0));
  k_zsplit<<<8192, blk, 0, stream>>>(zb, stat + 2 * D_DIM, stat + 3 * D_DIM,
                                     zh, zl);
  k_gram_mm<<<gm, blk, 0, stream>>>(zh, zl, PH(1), PL(1));
  k_trace_hl<<<1, blk, 0, stream>>>(PH(0), PL(0), scal + 1);
  k_trace_hl<<<1, blk, 0, stream>>>(PH(1), PL(1), scal + 2);
  k_mm<0><<<gm, blk, 0, stream>>>(PH(0), PL(0), PH(1), PL(1), PH(2), PL(2),
                                  scal);
  k_frob_hl<<<4096, blk, 0, stream>>>(PH(2), PL(2), scal);
  k_t1z1<<<4096, blk, 0, stream>>>(PH(2), PL(2), scal, PH(0), PL(0), PH(1),
                                   PL(1));
  k_mm<3><<<gm, blk, 0, stream>>>(PH(2), PL(2), PH(0), PL(0), PH(3), PL(3),
                                  scal);
  int Y = 3, Z = 1, fA = 0, fB = 2;
  for (int it = 2; it <= NS_ITERS; ++it) {
    k_mm<1><<<gm, blk, 0, stream>>>(PH(Z), PL(Z), PH(Y), PL(Y), PH(fA), PL(fA),
                                    scal);
    k_mm<2><<<gm, blk, 0, stream>>>(PH(Y), PL(Y), PH(fA), PL(fA), PH(fB),
                                    PL(fB), scal);
    if (it < NS_ITERS)
      k_mm<2><<<gm, blk, 0, stream>>>(PH(fA), PL(fA), PH(Z), PL(Z), PH(Y),
                                      PL(Y), scal);
    int oy = Y, oz = Z, oa = fA, ob = fB;
    Y = ob; Z = oy; fA = oz; fB = oa;
  }
  k_final<<<1, blk, 0, stream>>>(PH(Y), PL(Y), scal, out);
#undef PH
#undef PL
}